// Round 1
// baseline (1220.104 us; speedup 1.0000x reference)
//
#include <hip/hip_runtime.h>
#include <hip/hip_bf16.h>
#include <math.h>

#define NEG_SLOPE 0.2f
#define EPSF 1e-16f

// ---------------- CSR build (once per call; graph is identical every call) ----------------

__global__ void hist_kernel(const int* __restrict__ dst, int* __restrict__ counts, int E) {
  int t = blockIdx.x * 256 + threadIdx.x;
  if (t < E) atomicAdd(&counts[dst[t]], 1);
}

__global__ void scan_kernel(const int* __restrict__ counts, int* __restrict__ off, int N) {
  __shared__ int sdata[1024];
  int tid = threadIdx.x;
  int running = 0;
  for (int base = 0; base < N; base += 1024) {
    int v = (base + tid < N) ? counts[base + tid] : 0;
    sdata[tid] = v;
    __syncthreads();
    // Hillis-Steele inclusive scan
    for (int s = 1; s < 1024; s <<= 1) {
      int tv = (tid >= s) ? sdata[tid - s] : 0;
      __syncthreads();
      sdata[tid] += tv;
      __syncthreads();
    }
    if (base + tid < N) off[base + tid] = running + sdata[tid] - v;  // exclusive
    running += sdata[1023];
    __syncthreads();
  }
  if (tid == 0) off[N] = running;
}

__global__ void scatter_kernel(const int* __restrict__ src, const int* __restrict__ dst,
                               const int* __restrict__ off, int* __restrict__ cur,
                               int* __restrict__ srcp, int* __restrict__ dstp, int E) {
  int t = blockIdx.x * 256 + threadIdx.x;
  if (t < E) {
    int d = dst[t];
    int p = off[d] + atomicAdd(&cur[d], 1);
    srcp[p] = src[t];
    dstp[p] = d;
  }
}

// ---------------- fp32 tiled GEMM: C[M,N] = A[M,K] @ B[K,N] ----------------
// BM=BN=128, BK=16, 256 threads, 8x8 microtile (split 4+4 at +64 to dodge LDS bank conflicts)

__global__ __launch_bounds__(256) void gemm128(const float* __restrict__ A,
                                               const float* __restrict__ B,
                                               float* __restrict__ C, int M, int K, int N) {
  __shared__ float As[16][132];
  __shared__ float Bs[16][132];
  int bm = blockIdx.x, bn = blockIdx.y;
  int t = threadIdx.x;
  int tx = t & 15, ty = t >> 4;

  float acc[8][8];
#pragma unroll
  for (int i = 0; i < 8; i++)
#pragma unroll
    for (int j = 0; j < 8; j++) acc[i][j] = 0.f;

  int r_a = t >> 2;   // A-tile row (0..63), +64 for second half
  int cg_a = t & 3;   // A-tile k-group
  int k_b = t >> 5;   // B-tile k (0..7), +8 for second half
  int cg_b = t & 31;  // B-tile col-group

  for (int kt = 0; kt < K; kt += 16) {
#pragma unroll
    for (int half = 0; half < 2; half++) {
      int r = r_a + half * 64;
      int grow = bm * 128 + r;
      if (grow >= M) grow = M - 1;  // clamp: loaded garbage never stored
      const float4 av = *(const float4*)&A[(size_t)grow * K + kt + cg_a * 4];
      As[cg_a * 4 + 0][r] = av.x;
      As[cg_a * 4 + 1][r] = av.y;
      As[cg_a * 4 + 2][r] = av.z;
      As[cg_a * 4 + 3][r] = av.w;
    }
#pragma unroll
    for (int half = 0; half < 2; half++) {
      int k = k_b + half * 8;
      const float4 bv = *(const float4*)&B[(size_t)(kt + k) * N + bn * 128 + cg_b * 4];
      *(float4*)&Bs[k][cg_b * 4] = bv;
    }
    __syncthreads();
#pragma unroll
    for (int k = 0; k < 16; k++) {
      float a0[4], a1[4], b0[4], b1[4];
      *(float4*)a0 = *(const float4*)&As[k][ty * 4];
      *(float4*)a1 = *(const float4*)&As[k][64 + ty * 4];
      *(float4*)b0 = *(const float4*)&Bs[k][tx * 4];
      *(float4*)b1 = *(const float4*)&Bs[k][64 + tx * 4];
#pragma unroll
      for (int i = 0; i < 4; i++) {
#pragma unroll
        for (int j = 0; j < 4; j++) {
          acc[i][j]         += a0[i] * b0[j];
          acc[i][j + 4]     += a0[i] * b1[j];
          acc[i + 4][j]     += a1[i] * b0[j];
          acc[i + 4][j + 4] += a1[i] * b1[j];
        }
      }
    }
    __syncthreads();
  }
#pragma unroll
  for (int i = 0; i < 8; i++) {
    int r = (i < 4) ? (ty * 4 + i) : (64 + ty * 4 + (i - 4));
    int grow = bm * 128 + r;
    if (grow < M) {
      float4 v0 = {acc[i][0], acc[i][1], acc[i][2], acc[i][3]};
      float4 v1 = {acc[i][4], acc[i][5], acc[i][6], acc[i][7]};
      *(float4*)&C[(size_t)grow * N + bn * 128 + tx * 4] = v0;
      *(float4*)&C[(size_t)grow * N + bn * 128 + 64 + tx * 4] = v1;
    }
  }
}

// ---------------- skinny GEMM for layer 3: C[M,16] = A[M,512] @ B[512,16] ----------------

__global__ __launch_bounds__(256) void gemm_n16(const float* __restrict__ A,
                                                const float* __restrict__ B,
                                                float* __restrict__ C, int M) {
  __shared__ float WsL[512 * 16];
  for (int i = threadIdx.x * 4; i < 512 * 16; i += 1024)
    *(float4*)&WsL[i] = *(const float4*)&B[i];
  __syncthreads();
  int r = threadIdx.x >> 4, c = threadIdx.x & 15;
  int n = blockIdx.x * 16 + r;
  if (n >= M) return;
  float acc = 0.f;
  for (int k = 0; k < 512; k += 4) {
    float4 hv = *(const float4*)&A[(size_t)n * 512 + k];
    acc += hv.x * WsL[k * 16 + c] + hv.y * WsL[(k + 1) * 16 + c] +
           hv.z * WsL[(k + 2) * 16 + c] + hv.w * WsL[(k + 3) * 16 + c];
  }
  C[n * 16 + c] = acc;
}

// ---------------- wsd[k][h] = sum_c Wd[k][h*C+c] * a_d[h][c]  (al_d collapses to x @ wsd) --

__global__ void wsd_kernel(const float* __restrict__ Wd, const float* __restrict__ a_d,
                           float* __restrict__ wsd, int K, int H, int C) {
  int t = blockIdx.x * 256 + threadIdx.x;
  if (t >= K * H) return;
  int k = t / H, h = t % H;
  float s = 0.f;
  for (int c = 0; c < C; c++) s += Wd[(size_t)k * (H * C) + h * C + c] * a_d[h * C + c];
  wsd[k * H + h] = s;
}

// ---------------- attention logits per node: al_s = (xs*a_s).sum(-1), al_d = x @ wsd ------
// H=4, C=128 (layers 1,2). One wave per node.

__global__ void al_kernel(const float* __restrict__ xs, const float* __restrict__ xin,
                          const float* __restrict__ a_s, const float* __restrict__ wsd,
                          float* __restrict__ als, float* __restrict__ ald, int N, int K) {
  int wid = threadIdx.x >> 6, lane = threadIdx.x & 63;
  int n = blockIdx.x * 4 + wid;
  if (n >= N) return;
  // al_s: lane covers channels lane*8..+7, all within head lane>>4
  const float4* xp = (const float4*)&xs[(size_t)n * 512 + lane * 8];
  const float4* ap = (const float4*)&a_s[lane * 8];
  float4 v0 = xp[0], v1 = xp[1], a0 = ap[0], a1 = ap[1];
  float s = v0.x * a0.x + v0.y * a0.y + v0.z * a0.z + v0.w * a0.w +
            v1.x * a1.x + v1.y * a1.y + v1.z * a1.z + v1.w * a1.w;
  for (int o = 1; o < 16; o <<= 1) s += __shfl_xor(s, o);
  if ((lane & 15) == 0) als[n * 4 + (lane >> 4)] = s;
  // al_d: 4 heads simultaneously
  float d0 = 0.f, d1 = 0.f, d2 = 0.f, d3 = 0.f;
  for (int k = lane; k < K; k += 64) {
    float xv = xin[(size_t)n * K + k];
    float4 w = *(const float4*)&wsd[k * 4];
    d0 += xv * w.x; d1 += xv * w.y; d2 += xv * w.z; d3 += xv * w.w;
  }
  for (int o = 1; o < 64; o <<= 1) {
    d0 += __shfl_xor(d0, o); d1 += __shfl_xor(d1, o);
    d2 += __shfl_xor(d2, o); d3 += __shfl_xor(d3, o);
  }
  if (lane == 0) *(float4*)&ald[n * 4] = make_float4(d0, d1, d2, d3);
}

// H=1, C=16 (layer 3)
__global__ void al3_kernel(const float* __restrict__ xs3, const float* __restrict__ h2,
                           const float* __restrict__ as3, const float* __restrict__ wsd,
                           float* __restrict__ als, float* __restrict__ ald, int N) {
  int wid = threadIdx.x >> 6, lane = threadIdx.x & 63;
  int n = blockIdx.x * 4 + wid;
  if (n >= N) return;
  float s = (lane < 16) ? xs3[n * 16 + lane] * as3[lane] : 0.f;
  for (int o = 1; o < 16; o <<= 1) s += __shfl_xor(s, o);
  float d = 0.f;
  for (int k = lane; k < 512; k += 64) d += h2[(size_t)n * 512 + k] * wsd[k];
  for (int o = 1; o < 64; o <<= 1) d += __shfl_xor(d, o);
  if (lane == 0) { als[n] = s; ald[n] = d; }
}

// ---------------- edge phase: logits + segment max, then exp + segment sum ----------------

__device__ __forceinline__ unsigned fmap(float x) {
  unsigned u = __float_as_uint(x);
  return (u & 0x80000000u) ? ~u : (u | 0x80000000u);  // monotone float->uint
}
__device__ __forceinline__ float finvmap(unsigned u) {
  return (u & 0x80000000u) ? __uint_as_float(u ^ 0x80000000u) : __uint_as_float(~u);
}

template <int H>
__global__ void edgeA_kernel(const int* __restrict__ srcp, const int* __restrict__ dstp,
                             const float* __restrict__ als, const float* __restrict__ ald,
                             float* __restrict__ ebuf, unsigned* __restrict__ mbuf, int E) {
  int t = blockIdx.x * 256 + threadIdx.x;
  if (t >= E * H) return;
  int p = t / H, h = t % H;
  int s = srcp[p], d = dstp[p];
  float e = als[s * H + h] + ald[d * H + h];
  e = (e > 0.f) ? e : NEG_SLOPE * e;
  ebuf[t] = e;
  atomicMax(&mbuf[d * H + h], fmap(e));
}

template <int H>
__global__ void edgeB_kernel(const int* __restrict__ dstp, const unsigned* __restrict__ mbuf,
                             float* __restrict__ ebuf, float* __restrict__ den, int E) {
  int t = blockIdx.x * 256 + threadIdx.x;
  if (t >= E * H) return;
  int p = t / H, h = t % H;
  int d = dstp[p];
  float m = finvmap(mbuf[d * H + h]);
  float ex = expf(ebuf[t] - m);
  ebuf[t] = ex;
  atomicAdd(&den[d * H + h], ex);
}

// ---------------- aggregation: out[n] = relu(sum_e alpha_e * xs[src_e] + b) ---------------
// layers 1,2: H*C = 512 channels, one block (256 thr, 2 ch each) per node, CSR order.

__global__ __launch_bounds__(256) void agg512_kernel(
    const float* __restrict__ xs, const float* __restrict__ ebuf,
    const float* __restrict__ den, const int* __restrict__ off,
    const int* __restrict__ srcp, const float* __restrict__ bias,
    float* __restrict__ out, int N) {
  int n = blockIdx.x;
  int t = threadIdx.x;
  int h = t >> 6;  // channel 2t -> head (2t)>>7
  float rw = 1.f / (den[n * 4 + h] + EPSF);
  int p0 = off[n], p1 = off[n + 1];
  float ax = 0.f, ay = 0.f;
  for (int p = p0; p < p1; p++) {
    int s = srcp[p];
    float w = ebuf[p * 4 + h] * rw;
    float2 v = *(const float2*)&xs[(size_t)s * 512 + t * 2];
    ax += w * v.x; ay += w * v.y;
  }
  float2 b = *(const float2*)&bias[t * 2];
  ax = fmaxf(ax + b.x, 0.f);
  ay = fmaxf(ay + b.y, 0.f);
  *(float2*)&out[(size_t)n * 512 + t * 2] = make_float2(ax, ay);
}

// layer 3: H=1, C=16, no relu. 16 nodes per block.
__global__ void agg16_kernel(const float* __restrict__ xs, const float* __restrict__ ebuf,
                             const float* __restrict__ den, const int* __restrict__ off,
                             const int* __restrict__ srcp, const float* __restrict__ bias,
                             float* __restrict__ out, int N) {
  int g = threadIdx.x >> 4, c = threadIdx.x & 15;
  int n = blockIdx.x * 16 + g;
  if (n >= N) return;
  float rw = 1.f / (den[n] + EPSF);
  int p0 = off[n], p1 = off[n + 1];
  float acc = 0.f;
  for (int p = p0; p < p1; p++) acc += ebuf[p] * rw * xs[srcp[p] * 16 + c];
  out[n * 16 + c] = acc + bias[c];
}

// ---------------- launch ----------------

extern "C" void kernel_launch(void* const* d_in, const int* in_sizes, int n_in,
                              void* d_out, int out_size, void* d_ws, size_t ws_size,
                              hipStream_t stream) {
  const float* x   = (const float*)d_in[0];
  const int*   ei  = (const int*)d_in[1];
  const float* Ws1 = (const float*)d_in[2];
  const float* Wd1 = (const float*)d_in[3];
  const float* as1 = (const float*)d_in[4];
  const float* ad1 = (const float*)d_in[5];
  const float* b1  = (const float*)d_in[6];
  const float* Ws2 = (const float*)d_in[7];
  const float* Wd2 = (const float*)d_in[8];
  const float* as2 = (const float*)d_in[9];
  const float* ad2 = (const float*)d_in[10];
  const float* b2  = (const float*)d_in[11];
  const float* Ws3 = (const float*)d_in[12];
  const float* Wd3 = (const float*)d_in[13];
  const float* as3 = (const float*)d_in[14];
  const float* ad3 = (const float*)d_in[15];
  const float* b3  = (const float*)d_in[16];

  const int N = in_sizes[0] / 128;  // 50000
  const int E = in_sizes[1] / 2;    // 400000
  const int* src = ei;
  const int* dst = ei + E;

  // workspace layout (bytes); total ~218.3 MB
  char* w = (char*)d_ws;
  float*    A      = (float*)(w + 0);           // xs scratch  [N,512]  102,400,000
  float*    Bh     = (float*)(w + 102400000);   // h buffer    [N,512]  102,400,000
  float*    als    = (float*)(w + 204800000);   // [N,4]
  float*    ald    = (float*)(w + 205600000);   // [N,4]
  unsigned* mbuf   = (unsigned*)(w + 206400000);// [N,4] mapped-max
  float*    den    = (float*)(w + 207200000);   // [N,4]
  int*      counts = (int*)(w + 208000000);     // [N]
  int*      cur    = (int*)(w + 208200000);     // [N]
  int*      offs   = (int*)(w + 208400000);     // [N+1]
  int*      srcp   = (int*)(w + 208600192);     // [E]
  int*      dstp   = (int*)(w + 210200192);     // [E]
  float*    ebuf   = (float*)(w + 211800192);   // [E,4]
  float*    wsd    = (float*)(w + 218200192);   // [512,4]

  // ---- CSR build ----
  hipMemsetAsync(counts, 0, 2 * (size_t)N * 4, stream);  // counts + cur (contiguous)
  hist_kernel<<<(E + 255) / 256, 256, 0, stream>>>(dst, counts, E);
  scan_kernel<<<1, 1024, 0, stream>>>(counts, offs, N);
  scatter_kernel<<<(E + 255) / 256, 256, 0, stream>>>(src, dst, offs, cur, srcp, dstp, E);

  dim3 gemm_grid((N + 127) / 128, 4);

  // ---- layer 1: in=x (K=128) ----
  wsd_kernel<<<(128 * 4 + 255) / 256, 256, 0, stream>>>(Wd1, ad1, wsd, 128, 4, 128);
  gemm128<<<gemm_grid, 256, 0, stream>>>(x, Ws1, A, N, 128, 512);
  al_kernel<<<(N + 3) / 4, 256, 0, stream>>>(A, x, as1, wsd, als, ald, N, 128);
  hipMemsetAsync(mbuf, 0, 2 * (size_t)N * 4 * 4, stream);  // mbuf (mapped -inf = 0) + den
  edgeA_kernel<4><<<(E * 4 + 255) / 256, 256, 0, stream>>>(srcp, dstp, als, ald, ebuf, mbuf, E);
  edgeB_kernel<4><<<(E * 4 + 255) / 256, 256, 0, stream>>>(dstp, mbuf, ebuf, den, E);
  agg512_kernel<<<N, 256, 0, stream>>>(A, ebuf, den, offs, srcp, b1, Bh, N);

  // ---- layer 2: in=Bh (K=512) ----
  wsd_kernel<<<(512 * 4 + 255) / 256, 256, 0, stream>>>(Wd2, ad2, wsd, 512, 4, 128);
  gemm128<<<gemm_grid, 256, 0, stream>>>(Bh, Ws2, A, N, 512, 512);
  al_kernel<<<(N + 3) / 4, 256, 0, stream>>>(A, Bh, as2, wsd, als, ald, N, 512);
  hipMemsetAsync(mbuf, 0, 2 * (size_t)N * 4 * 4, stream);
  edgeA_kernel<4><<<(E * 4 + 255) / 256, 256, 0, stream>>>(srcp, dstp, als, ald, ebuf, mbuf, E);
  edgeB_kernel<4><<<(E * 4 + 255) / 256, 256, 0, stream>>>(dstp, mbuf, ebuf, den, E);
  agg512_kernel<<<N, 256, 0, stream>>>(A, ebuf, den, offs, srcp, b2, Bh, N);  // in-place h ok

  // ---- layer 3: in=Bh (K=512, N=16, H=1) ----
  wsd_kernel<<<(512 + 255) / 256, 256, 0, stream>>>(Wd3, ad3, wsd, 512, 1, 16);
  gemm_n16<<<(N + 15) / 16, 256, 0, stream>>>(Bh, Ws3, A, N);
  al3_kernel<<<(N + 3) / 4, 256, 0, stream>>>(A, Bh, as3, wsd, als, ald, N);
  hipMemsetAsync(mbuf, 0, 2 * (size_t)N * 4 * 4, stream);
  edgeA_kernel<1><<<(E + 255) / 256, 256, 0, stream>>>(srcp, dstp, als, ald, ebuf, mbuf, E);
  edgeB_kernel<1><<<(E + 255) / 256, 256, 0, stream>>>(dstp, mbuf, ebuf, den, E);
  agg16_kernel<<<(N + 15) / 16, 256, 0, stream>>>(A, ebuf, den, offs, srcp, b3, (float*)d_out, N);
}

// Round 2
// 1091.072 us; speedup vs baseline: 1.1183x; 1.1183x over previous
//
#include <hip/hip_runtime.h>
#include <math.h>

#define NEG_SLOPE 0.2f
#define EPSF 1e-16f

typedef _Float16 h2v __attribute__((ext_vector_type(2)));
typedef _Float16 h4v __attribute__((ext_vector_type(4)));
typedef _Float16 h8v __attribute__((ext_vector_type(8)));
typedef float f4v __attribute__((ext_vector_type(4)));

#define AS1 __attribute__((address_space(1)))
#define AS3 __attribute__((address_space(3)))

__device__ __forceinline__ void gll16(const void* g, void* l) {
  __builtin_amdgcn_global_load_lds((AS1 void*)g, (AS3 void*)l, 16, 0, 0);
}

// ---------------- CSR build ----------------

__global__ void hist_kernel(const int* __restrict__ dst, int* __restrict__ counts, int E) {
  int t = blockIdx.x * 256 + threadIdx.x;
  if (t < E) atomicAdd(&counts[dst[t]], 1);
}

__global__ void scan1(const int* __restrict__ counts, int* __restrict__ offs,
                      int* __restrict__ bsum, int N) {
  __shared__ int sd[1024];
  int tid = threadIdx.x;
  int i = blockIdx.x * 1024 + tid;
  int v = (i < N) ? counts[i] : 0;
  sd[tid] = v;
  __syncthreads();
  for (int s = 1; s < 1024; s <<= 1) {
    int tv = (tid >= s) ? sd[tid - s] : 0;
    __syncthreads();
    sd[tid] += tv;
    __syncthreads();
  }
  if (i < N) offs[i] = sd[tid] - v;  // local exclusive
  if (tid == 1023) bsum[blockIdx.x] = sd[1023];
}

__global__ void scan2(int* __restrict__ bsum, int* __restrict__ offs, int nb, int N, int E) {
  if (threadIdx.x == 0) {
    int r = 0;
    for (int i = 0; i < nb; i++) { int v = bsum[i]; bsum[i] = r; r += v; }
    offs[N] = E;
  }
}

__global__ void scan3(int* __restrict__ offs, const int* __restrict__ bsum, int N) {
  int i = blockIdx.x * 1024 + threadIdx.x;
  if (i < N) offs[i] += bsum[blockIdx.x];
}

__global__ void scatter_kernel(const int* __restrict__ src, const int* __restrict__ dst,
                               const int* __restrict__ off, int* __restrict__ cur,
                               int* __restrict__ srcp, int E) {
  int t = blockIdx.x * 256 + threadIdx.x;
  if (t < E) {
    int d = dst[t];
    int p = off[d] + atomicAdd(&cur[d], 1);
    srcp[p] = src[t];
  }
}

// ---------------- fp32->f16 hi/lo converts ----------------

__global__ void convX(const float* __restrict__ x, _Float16* __restrict__ xh,
                      _Float16* __restrict__ xl, int n4) {
  int i = blockIdx.x * 256 + threadIdx.x;
  if (i >= n4) return;
  float4 v = ((const float4*)x)[i];
  h4v h, l;
  h[0] = (_Float16)v.x; l[0] = (_Float16)(v.x - (float)h[0]);
  h[1] = (_Float16)v.y; l[1] = (_Float16)(v.y - (float)h[1]);
  h[2] = (_Float16)v.z; l[2] = (_Float16)(v.z - (float)h[2]);
  h[3] = (_Float16)v.w; l[3] = (_Float16)(v.w - (float)h[3]);
  ((h4v*)xh)[i] = h;
  ((h4v*)xl)[i] = l;
}

// W [K][512] f32 -> Wt_hi/lo [512][K] f16 (transposed).  grid=512 blocks, block=K threads
__global__ void convW(const float* __restrict__ W, _Float16* __restrict__ Th,
                      _Float16* __restrict__ Tl) {
  int col = blockIdx.x;
  int k = threadIdx.x;
  int K = blockDim.x;
  float v = W[(size_t)k * 512 + col];
  _Float16 h = (_Float16)v;
  Th[(size_t)col * K + k] = h;
  Tl[(size_t)col * K + k] = (_Float16)(v - (float)h);
}

// ---------------- split-f16 MFMA GEMM: C[M,512] = A[M,K] @ B[K,512] ----------------
// A as (Ah+Al) f16 pair row-major; B as (Bh+Bl) f16 pair stored TRANSPOSED [512][K].
// 128x128 tile, BK=32, 4 waves (2x2), wave tile 64x64, mfma 16x16x32, 3-product split.
// LDS layout per array: [kg 0..3][idx 0..127] of 16B chunks -> conflict-free (2-way)
// AND global_load_lds-linear (wave w stages kg=w; chunk = w*128 + q*64 + lane).

template <int K>
__global__ __launch_bounds__(256) void gemm_f16(
    const _Float16* __restrict__ Ah, const _Float16* __restrict__ Al,
    const _Float16* __restrict__ Bh, const _Float16* __restrict__ Bl,
    _Float16* __restrict__ Ch, _Float16* __restrict__ Cl, int M) {
  __shared__ __align__(16) char sm[32768];  // Ah:0 Al:8192 Bh:16384 Bl:24576
  const int t = threadIdx.x;
  const int w = t >> 6, l = t & 63;
  const int wr = w >> 1, wc = w & 1;
  const int kg = l >> 4, rr = l & 15;
  const size_t tm = (size_t)blockIdx.x * 128;
  const size_t cn = (size_t)blockIdx.y * 128;

  f4v acc[4][4];
#pragma unroll
  for (int i = 0; i < 4; i++)
#pragma unroll
    for (int j = 0; j < 4; j++) acc[i][j] = (f4v){0.f, 0.f, 0.f, 0.f};

  for (int kt = 0; kt < K; kt += 32) {
    __syncthreads();
    {
      const size_t ko = (size_t)kt + w * 8;
      char* d0 = sm + (w * 128) * 16;
      char* d1 = sm + (w * 128 + 64) * 16;
      gll16(Ah + (tm + l) * K + ko,      d0);
      gll16(Ah + (tm + 64 + l) * K + ko, d1);
      gll16(Al + (tm + l) * K + ko,      d0 + 8192);
      gll16(Al + (tm + 64 + l) * K + ko, d1 + 8192);
      gll16(Bh + (cn + l) * K + ko,      d0 + 16384);
      gll16(Bh + (cn + 64 + l) * K + ko, d1 + 16384);
      gll16(Bl + (cn + l) * K + ko,      d0 + 24576);
      gll16(Bl + (cn + 64 + l) * K + ko, d1 + 24576);
    }
    __syncthreads();  // drains vmcnt (global_load_lds) per compiler barrier semantics

    h8v ah[4], alo[4], bh[4], blo[4];
#pragma unroll
    for (int i = 0; i < 4; i++) {
      int ca = kg * 128 + wr * 64 + i * 16 + rr;
      int cb = kg * 128 + wc * 64 + i * 16 + rr;
      ah[i]  = *(const h8v*)(sm + ca * 16);
      alo[i] = *(const h8v*)(sm + 8192 + ca * 16);
      bh[i]  = *(const h8v*)(sm + 16384 + cb * 16);
      blo[i] = *(const h8v*)(sm + 24576 + cb * 16);
    }
#pragma unroll
    for (int i = 0; i < 4; i++)
#pragma unroll
      for (int j = 0; j < 4; j++) {
        acc[i][j] = __builtin_amdgcn_mfma_f32_16x16x32_f16(ah[i],  bh[j],  acc[i][j], 0, 0, 0);
        acc[i][j] = __builtin_amdgcn_mfma_f32_16x16x32_f16(alo[i], bh[j],  acc[i][j], 0, 0, 0);
        acc[i][j] = __builtin_amdgcn_mfma_f32_16x16x32_f16(ah[i],  blo[j], acc[i][j], 0, 0, 0);
      }
  }

  // epilogue: C/D layout col=lane&15, row=(lane>>4)*4+reg
#pragma unroll
  for (int i = 0; i < 4; i++) {
    int row0 = wr * 64 + i * 16 + (l >> 4) * 4;
#pragma unroll
    for (int j = 0; j < 4; j++) {
      int col = wc * 64 + j * 16 + rr;
#pragma unroll
      for (int r = 0; r < 4; r++) {
        size_t row = tm + row0 + r;
        if (row < (size_t)M) {
          float v = acc[i][j][r];
          _Float16 hi = (_Float16)v;
          Ch[row * 512 + cn + col] = hi;
          Cl[row * 512 + cn + col] = (_Float16)(v - (float)hi);
        }
      }
    }
  }
}

// ---------------- skinny GEMM layer 3: C[M,16] = (Ah+Al)[M,512] @ B[512,16] ----------------

__global__ __launch_bounds__(256) void gemm_n16f(const _Float16* __restrict__ Ahh,
                                                 const _Float16* __restrict__ All,
                                                 const float* __restrict__ B,
                                                 float* __restrict__ C, int M) {
  __shared__ float WsL[512 * 16];
  for (int i = threadIdx.x * 4; i < 512 * 16; i += 1024)
    *(float4*)&WsL[i] = *(const float4*)&B[i];
  __syncthreads();
  int r = threadIdx.x >> 4, c = threadIdx.x & 15;
  int n = blockIdx.x * 16 + r;
  if (n >= M) return;
  float acc = 0.f;
  for (int k = 0; k < 512; k += 8) {
    h8v hh = *(const h8v*)&Ahh[(size_t)n * 512 + k];
    h8v hl = *(const h8v*)&All[(size_t)n * 512 + k];
#pragma unroll
    for (int j = 0; j < 8; j++)
      acc += ((float)hh[j] + (float)hl[j]) * WsL[(k + j) * 16 + c];
  }
  C[(size_t)n * 16 + c] = acc;
}

// ---------------- wsd[k][h] = sum_c Wd[k][h*C+c] * a_d[h][c] ----------------

__global__ void wsd_kernel(const float* __restrict__ Wd, const float* __restrict__ a_d,
                           float* __restrict__ wsd, int K, int H, int C) {
  int t = blockIdx.x * 256 + threadIdx.x;
  if (t >= K * H) return;
  int k = t / H, h = t % H;
  float s = 0.f;
  for (int c = 0; c < C; c++) s += Wd[(size_t)k * (H * C) + h * C + c] * a_d[h * C + c];
  wsd[k * H + h] = s;
}

// ---------------- attention logits (layers 1,2: H=4, 512-wide xs) ----------------

__global__ void al_f16(const _Float16* __restrict__ xh, const _Float16* __restrict__ xl,
                       const _Float16* __restrict__ ih, const _Float16* __restrict__ il,
                       const float* __restrict__ a_s, const float* __restrict__ wsd,
                       float* __restrict__ als, float* __restrict__ ald, int N, int K) {
  int wid = threadIdx.x >> 6, lane = threadIdx.x & 63;
  int n = blockIdx.x * 4 + wid;
  if (n >= N) return;
  h8v vh = *(const h8v*)&xh[(size_t)n * 512 + lane * 8];
  h8v vl = *(const h8v*)&xl[(size_t)n * 512 + lane * 8];
  float s = 0.f;
#pragma unroll
  for (int j = 0; j < 8; j++) s += ((float)vh[j] + (float)vl[j]) * a_s[lane * 8 + j];
  for (int o = 1; o < 16; o <<= 1) s += __shfl_xor(s, o);
  if (!(lane & 15)) als[n * 4 + (lane >> 4)] = s;

  float d0 = 0.f, d1 = 0.f, d2 = 0.f, d3 = 0.f;
  int k0 = lane * 8;
  if (k0 < K) {
    h8v qh = *(const h8v*)&ih[(size_t)n * K + k0];
    h8v ql = *(const h8v*)&il[(size_t)n * K + k0];
#pragma unroll
    for (int j = 0; j < 8; j++) {
      float xv = (float)qh[j] + (float)ql[j];
      float4 wv = *(const float4*)&wsd[(k0 + j) * 4];
      d0 += xv * wv.x; d1 += xv * wv.y; d2 += xv * wv.z; d3 += xv * wv.w;
    }
  }
  for (int o = 1; o < 64; o <<= 1) {
    d0 += __shfl_xor(d0, o); d1 += __shfl_xor(d1, o);
    d2 += __shfl_xor(d2, o); d3 += __shfl_xor(d3, o);
  }
  if (lane == 0) *(float4*)&ald[n * 4] = make_float4(d0, d1, d2, d3);
}

// layer 3 logits: H=1, xs3 f32 [N,16], xin = h pair
__global__ void al3_f16(const float* __restrict__ xs3, const _Float16* __restrict__ ih,
                        const _Float16* __restrict__ il, const float* __restrict__ as3,
                        const float* __restrict__ wsd, float* __restrict__ als,
                        float* __restrict__ ald, int N) {
  int wid = threadIdx.x >> 6, lane = threadIdx.x & 63;
  int n = blockIdx.x * 4 + wid;
  if (n >= N) return;
  float s = (lane < 16) ? xs3[(size_t)n * 16 + lane] * as3[lane] : 0.f;
  for (int o = 1; o < 16; o <<= 1) s += __shfl_xor(s, o);
  h8v qh = *(const h8v*)&ih[(size_t)n * 512 + lane * 8];
  h8v ql = *(const h8v*)&il[(size_t)n * 512 + lane * 8];
  float d = 0.f;
#pragma unroll
  for (int j = 0; j < 8; j++) d += ((float)qh[j] + (float)ql[j]) * wsd[lane * 8 + j];
  for (int o = 1; o < 64; o <<= 1) d += __shfl_xor(d, o);
  if (lane == 0) { als[n] = s; ald[n] = d; }
}

// ---------------- fused segment-softmax + aggregation (layers 1,2) ----------------
// one block per node; wave = head; 3 passes over the node's CSR edge list.

__global__ __launch_bounds__(256) void agg512f(
    const _Float16* __restrict__ xh, const _Float16* __restrict__ xl,
    const float* __restrict__ als, const float* __restrict__ ald,
    const int* __restrict__ off, const int* __restrict__ srcp,
    const float* __restrict__ bias,
    _Float16* __restrict__ oh, _Float16* __restrict__ ol, int N) {
  int n = blockIdx.x;
  int t = threadIdx.x;
  int h = t >> 6;
  float aldn = ald[n * 4 + h];
  int p0 = off[n], p1 = off[n + 1];

  float m = -1e30f;
  for (int p = p0; p < p1; p++) {
    float e = als[srcp[p] * 4 + h] + aldn;
    e = (e > 0.f) ? e : NEG_SLOPE * e;
    m = fmaxf(m, e);
  }
  float den = 0.f;
  for (int p = p0; p < p1; p++) {
    float e = als[srcp[p] * 4 + h] + aldn;
    e = (e > 0.f) ? e : NEG_SLOPE * e;
    den += __expf(e - m);
  }
  float rw = 1.f / (den + EPSF);
  float ax = 0.f, ay = 0.f;
  for (int p = p0; p < p1; p++) {
    int s = srcp[p];
    float e = als[s * 4 + h] + aldn;
    e = (e > 0.f) ? e : NEG_SLOPE * e;
    float wgt = __expf(e - m) * rw;
    h2v vh = *(const h2v*)&xh[(size_t)s * 512 + 2 * t];
    h2v vl = *(const h2v*)&xl[(size_t)s * 512 + 2 * t];
    ax += wgt * ((float)vh[0] + (float)vl[0]);
    ay += wgt * ((float)vh[1] + (float)vl[1]);
  }
  float2 b = *(const float2*)&bias[2 * t];
  ax = fmaxf(ax + b.x, 0.f);  // fused relu (layers 1,2 only)
  ay = fmaxf(ay + b.y, 0.f);
  _Float16 hx = (_Float16)ax, hy = (_Float16)ay;
  h2v wh, wl;
  wh[0] = hx; wh[1] = hy;
  wl[0] = (_Float16)(ax - (float)hx); wl[1] = (_Float16)(ay - (float)hy);
  *(h2v*)&oh[(size_t)n * 512 + 2 * t] = wh;
  *(h2v*)&ol[(size_t)n * 512 + 2 * t] = wl;
}

// layer 3: H=1, C=16, no relu, f32 out. 16 nodes per block.
__global__ void agg16f(const float* __restrict__ xs3, const float* __restrict__ als,
                       const float* __restrict__ ald, const int* __restrict__ off,
                       const int* __restrict__ srcp, const float* __restrict__ bias,
                       float* __restrict__ out, int N) {
  int g = threadIdx.x >> 4, c = threadIdx.x & 15;
  int n = blockIdx.x * 16 + g;
  if (n >= N) return;
  float aldn = ald[n];
  int p0 = off[n], p1 = off[n + 1];
  float m = -1e30f;
  for (int p = p0; p < p1; p++) {
    float e = als[srcp[p]] + aldn;
    e = (e > 0.f) ? e : NEG_SLOPE * e;
    m = fmaxf(m, e);
  }
  float den = 0.f;
  for (int p = p0; p < p1; p++) {
    float e = als[srcp[p]] + aldn;
    e = (e > 0.f) ? e : NEG_SLOPE * e;
    den += __expf(e - m);
  }
  float rw = 1.f / (den + EPSF);
  float acc = 0.f;
  for (int p = p0; p < p1; p++) {
    int s = srcp[p];
    float e = als[s] + aldn;
    e = (e > 0.f) ? e : NEG_SLOPE * e;
    acc += __expf(e - m) * rw * xs3[(size_t)s * 16 + c];
  }
  out[(size_t)n * 16 + c] = acc + bias[c];
}

// ---------------- launch ----------------

extern "C" void kernel_launch(void* const* d_in, const int* in_sizes, int n_in,
                              void* d_out, int out_size, void* d_ws, size_t ws_size,
                              hipStream_t stream) {
  const float* x   = (const float*)d_in[0];
  const int*   ei  = (const int*)d_in[1];
  const float* Ws1 = (const float*)d_in[2];
  const float* Wd1 = (const float*)d_in[3];
  const float* as1 = (const float*)d_in[4];
  const float* ad1 = (const float*)d_in[5];
  const float* b1  = (const float*)d_in[6];
  const float* Ws2 = (const float*)d_in[7];
  const float* Wd2 = (const float*)d_in[8];
  const float* as2 = (const float*)d_in[9];
  const float* ad2 = (const float*)d_in[10];
  const float* b2  = (const float*)d_in[11];
  const float* Ws3 = (const float*)d_in[12];
  const float* Wd3 = (const float*)d_in[13];
  const float* as3 = (const float*)d_in[14];
  const float* ad3 = (const float*)d_in[15];
  const float* b3  = (const float*)d_in[16];

  const int N = in_sizes[0] / 128;  // 50000
  const int E = in_sizes[1] / 2;    // 400000
  const int* src = ei;
  const int* dst = ei + E;

  // workspace layout (bytes), ~213 MB total; all offsets 16B-aligned
  char* w = (char*)d_ws;
  _Float16* xs_hi = (_Float16*)(w + 0);           // [N,512] f16
  _Float16* xs_lo = (_Float16*)(w + 51200000);
  _Float16* h_hi  = (_Float16*)(w + 102400000);   // [N,512] f16 (x hi/lo alias front)
  _Float16* h_lo  = (_Float16*)(w + 153600000);
  float*    als   = (float*)(w + 204800000);      // [N,4]
  float*    ald   = (float*)(w + 205600000);      // [N,4]
  float*    xs3   = (float*)(w + 206400000);      // [N,16] f32
  int*      counts= (int*)(w + 209600000);        // [N]
  int*      cur   = (int*)(w + 209800000);        // [N]
  int*      offs  = (int*)(w + 210000000);        // [N+1]
  int*      bsum  = (int*)(w + 210200192);        // [~49]
  int*      srcp  = (int*)(w + 210204288);        // [E]
  float*    wsd   = (float*)(w + 211804288);      // [512,4]
  _Float16* wt_hi = (_Float16*)(w + 211812480);   // [512,512] f16 (B^T)
  _Float16* wt_lo = (_Float16*)(w + 212336768);

  // ---- CSR build ----
  hipMemsetAsync(counts, 0, 2 * (size_t)N * 4, stream);  // counts + cur contiguous
  hist_kernel<<<(E + 255) / 256, 256, 0, stream>>>(dst, counts, E);
  int nb = (N + 1023) / 1024;
  scan1<<<nb, 1024, 0, stream>>>(counts, offs, bsum, N);
  scan2<<<1, 64, 0, stream>>>(bsum, offs, nb, N, E);
  scan3<<<nb, 1024, 0, stream>>>(offs, bsum, N);
  scatter_kernel<<<(E + 255) / 256, 256, 0, stream>>>(src, dst, offs, cur, srcp, E);

  dim3 ggrid((N + 127) / 128, 4);

  // ---- layer 1 (K=128) ----
  convX<<<(N * 128 / 4 + 255) / 256, 256, 0, stream>>>(x, h_hi, h_lo, N * 128 / 4);
  wsd_kernel<<<(128 * 4 + 255) / 256, 256, 0, stream>>>(Wd1, ad1, wsd, 128, 4, 128);
  convW<<<512, 128, 0, stream>>>(Ws1, wt_hi, wt_lo);
  gemm_f16<128><<<ggrid, 256, 0, stream>>>(h_hi, h_lo, wt_hi, wt_lo, xs_hi, xs_lo, N);
  al_f16<<<(N + 3) / 4, 256, 0, stream>>>(xs_hi, xs_lo, h_hi, h_lo, as1, wsd, als, ald, N, 128);
  agg512f<<<N, 256, 0, stream>>>(xs_hi, xs_lo, als, ald, offs, srcp, b1, h_hi, h_lo, N);

  // ---- layer 2 (K=512) ----
  wsd_kernel<<<(512 * 4 + 255) / 256, 256, 0, stream>>>(Wd2, ad2, wsd, 512, 4, 128);
  convW<<<512, 512, 0, stream>>>(Ws2, wt_hi, wt_lo);
  gemm_f16<512><<<ggrid, 256, 0, stream>>>(h_hi, h_lo, wt_hi, wt_lo, xs_hi, xs_lo, N);
  al_f16<<<(N + 3) / 4, 256, 0, stream>>>(xs_hi, xs_lo, h_hi, h_lo, as2, wsd, als, ald, N, 512);
  agg512f<<<N, 256, 0, stream>>>(xs_hi, xs_lo, als, ald, offs, srcp, b2, h_hi, h_lo, N);

  // ---- layer 3 (K=512, N=16, H=1) ----
  wsd_kernel<<<(512 + 255) / 256, 256, 0, stream>>>(Wd3, ad3, wsd, 512, 1, 16);
  gemm_n16f<<<(N + 15) / 16, 256, 0, stream>>>(h_hi, h_lo, Ws3, xs3, N);
  al3_f16<<<(N + 3) / 4, 256, 0, stream>>>(xs3, h_hi, h_lo, as3, wsd, als, ald, N);
  agg16f<<<(N + 15) / 16, 256, 0, stream>>>(xs3, als, ald, offs, srcp, b3, (float*)d_out, N);
}

// Round 3
// 830.601 us; speedup vs baseline: 1.4689x; 1.3136x over previous
//
#include <hip/hip_runtime.h>
#include <math.h>

#define NEG_SLOPE 0.2f
#define EPSF 1e-16f

typedef _Float16 h2v __attribute__((ext_vector_type(2)));
typedef _Float16 h4v __attribute__((ext_vector_type(4)));
typedef _Float16 h8v __attribute__((ext_vector_type(8)));
typedef float f4v __attribute__((ext_vector_type(4)));

#define AS1 __attribute__((address_space(1)))
#define AS3 __attribute__((address_space(3)))

__device__ __forceinline__ void gll16(const void* g, void* l) {
  __builtin_amdgcn_global_load_lds((AS1 void*)g, (AS3 void*)l, 16, 0, 0);
}

// ---------------- CSR build ----------------

__global__ void hist_kernel(const int* __restrict__ dst, int* __restrict__ counts, int E) {
  int t = blockIdx.x * 256 + threadIdx.x;
  if (t < E) atomicAdd(&counts[dst[t]], 1);
}

__global__ void scan1(const int* __restrict__ counts, int* __restrict__ offs,
                      int* __restrict__ bsum, int N) {
  __shared__ int sd[1024];
  int tid = threadIdx.x;
  int i = blockIdx.x * 1024 + tid;
  int v = (i < N) ? counts[i] : 0;
  sd[tid] = v;
  __syncthreads();
  for (int s = 1; s < 1024; s <<= 1) {
    int tv = (tid >= s) ? sd[tid - s] : 0;
    __syncthreads();
    sd[tid] += tv;
    __syncthreads();
  }
  if (i < N) offs[i] = sd[tid] - v;  // local exclusive
  if (tid == 1023) bsum[blockIdx.x] = sd[1023];
}

__global__ void scan2(int* __restrict__ bsum, int* __restrict__ offs, int nb, int N, int E) {
  if (threadIdx.x == 0) {
    int r = 0;
    for (int i = 0; i < nb; i++) { int v = bsum[i]; bsum[i] = r; r += v; }
    offs[N] = E;
  }
}

__global__ void scan3(int* __restrict__ offs, const int* __restrict__ bsum, int N) {
  int i = blockIdx.x * 1024 + threadIdx.x;
  if (i < N) offs[i] += bsum[blockIdx.x];
}

__global__ void scatter_kernel(const int* __restrict__ src, const int* __restrict__ dst,
                               const int* __restrict__ off, int* __restrict__ cur,
                               int* __restrict__ srcp, int E) {
  int t = blockIdx.x * 256 + threadIdx.x;
  if (t < E) {
    int d = dst[t];
    int p = off[d] + atomicAdd(&cur[d], 1);
    srcp[p] = src[t];
  }
}

// ---------------- fp32->f16 hi/lo converts ----------------

__global__ void convX(const float* __restrict__ x, _Float16* __restrict__ xh,
                      _Float16* __restrict__ xl, int n4) {
  int i = blockIdx.x * 256 + threadIdx.x;
  if (i >= n4) return;
  float4 v = ((const float4*)x)[i];
  h4v h, l;
  h[0] = (_Float16)v.x; l[0] = (_Float16)(v.x - (float)h[0]);
  h[1] = (_Float16)v.y; l[1] = (_Float16)(v.y - (float)h[1]);
  h[2] = (_Float16)v.z; l[2] = (_Float16)(v.z - (float)h[2]);
  h[3] = (_Float16)v.w; l[3] = (_Float16)(v.w - (float)h[3]);
  ((h4v*)xh)[i] = h;
  ((h4v*)xl)[i] = l;
}

// W [K][512] f32 -> Wt_hi/lo [512][K] f16 transposed, coalesced via LDS tile.
// grid (512/32, K/32), block (32,8)
__global__ void convW(const float* __restrict__ W, _Float16* __restrict__ Th,
                      _Float16* __restrict__ Tl, int K) {
  __shared__ float tile[32][33];
  int bx = blockIdx.x * 32;  // output-col base (N=512 dim)
  int by = blockIdx.y * 32;  // k base
  int tx = threadIdx.x, ty = threadIdx.y;
#pragma unroll
  for (int i = 0; i < 32; i += 8)
    tile[ty + i][tx] = W[(size_t)(by + ty + i) * 512 + bx + tx];
  __syncthreads();
#pragma unroll
  for (int i = 0; i < 32; i += 8) {
    float v = tile[tx][ty + i];  // = W[by+tx][bx+ty+i]
    _Float16 h = (_Float16)v;
    Th[(size_t)(bx + ty + i) * K + by + tx] = h;
    Tl[(size_t)(bx + ty + i) * K + by + tx] = (_Float16)(v - (float)h);
  }
}

// ---------------- split-f16 MFMA GEMM: C[M,512](f32) = A[M,K] @ B[K,512] ----------------
// A = (Ah+Al) f16 row-major; B = (Bh+Bl) f16 TRANSPOSED [512][K].
// 128x128 tile, BK=32, 4 waves (2x2), 16x16x32 mfma, 3-product split.

template <int K>
__global__ __launch_bounds__(256) void gemm_f16(
    const _Float16* __restrict__ Ah, const _Float16* __restrict__ Al,
    const _Float16* __restrict__ Bh, const _Float16* __restrict__ Bl,
    float* __restrict__ C, int M) {
  __shared__ __align__(16) char sm[32768];  // Ah:0 Al:8192 Bh:16384 Bl:24576
  const int t = threadIdx.x;
  const int w = t >> 6, l = t & 63;
  const int wr = w >> 1, wc = w & 1;
  const int kg = l >> 4, rr = l & 15;
  const size_t tm = (size_t)blockIdx.x * 128;
  const size_t cn = (size_t)blockIdx.y * 128;

  f4v acc[4][4];
#pragma unroll
  for (int i = 0; i < 4; i++)
#pragma unroll
    for (int j = 0; j < 4; j++) acc[i][j] = (f4v){0.f, 0.f, 0.f, 0.f};

  for (int kt = 0; kt < K; kt += 32) {
    __syncthreads();
    {
      const size_t ko = (size_t)kt + w * 8;
      char* d0 = sm + (w * 128) * 16;
      char* d1 = sm + (w * 128 + 64) * 16;
      gll16(Ah + (tm + l) * K + ko,      d0);
      gll16(Ah + (tm + 64 + l) * K + ko, d1);
      gll16(Al + (tm + l) * K + ko,      d0 + 8192);
      gll16(Al + (tm + 64 + l) * K + ko, d1 + 8192);
      gll16(Bh + (cn + l) * K + ko,      d0 + 16384);
      gll16(Bh + (cn + 64 + l) * K + ko, d1 + 16384);
      gll16(Bl + (cn + l) * K + ko,      d0 + 24576);
      gll16(Bl + (cn + 64 + l) * K + ko, d1 + 24576);
    }
    __syncthreads();

    h8v ah[4], alo[4], bh[4], blo[4];
#pragma unroll
    for (int i = 0; i < 4; i++) {
      int ca = kg * 128 + wr * 64 + i * 16 + rr;
      int cb = kg * 128 + wc * 64 + i * 16 + rr;
      ah[i]  = *(const h8v*)(sm + ca * 16);
      alo[i] = *(const h8v*)(sm + 8192 + ca * 16);
      bh[i]  = *(const h8v*)(sm + 16384 + cb * 16);
      blo[i] = *(const h8v*)(sm + 24576 + cb * 16);
    }
#pragma unroll
    for (int i = 0; i < 4; i++)
#pragma unroll
      for (int j = 0; j < 4; j++) {
        acc[i][j] = __builtin_amdgcn_mfma_f32_16x16x32_f16(ah[i],  bh[j],  acc[i][j], 0, 0, 0);
        acc[i][j] = __builtin_amdgcn_mfma_f32_16x16x32_f16(alo[i], bh[j],  acc[i][j], 0, 0, 0);
        acc[i][j] = __builtin_amdgcn_mfma_f32_16x16x32_f16(ah[i],  blo[j], acc[i][j], 0, 0, 0);
      }
  }

  // epilogue: C/D layout col=lane&15, row=(lane>>4)*4+reg; store f32
#pragma unroll
  for (int i = 0; i < 4; i++) {
    int row0 = wr * 64 + i * 16 + (l >> 4) * 4;
#pragma unroll
    for (int j = 0; j < 4; j++) {
      int col = wc * 64 + j * 16 + rr;
#pragma unroll
      for (int r = 0; r < 4; r++) {
        size_t row = tm + row0 + r;
        if (row < (size_t)M) C[row * 512 + cn + col] = acc[i][j][r];
      }
    }
  }
}

// ---------------- skinny GEMM layer 3: C[M,16] = (Ah+Al)[M,512] @ B[512,16] ----------------

__global__ __launch_bounds__(256) void gemm_n16f(const _Float16* __restrict__ Ahh,
                                                 const _Float16* __restrict__ All,
                                                 const float* __restrict__ B,
                                                 float* __restrict__ C, int M) {
  __shared__ float WsL[512 * 16];
  for (int i = threadIdx.x * 4; i < 512 * 16; i += 1024)
    *(float4*)&WsL[i] = *(const float4*)&B[i];
  __syncthreads();
  int r = threadIdx.x >> 4, c = threadIdx.x & 15;
  int n = blockIdx.x * 16 + r;
  if (n >= M) return;
  float acc = 0.f;
  for (int k = 0; k < 512; k += 8) {
    h8v hh = *(const h8v*)&Ahh[(size_t)n * 512 + k];
    h8v hl = *(const h8v*)&All[(size_t)n * 512 + k];
#pragma unroll
    for (int j = 0; j < 8; j++)
      acc += ((float)hh[j] + (float)hl[j]) * WsL[(k + j) * 16 + c];
  }
  C[(size_t)n * 16 + c] = acc;
}

// ---------------- wsd[k][h] = sum_c Wd[k][h*C+c] * a_d[h][c] (16 lanes per dot) ----------

__global__ void wsd_kernel(const float* __restrict__ Wd, const float* __restrict__ a_d,
                           float* __restrict__ wsd, int K, int H, int C) {
  int g = (blockIdx.x * 256 + threadIdx.x) >> 4;
  int l16 = threadIdx.x & 15;
  if (g >= K * H) return;
  int k = g / H, h = g - k * H;
  int ce = C >> 4;
  float s = 0.f;
  for (int j = 0; j < ce; j++) {
    int c = l16 * ce + j;
    s += Wd[(size_t)k * (H * C) + h * C + c] * a_d[h * C + c];
  }
#pragma unroll
  for (int o = 1; o < 16; o <<= 1) s += __shfl_xor(s, o);
  if (l16 == 0) wsd[k * H + h] = s;
}

// ---------------- attention logits (layers 1,2: H=4) ----------------
// xs now f32 [N,512]; xin = h hi/lo f16 pair [N,K]

__global__ void al_f16(const float* __restrict__ xs, const _Float16* __restrict__ ih,
                       const _Float16* __restrict__ il, const float* __restrict__ a_s,
                       const float* __restrict__ wsd, float* __restrict__ als,
                       float* __restrict__ ald, int N, int K) {
  int wid = threadIdx.x >> 6, lane = threadIdx.x & 63;
  int n = blockIdx.x * 4 + wid;
  if (n >= N) return;
  float4 v0 = *(const float4*)&xs[(size_t)n * 512 + lane * 8];
  float4 v1 = *(const float4*)&xs[(size_t)n * 512 + lane * 8 + 4];
  float4 a0 = *(const float4*)&a_s[lane * 8];
  float4 a1 = *(const float4*)&a_s[lane * 8 + 4];
  float s = v0.x * a0.x + v0.y * a0.y + v0.z * a0.z + v0.w * a0.w +
            v1.x * a1.x + v1.y * a1.y + v1.z * a1.z + v1.w * a1.w;
  for (int o = 1; o < 16; o <<= 1) s += __shfl_xor(s, o);
  if (!(lane & 15)) als[n * 4 + (lane >> 4)] = s;

  float d0 = 0.f, d1 = 0.f, d2 = 0.f, d3 = 0.f;
  int k0 = lane * 8;
  if (k0 < K) {
    h8v qh = *(const h8v*)&ih[(size_t)n * K + k0];
    h8v ql = *(const h8v*)&il[(size_t)n * K + k0];
#pragma unroll
    for (int j = 0; j < 8; j++) {
      float xv = (float)qh[j] + (float)ql[j];
      float4 wv = *(const float4*)&wsd[(k0 + j) * 4];
      d0 += xv * wv.x; d1 += xv * wv.y; d2 += xv * wv.z; d3 += xv * wv.w;
    }
  }
  for (int o = 1; o < 64; o <<= 1) {
    d0 += __shfl_xor(d0, o); d1 += __shfl_xor(d1, o);
    d2 += __shfl_xor(d2, o); d3 += __shfl_xor(d3, o);
  }
  if (lane == 0) *(float4*)&ald[n * 4] = make_float4(d0, d1, d2, d3);
}

// layer 3 logits: H=1
__global__ void al3_f16(const float* __restrict__ xs3, const _Float16* __restrict__ ih,
                        const _Float16* __restrict__ il, const float* __restrict__ as3,
                        const float* __restrict__ wsd, float* __restrict__ als,
                        float* __restrict__ ald, int N) {
  int wid = threadIdx.x >> 6, lane = threadIdx.x & 63;
  int n = blockIdx.x * 4 + wid;
  if (n >= N) return;
  float s = (lane < 16) ? xs3[(size_t)n * 16 + lane] * as3[lane] : 0.f;
  for (int o = 1; o < 16; o <<= 1) s += __shfl_xor(s, o);
  h8v qh = *(const h8v*)&ih[(size_t)n * 512 + lane * 8];
  h8v ql = *(const h8v*)&il[(size_t)n * 512 + lane * 8];
  float d = 0.f;
#pragma unroll
  for (int j = 0; j < 8; j++) d += ((float)qh[j] + (float)ql[j]) * wsd[lane * 8 + j];
  for (int o = 1; o < 64; o <<= 1) d += __shfl_xor(d, o);
  if (lane == 0) { als[n] = s; ald[n] = d; }
}

// ---------------- per-edge normalized softmax weights ----------------
// H=4: one wave per node. lane = e*4+h (e=edge slot 0..15, h=head).

__global__ void wgt4_kernel(const float* __restrict__ als, const float* __restrict__ ald,
                            const int* __restrict__ off, const int* __restrict__ srcp,
                            _Float16* __restrict__ wgt, int N) {
  int wid = threadIdx.x >> 6, lane = threadIdx.x & 63;
  int n = blockIdx.x * 4 + wid;
  if (n >= N) return;
  int h = lane & 3, e = lane >> 2;
  float aldn = ald[n * 4 + h];
  int p0 = off[n], deg = off[n + 1] - p0;
  if (deg == 0) return;
  float ev0 = -1e30f;
  if (e < deg) {
    float v = als[srcp[p0 + e] * 4 + h] + aldn;
    ev0 = (v > 0.f) ? v : NEG_SLOPE * v;
  }
  float m = ev0;
  for (int base = 16; base < deg; base += 16) {  // rare (deg>16)
    float ev = -1e30f;
    if (base + e < deg) {
      float v = als[srcp[p0 + base + e] * 4 + h] + aldn;
      ev = (v > 0.f) ? v : NEG_SLOPE * v;
    }
    m = fmaxf(m, ev);
  }
#pragma unroll
  for (int o = 4; o < 64; o <<= 1) m = fmaxf(m, __shfl_xor(m, o));
  float den = (e < deg) ? __expf(ev0 - m) : 0.f;
  for (int base = 16; base < deg; base += 16) {
    if (base + e < deg) {
      float v = als[srcp[p0 + base + e] * 4 + h] + aldn;
      v = (v > 0.f) ? v : NEG_SLOPE * v;
      den += __expf(v - m);
    }
  }
#pragma unroll
  for (int o = 4; o < 64; o <<= 1) den += __shfl_xor(den, o);
  float rw = 1.f / (den + EPSF);
  if (e < deg) wgt[(size_t)(p0 + e) * 4 + h] = (_Float16)(__expf(ev0 - m) * rw);
  for (int base = 16; base < deg; base += 16) {
    if (base + e < deg) {
      float v = als[srcp[p0 + base + e] * 4 + h] + aldn;
      v = (v > 0.f) ? v : NEG_SLOPE * v;
      wgt[(size_t)(p0 + base + e) * 4 + h] = (_Float16)(__expf(v - m) * rw);
    }
  }
}

// H=1: one wave per node, lane = edge slot (64 per chunk).
__global__ void wgt1_kernel(const float* __restrict__ als, const float* __restrict__ ald,
                            const int* __restrict__ off, const int* __restrict__ srcp,
                            _Float16* __restrict__ wgt, int N) {
  int wid = threadIdx.x >> 6, lane = threadIdx.x & 63;
  int n = blockIdx.x * 4 + wid;
  if (n >= N) return;
  float aldn = ald[n];
  int p0 = off[n], deg = off[n + 1] - p0;
  if (deg == 0) return;
  float ev0 = -1e30f;
  if (lane < deg) {
    float v = als[srcp[p0 + lane]] + aldn;
    ev0 = (v > 0.f) ? v : NEG_SLOPE * v;
  }
  float m = ev0;
  for (int base = 64; base < deg; base += 64) {
    float ev = -1e30f;
    if (base + lane < deg) {
      float v = als[srcp[p0 + base + lane]] + aldn;
      ev = (v > 0.f) ? v : NEG_SLOPE * v;
    }
    m = fmaxf(m, ev);
  }
#pragma unroll
  for (int o = 1; o < 64; o <<= 1) m = fmaxf(m, __shfl_xor(m, o));
  float den = (lane < deg) ? __expf(ev0 - m) : 0.f;
  for (int base = 64; base < deg; base += 64) {
    if (base + lane < deg) {
      float v = als[srcp[p0 + base + lane]] + aldn;
      v = (v > 0.f) ? v : NEG_SLOPE * v;
      den += __expf(v - m);
    }
  }
#pragma unroll
  for (int o = 1; o < 64; o <<= 1) den += __shfl_xor(den, o);
  float rw = 1.f / (den + EPSF);
  if (lane < deg) wgt[p0 + lane] = (_Float16)(__expf(ev0 - m) * rw);
  for (int base = 64; base < deg; base += 64) {
    if (base + lane < deg) {
      float v = als[srcp[p0 + base + lane]] + aldn;
      v = (v > 0.f) ? v : NEG_SLOPE * v;
      wgt[p0 + base + lane] = (_Float16)(__expf(v - m) * rw);
    }
  }
}

// ---------------- aggregation: single weighted-gather pass ----------------
// layers 1,2: one block per node, thread t handles channels 2t,2t+1.

__global__ __launch_bounds__(256) void agg512(
    const float* __restrict__ xs, const _Float16* __restrict__ wgt,
    const int* __restrict__ off, const int* __restrict__ srcp,
    const float* __restrict__ bias,
    _Float16* __restrict__ oh, _Float16* __restrict__ ol, int N) {
  int n = blockIdx.x;
  int t = threadIdx.x;
  int h = t >> 6;
  int p0 = off[n], p1 = off[n + 1];
  float ax = 0.f, ay = 0.f;
  for (int p = p0; p < p1; p++) {
    int s = srcp[p];
    float w = (float)wgt[(size_t)p * 4 + h];
    float2 v = *(const float2*)&xs[(size_t)s * 512 + 2 * t];
    ax += w * v.x; ay += w * v.y;
  }
  float2 b = *(const float2*)&bias[2 * t];
  ax = fmaxf(ax + b.x, 0.f);  // fused relu
  ay = fmaxf(ay + b.y, 0.f);
  _Float16 hx = (_Float16)ax, hy = (_Float16)ay;
  h2v wh, wl;
  wh[0] = hx; wh[1] = hy;
  wl[0] = (_Float16)(ax - (float)hx); wl[1] = (_Float16)(ay - (float)hy);
  *(h2v*)&oh[(size_t)n * 512 + 2 * t] = wh;
  *(h2v*)&ol[(size_t)n * 512 + 2 * t] = wl;
}

// layer 3: H=1, C=16, no relu, f32 out. 16 nodes per block.
__global__ void agg16(const float* __restrict__ xs3, const _Float16* __restrict__ wgt,
                      const int* __restrict__ off, const int* __restrict__ srcp,
                      const float* __restrict__ bias, float* __restrict__ out, int N) {
  int g = threadIdx.x >> 4, c = threadIdx.x & 15;
  int n = blockIdx.x * 16 + g;
  if (n >= N) return;
  int p0 = off[n], p1 = off[n + 1];
  float acc = 0.f;
  for (int p = p0; p < p1; p++)
    acc += (float)wgt[p] * xs3[(size_t)srcp[p] * 16 + c];
  out[(size_t)n * 16 + c] = acc + bias[c];
}

// ---------------- launch ----------------

extern "C" void kernel_launch(void* const* d_in, const int* in_sizes, int n_in,
                              void* d_out, int out_size, void* d_ws, size_t ws_size,
                              hipStream_t stream) {
  const float* x   = (const float*)d_in[0];
  const int*   ei  = (const int*)d_in[1];
  const float* Ws1 = (const float*)d_in[2];
  const float* Wd1 = (const float*)d_in[3];
  const float* as1 = (const float*)d_in[4];
  const float* ad1 = (const float*)d_in[5];
  const float* b1  = (const float*)d_in[6];
  const float* Ws2 = (const float*)d_in[7];
  const float* Wd2 = (const float*)d_in[8];
  const float* as2 = (const float*)d_in[9];
  const float* ad2 = (const float*)d_in[10];
  const float* b2  = (const float*)d_in[11];
  const float* Ws3 = (const float*)d_in[12];
  const float* Wd3 = (const float*)d_in[13];
  const float* as3 = (const float*)d_in[14];
  const float* ad3 = (const float*)d_in[15];
  const float* b3  = (const float*)d_in[16];

  const int N = in_sizes[0] / 128;  // 50000
  const int E = in_sizes[1] / 2;    // 400000
  const int* src = ei;
  const int* dst = ei + E;

  // workspace layout (bytes), total ~216.1 MB
  char* w = (char*)d_ws;
  float*    xs    = (float*)(w + 0);              // [N,512] f32
  _Float16* h_hi  = (_Float16*)(w + 102400000);   // [N,512] f16 (x_hi [N,128] early)
  _Float16* h_lo  = (_Float16*)(w + 153600000);
  float*    als   = (float*)(w + 204800000);      // [N,4]
  float*    ald   = (float*)(w + 205600000);      // [N,4]
  float*    xs3   = (float*)(w + 206400000);      // [N,16] f32
  _Float16* wgt   = (_Float16*)(w + 209600000);   // [E,4] f16
  int*      counts= (int*)(w + 212800000);        // [N]
  int*      cur   = (int*)(w + 213000000);        // [N]
  int*      offs  = (int*)(w + 213200000);        // [N+1]
  int*      bsum  = (int*)(w + 213400192);        // [~49]
  int*      srcp  = (int*)(w + 213404288);        // [E]
  float*    wsd   = (float*)(w + 215004288);      // [512,4]
  _Float16* wt_hi = (_Float16*)(w + 215012480);   // [512,512] f16 (B^T)
  _Float16* wt_lo = (_Float16*)(w + 215536768);

  // ---- CSR build ----
  hipMemsetAsync(counts, 0, 2 * (size_t)N * 4, stream);  // counts + cur contiguous
  hist_kernel<<<(E + 255) / 256, 256, 0, stream>>>(dst, counts, E);
  int nb = (N + 1023) / 1024;
  scan1<<<nb, 1024, 0, stream>>>(counts, offs, bsum, N);
  scan2<<<1, 64, 0, stream>>>(bsum, offs, nb, N, E);
  scan3<<<nb, 1024, 0, stream>>>(offs, bsum, N);
  scatter_kernel<<<(E + 255) / 256, 256, 0, stream>>>(src, dst, offs, cur, srcp, E);

  dim3 ggrid((N + 127) / 128, 4);
  dim3 cwb(32, 8);
  int nwb = (N + 3) / 4;

  // ---- layer 1 (K=128) ----
  convX<<<(N * 128 / 4 + 255) / 256, 256, 0, stream>>>(x, h_hi, h_lo, N * 128 / 4);
  wsd_kernel<<<(128 * 4 * 16 + 255) / 256, 256, 0, stream>>>(Wd1, ad1, wsd, 128, 4, 128);
  convW<<<dim3(16, 4), cwb, 0, stream>>>(Ws1, wt_hi, wt_lo, 128);
  gemm_f16<128><<<ggrid, 256, 0, stream>>>(h_hi, h_lo, wt_hi, wt_lo, xs, N);
  al_f16<<<nwb, 256, 0, stream>>>(xs, h_hi, h_lo, as1, wsd, als, ald, N, 128);
  wgt4_kernel<<<nwb, 256, 0, stream>>>(als, ald, offs, srcp, wgt, N);
  agg512<<<N, 256, 0, stream>>>(xs, wgt, offs, srcp, b1, h_hi, h_lo, N);

  // ---- layer 2 (K=512) ----
  wsd_kernel<<<(512 * 4 * 16 + 255) / 256, 256, 0, stream>>>(Wd2, ad2, wsd, 512, 4, 128);
  convW<<<dim3(16, 16), cwb, 0, stream>>>(Ws2, wt_hi, wt_lo, 512);
  gemm_f16<512><<<ggrid, 256, 0, stream>>>(h_hi, h_lo, wt_hi, wt_lo, xs, N);
  al_f16<<<nwb, 256, 0, stream>>>(xs, h_hi, h_lo, as2, wsd, als, ald, N, 512);
  wgt4_kernel<<<nwb, 256, 0, stream>>>(als, ald, offs, srcp, wgt, N);
  agg512<<<N, 256, 0, stream>>>(xs, wgt, offs, srcp, b2, h_hi, h_lo, N);

  // ---- layer 3 (K=512, N=16, H=1) ----
  wsd_kernel<<<(512 * 16 + 255) / 256, 256, 0, stream>>>(Wd3, ad3, wsd, 512, 1, 16);
  gemm_n16f<<<(N + 15) / 16, 256, 0, stream>>>(h_hi, h_lo, Ws3, xs3, N);
  al3_f16<<<nwb, 256, 0, stream>>>(xs3, h_hi, h_lo, as3, wsd, als, ald, N);
  wgt1_kernel<<<nwb, 256, 0, stream>>>(als, ald, offs, srcp, wgt, N);
  agg16<<<(N + 15) / 16, 256, 0, stream>>>(xs3, wgt, offs, srcp, b3, (float*)d_out, N);
}

// Round 4
// 749.455 us; speedup vs baseline: 1.6280x; 1.1083x over previous
//
#include <hip/hip_runtime.h>
#include <math.h>

#define NEG_SLOPE 0.2f
#define EPSF 1e-16f

typedef _Float16 h2v __attribute__((ext_vector_type(2)));
typedef _Float16 h4v __attribute__((ext_vector_type(4)));
typedef _Float16 h8v __attribute__((ext_vector_type(8)));
typedef float f4v __attribute__((ext_vector_type(4)));

#define AS1 __attribute__((address_space(1)))
#define AS3 __attribute__((address_space(3)))

__device__ __forceinline__ void gll16(const void* g, void* l) {
  __builtin_amdgcn_global_load_lds((AS1 void*)g, (AS3 void*)l, 16, 0, 0);
}

// ---------------- CSR build ----------------

__global__ void hist_kernel(const int* __restrict__ dst, int* __restrict__ counts, int E) {
  int t = blockIdx.x * 256 + threadIdx.x;
  if (t < E) atomicAdd(&counts[dst[t]], 1);
}

__global__ void scan1(const int* __restrict__ counts, int* __restrict__ offs,
                      int* __restrict__ bsum, int N) {
  __shared__ int sd[1024];
  int tid = threadIdx.x;
  int i = blockIdx.x * 1024 + tid;
  int v = (i < N) ? counts[i] : 0;
  sd[tid] = v;
  __syncthreads();
  for (int s = 1; s < 1024; s <<= 1) {
    int tv = (tid >= s) ? sd[tid - s] : 0;
    __syncthreads();
    sd[tid] += tv;
    __syncthreads();
  }
  if (i < N) offs[i] = sd[tid] - v;  // local exclusive
  if (tid == 1023) bsum[blockIdx.x] = sd[1023];
}

__global__ void scan2(int* __restrict__ bsum, int* __restrict__ offs, int nb, int N, int E) {
  if (threadIdx.x == 0) {
    int r = 0;
    for (int i = 0; i < nb; i++) { int v = bsum[i]; bsum[i] = r; r += v; }
    offs[N] = E;
  }
}

__global__ void scan3(int* __restrict__ offs, const int* __restrict__ bsum, int N) {
  int i = blockIdx.x * 1024 + threadIdx.x;
  if (i < N) offs[i] += bsum[blockIdx.x];
}

__global__ void scatter_kernel(const int* __restrict__ src, const int* __restrict__ dst,
                               const int* __restrict__ off, int* __restrict__ cur,
                               int* __restrict__ srcp, int E) {
  int t = blockIdx.x * 256 + threadIdx.x;
  if (t < E) {
    int d = dst[t];
    int p = off[d] + atomicAdd(&cur[d], 1);
    srcp[p] = src[t];
  }
}

// ---------------- fp32->f16 hi/lo converts ----------------

__global__ void convX(const float* __restrict__ x, _Float16* __restrict__ xh,
                      _Float16* __restrict__ xl, int n4) {
  int i = blockIdx.x * 256 + threadIdx.x;
  if (i >= n4) return;
  float4 v = ((const float4*)x)[i];
  h4v h, l;
  h[0] = (_Float16)v.x; l[0] = (_Float16)(v.x - (float)h[0]);
  h[1] = (_Float16)v.y; l[1] = (_Float16)(v.y - (float)h[1]);
  h[2] = (_Float16)v.z; l[2] = (_Float16)(v.z - (float)h[2]);
  h[3] = (_Float16)v.w; l[3] = (_Float16)(v.w - (float)h[3]);
  ((h4v*)xh)[i] = h;
  ((h4v*)xl)[i] = l;
}

// W [K][512] f32 -> Wt_hi/lo [512][K] f16 transposed, coalesced via LDS tile.
__global__ void convW(const float* __restrict__ W, _Float16* __restrict__ Th,
                      _Float16* __restrict__ Tl, int K) {
  __shared__ float tile[32][33];
  int bx = blockIdx.x * 32;  // output-col base (N=512 dim)
  int by = blockIdx.y * 32;  // k base
  int tx = threadIdx.x, ty = threadIdx.y;
#pragma unroll
  for (int i = 0; i < 32; i += 8)
    tile[ty + i][tx] = W[(size_t)(by + ty + i) * 512 + bx + tx];
  __syncthreads();
#pragma unroll
  for (int i = 0; i < 32; i += 8) {
    float v = tile[tx][ty + i];  // = W[by+tx][bx+ty+i]
    _Float16 h = (_Float16)v;
    Th[(size_t)(bx + ty + i) * K + by + tx] = h;
    Tl[(size_t)(bx + ty + i) * K + by + tx] = (_Float16)(v - (float)h);
  }
}

// Ws3 [512][16] -> Bt_hi/lo [16][512]
__global__ void convW3(const float* __restrict__ W, _Float16* __restrict__ Th,
                       _Float16* __restrict__ Tl) {
  int t = blockIdx.x * 256 + threadIdx.x;
  if (t >= 512 * 16) return;
  int k = t >> 4, c = t & 15;
  float v = W[t];
  _Float16 h = (_Float16)v;
  Th[c * 512 + k] = h;
  Tl[c * 512 + k] = (_Float16)(v - (float)h);
}

// ---------------- split-f16 MFMA GEMM, 2-phase double-buffered ----------------
// C[M,512](f16) = A[M,K] @ B[K,512]; A=(Ah+Al) row-major, B=(Bh+Bl) transposed [512][K].
// 128x128 tile, BK=32, 4 waves (2x2), 16x16x32 mfma, 3-product split.
// 1-D grid: bm = bid>>2, bn = bid&3 (col-tiles adjacent -> A-panel locality).

#define STAGE(bs, kt)                                  \
  do {                                                 \
    const size_t ko = (size_t)(kt) + w * 8;            \
    char* d0 = sm + (bs) + (w * 128) * 16;             \
    char* d1 = d0 + 1024;                              \
    gll16(Ah + (tm + l) * K + ko,      d0);            \
    gll16(Ah + (tm + 64 + l) * K + ko, d1);            \
    gll16(Al + (tm + l) * K + ko,      d0 + 8192);     \
    gll16(Al + (tm + 64 + l) * K + ko, d1 + 8192);     \
    gll16(Bh + (cn + l) * K + ko,      d0 + 16384);    \
    gll16(Bh + (cn + 64 + l) * K + ko, d1 + 16384);    \
    gll16(Bl + (cn + l) * K + ko,      d0 + 24576);    \
    gll16(Bl + (cn + 64 + l) * K + ko, d1 + 24576);    \
  } while (0)

template <int K>
__global__ __launch_bounds__(256) void gemm_f16(
    const _Float16* __restrict__ Ah, const _Float16* __restrict__ Al,
    const _Float16* __restrict__ Bh, const _Float16* __restrict__ Bl,
    _Float16* __restrict__ C, int M) {
  __shared__ __align__(16) char sm[65536];  // 2 x 32KB: Ah:0 Al:8192 Bh:16384 Bl:24576
  const int t = threadIdx.x;
  const int w = t >> 6, l = t & 63;
  const int wr = w >> 1, wc = w & 1;
  const int kg = l >> 4, rr = l & 15;
  const int bid = blockIdx.x;
  const size_t tm = (size_t)(bid >> 2) * 128;
  const size_t cn = (size_t)(bid & 3) * 128;

  f4v acc[4][4];
#pragma unroll
  for (int i = 0; i < 4; i++)
#pragma unroll
    for (int j = 0; j < 4; j++) acc[i][j] = (f4v){0.f, 0.f, 0.f, 0.f};

  STAGE(0, 0);
  __syncthreads();  // vmcnt(0)+lgkmcnt(0)+barrier (compiler-inserted drain)
  int cur = 0;

  for (int kt = 0; kt < K; kt += 32) {
    if (kt + 32 < K) STAGE(cur ^ 32768, kt + 32);  // prefetch next tile (in flight over MFMA)

    const char* base = sm + cur;
    h8v ah[4], alo[4], bh[4], blo[4];
#pragma unroll
    for (int i = 0; i < 4; i++) {
      int ca = (kg * 128 + wr * 64 + i * 16 + rr) * 16;
      int cb = (kg * 128 + wc * 64 + i * 16 + rr) * 16;
      ah[i]  = *(const h8v*)(base + ca);
      alo[i] = *(const h8v*)(base + 8192 + ca);
      bh[i]  = *(const h8v*)(base + 16384 + cb);
      blo[i] = *(const h8v*)(base + 24576 + cb);
    }
#pragma unroll
    for (int i = 0; i < 4; i++)
#pragma unroll
      for (int j = 0; j < 4; j++) {
        acc[i][j] = __builtin_amdgcn_mfma_f32_16x16x32_f16(ah[i],  bh[j],  acc[i][j], 0, 0, 0);
        acc[i][j] = __builtin_amdgcn_mfma_f32_16x16x32_f16(alo[i], bh[j],  acc[i][j], 0, 0, 0);
        acc[i][j] = __builtin_amdgcn_mfma_f32_16x16x32_f16(ah[i],  blo[j], acc[i][j], 0, 0, 0);
      }
    __syncthreads();  // drains next-tile vmcnt + barriers buffer swap
    cur ^= 32768;
  }

  // epilogue: C/D layout col=lane&15, row=(lane>>4)*4+reg; store f16
#pragma unroll
  for (int i = 0; i < 4; i++) {
    int row0 = wr * 64 + i * 16 + (l >> 4) * 4;
#pragma unroll
    for (int j = 0; j < 4; j++) {
      int col = wc * 64 + j * 16 + rr;
#pragma unroll
      for (int r = 0; r < 4; r++) {
        size_t row = tm + row0 + r;
        if (row < (size_t)M) C[row * 512 + cn + col] = (_Float16)acc[i][j][r];
      }
    }
  }
}

// ---------------- layer-3 projection via MFMA: C[M,16](f32) = A[M,512] @ B[512,16] -------
// one wave per 16-row tile; B pre-transposed hi/lo [16][512].

__global__ __launch_bounds__(256) void gemm3(const _Float16* __restrict__ Ah,
                                             const _Float16* __restrict__ Al,
                                             const _Float16* __restrict__ Bth,
                                             const _Float16* __restrict__ Btl,
                                             float* __restrict__ C, int M) {
  int wv = threadIdx.x >> 6, l = threadIdx.x & 63;
  size_t tm = ((size_t)blockIdx.x * 4 + wv) * 16;
  if (tm >= (size_t)M) return;
  int rr = l & 15, kg = l >> 4;
  f4v acc = (f4v){0.f, 0.f, 0.f, 0.f};
  for (int kt = 0; kt < 512; kt += 32) {
    int ka = kt + kg * 8;
    h8v a_h = *(const h8v*)&Ah[(tm + rr) * 512 + ka];
    h8v a_l = *(const h8v*)&Al[(tm + rr) * 512 + ka];
    h8v b_h = *(const h8v*)&Bth[rr * 512 + ka];
    h8v b_l = *(const h8v*)&Btl[rr * 512 + ka];
    acc = __builtin_amdgcn_mfma_f32_16x16x32_f16(a_h, b_h, acc, 0, 0, 0);
    acc = __builtin_amdgcn_mfma_f32_16x16x32_f16(a_l, b_h, acc, 0, 0, 0);
    acc = __builtin_amdgcn_mfma_f32_16x16x32_f16(a_h, b_l, acc, 0, 0, 0);
  }
#pragma unroll
  for (int r = 0; r < 4; r++) {
    size_t row = tm + kg * 4 + r;
    if (row < (size_t)M) C[row * 16 + rr] = acc[r];
  }
}

// ---------------- wsd[k][h] = sum_c Wd[k][h*C+c] * a_d[h][c] ----------------

__global__ void wsd_kernel(const float* __restrict__ Wd, const float* __restrict__ a_d,
                           float* __restrict__ wsd, int K, int H, int C) {
  int g = (blockIdx.x * 256 + threadIdx.x) >> 4;
  int l16 = threadIdx.x & 15;
  if (g >= K * H) return;
  int k = g / H, h = g - k * H;
  int ce = C >> 4;
  float s = 0.f;
  for (int j = 0; j < ce; j++) {
    int c = l16 * ce + j;
    s += Wd[(size_t)k * (H * C) + h * C + c] * a_d[h * C + c];
  }
#pragma unroll
  for (int o = 1; o < 16; o <<= 1) s += __shfl_xor(s, o);
  if (l16 == 0) wsd[k * H + h] = s;
}

// ---------------- attention logits (layers 1,2: H=4) ----------------
// xs f16 [N,512]; xin = h hi/lo f16 pair [N,K]

__global__ void al_f16(const _Float16* __restrict__ xs, const _Float16* __restrict__ ih,
                       const _Float16* __restrict__ il, const float* __restrict__ a_s,
                       const float* __restrict__ wsd, float* __restrict__ als,
                       float* __restrict__ ald, int N, int K) {
  int wid = threadIdx.x >> 6, lane = threadIdx.x & 63;
  int n = blockIdx.x * 4 + wid;
  if (n >= N) return;
  h8v vx = *(const h8v*)&xs[(size_t)n * 512 + lane * 8];
  float s = 0.f;
#pragma unroll
  for (int j = 0; j < 8; j++) s += (float)vx[j] * a_s[lane * 8 + j];
  for (int o = 1; o < 16; o <<= 1) s += __shfl_xor(s, o);
  if (!(lane & 15)) als[n * 4 + (lane >> 4)] = s;

  float d0 = 0.f, d1 = 0.f, d2 = 0.f, d3 = 0.f;
  int k0 = lane * 8;
  if (k0 < K) {
    h8v qh = *(const h8v*)&ih[(size_t)n * K + k0];
    h8v ql = *(const h8v*)&il[(size_t)n * K + k0];
#pragma unroll
    for (int j = 0; j < 8; j++) {
      float xv = (float)qh[j] + (float)ql[j];
      float4 wv = *(const float4*)&wsd[(k0 + j) * 4];
      d0 += xv * wv.x; d1 += xv * wv.y; d2 += xv * wv.z; d3 += xv * wv.w;
    }
  }
  for (int o = 1; o < 64; o <<= 1) {
    d0 += __shfl_xor(d0, o); d1 += __shfl_xor(d1, o);
    d2 += __shfl_xor(d2, o); d3 += __shfl_xor(d3, o);
  }
  if (lane == 0) *(float4*)&ald[n * 4] = make_float4(d0, d1, d2, d3);
}

// layer 3 logits: H=1
__global__ void al3_f16(const float* __restrict__ xs3, const _Float16* __restrict__ ih,
                        const _Float16* __restrict__ il, const float* __restrict__ as3,
                        const float* __restrict__ wsd, float* __restrict__ als,
                        float* __restrict__ ald, int N) {
  int wid = threadIdx.x >> 6, lane = threadIdx.x & 63;
  int n = blockIdx.x * 4 + wid;
  if (n >= N) return;
  float s = (lane < 16) ? xs3[(size_t)n * 16 + lane] * as3[lane] : 0.f;
  for (int o = 1; o < 16; o <<= 1) s += __shfl_xor(s, o);
  h8v qh = *(const h8v*)&ih[(size_t)n * 512 + lane * 8];
  h8v ql = *(const h8v*)&il[(size_t)n * 512 + lane * 8];
  float d = 0.f;
#pragma unroll
  for (int j = 0; j < 8; j++) d += ((float)qh[j] + (float)ql[j]) * wsd[lane * 8 + j];
  for (int o = 1; o < 64; o <<= 1) d += __shfl_xor(d, o);
  if (lane == 0) { als[n] = s; ald[n] = d; }
}

// ---------------- per-edge normalized softmax weights ----------------
// H=4: one wave per node. lane = e*4+h.

__global__ void wgt4_kernel(const float* __restrict__ als, const float* __restrict__ ald,
                            const int* __restrict__ off, const int* __restrict__ srcp,
                            _Float16* __restrict__ wgt, int N) {
  int wid = threadIdx.x >> 6, lane = threadIdx.x & 63;
  int n = blockIdx.x * 4 + wid;
  if (n >= N) return;
  int h = lane & 3, e = lane >> 2;
  float aldn = ald[n * 4 + h];
  int p0 = off[n], deg = off[n + 1] - p0;
  if (deg == 0) return;
  float ev0 = -1e30f;
  if (e < deg) {
    float v = als[srcp[p0 + e] * 4 + h] + aldn;
    ev0 = (v > 0.f) ? v : NEG_SLOPE * v;
  }
  float m = ev0;
  for (int base = 16; base < deg; base += 16) {
    float ev = -1e30f;
    if (base + e < deg) {
      float v = als[srcp[p0 + base + e] * 4 + h] + aldn;
      ev = (v > 0.f) ? v : NEG_SLOPE * v;
    }
    m = fmaxf(m, ev);
  }
#pragma unroll
  for (int o = 4; o < 64; o <<= 1) m = fmaxf(m, __shfl_xor(m, o));
  float den = (e < deg) ? __expf(ev0 - m) : 0.f;
  for (int base = 16; base < deg; base += 16) {
    if (base + e < deg) {
      float v = als[srcp[p0 + base + e] * 4 + h] + aldn;
      v = (v > 0.f) ? v : NEG_SLOPE * v;
      den += __expf(v - m);
    }
  }
#pragma unroll
  for (int o = 4; o < 64; o <<= 1) den += __shfl_xor(den, o);
  float rw = 1.f / (den + EPSF);
  if (e < deg) wgt[(size_t)(p0 + e) * 4 + h] = (_Float16)(__expf(ev0 - m) * rw);
  for (int base = 16; base < deg; base += 16) {
    if (base + e < deg) {
      float v = als[srcp[p0 + base + e] * 4 + h] + aldn;
      v = (v > 0.f) ? v : NEG_SLOPE * v;
      wgt[(size_t)(p0 + base + e) * 4 + h] = (_Float16)(__expf(v - m) * rw);
    }
  }
}

// H=1: one wave per node, lane = edge slot.
__global__ void wgt1_kernel(const float* __restrict__ als, const float* __restrict__ ald,
                            const int* __restrict__ off, const int* __restrict__ srcp,
                            _Float16* __restrict__ wgt, int N) {
  int wid = threadIdx.x >> 6, lane = threadIdx.x & 63;
  int n = blockIdx.x * 4 + wid;
  if (n >= N) return;
  float aldn = ald[n];
  int p0 = off[n], deg = off[n + 1] - p0;
  if (deg == 0) return;
  float ev0 = -1e30f;
  if (lane < deg) {
    float v = als[srcp[p0 + lane]] + aldn;
    ev0 = (v > 0.f) ? v : NEG_SLOPE * v;
  }
  float m = ev0;
  for (int base = 64; base < deg; base += 64) {
    float ev = -1e30f;
    if (base + lane < deg) {
      float v = als[srcp[p0 + base + lane]] + aldn;
      ev = (v > 0.f) ? v : NEG_SLOPE * v;
    }
    m = fmaxf(m, ev);
  }
#pragma unroll
  for (int o = 1; o < 64; o <<= 1) m = fmaxf(m, __shfl_xor(m, o));
  float den = (lane < deg) ? __expf(ev0 - m) : 0.f;
  for (int base = 64; base < deg; base += 64) {
    if (base + lane < deg) {
      float v = als[srcp[p0 + base + lane]] + aldn;
      v = (v > 0.f) ? v : NEG_SLOPE * v;
      den += __expf(v - m);
    }
  }
#pragma unroll
  for (int o = 1; o < 64; o <<= 1) den += __shfl_xor(den, o);
  float rw = 1.f / (den + EPSF);
  if (lane < deg) wgt[p0 + lane] = (_Float16)(__expf(ev0 - m) * rw);
  for (int base = 64; base < deg; base += 64) {
    if (base + lane < deg) {
      float v = als[srcp[p0 + base + lane]] + aldn;
      v = (v > 0.f) ? v : NEG_SLOPE * v;
      wgt[p0 + base + lane] = (_Float16)(__expf(v - m) * rw);
    }
  }
}

// ---------------- aggregation: single weighted-gather pass ----------------
// layers 1,2: one block per node, thread t handles channels 2t,2t+1. xs f16.

__global__ __launch_bounds__(256) void agg512(
    const _Float16* __restrict__ xs, const _Float16* __restrict__ wgt,
    const int* __restrict__ off, const int* __restrict__ srcp,
    const float* __restrict__ bias,
    _Float16* __restrict__ oh, _Float16* __restrict__ ol, int N) {
  int n = blockIdx.x;
  int t = threadIdx.x;
  int h = t >> 6;
  int p0 = off[n], p1 = off[n + 1];
  float ax = 0.f, ay = 0.f;
  for (int p = p0; p < p1; p++) {
    int s = srcp[p];
    float w = (float)wgt[(size_t)p * 4 + h];
    h2v v = *(const h2v*)&xs[(size_t)s * 512 + 2 * t];
    ax += w * (float)v[0]; ay += w * (float)v[1];
  }
  float2 b = *(const float2*)&bias[2 * t];
  ax = fmaxf(ax + b.x, 0.f);  // fused relu
  ay = fmaxf(ay + b.y, 0.f);
  _Float16 hx = (_Float16)ax, hy = (_Float16)ay;
  h2v wh, wl;
  wh[0] = hx; wh[1] = hy;
  wl[0] = (_Float16)(ax - (float)hx); wl[1] = (_Float16)(ay - (float)hy);
  *(h2v*)&oh[(size_t)n * 512 + 2 * t] = wh;
  *(h2v*)&ol[(size_t)n * 512 + 2 * t] = wl;
}

// layer 3: H=1, C=16, no relu, f32 out. 16 nodes per block.
__global__ void agg16(const float* __restrict__ xs3, const _Float16* __restrict__ wgt,
                      const int* __restrict__ off, const int* __restrict__ srcp,
                      const float* __restrict__ bias, float* __restrict__ out, int N) {
  int g = threadIdx.x >> 4, c = threadIdx.x & 15;
  int n = blockIdx.x * 16 + g;
  if (n >= N) return;
  int p0 = off[n], p1 = off[n + 1];
  float acc = 0.f;
  for (int p = p0; p < p1; p++)
    acc += (float)wgt[p] * xs3[(size_t)srcp[p] * 16 + c];
  out[(size_t)n * 16 + c] = acc + bias[c];
}

// ---------------- launch ----------------

extern "C" void kernel_launch(void* const* d_in, const int* in_sizes, int n_in,
                              void* d_out, int out_size, void* d_ws, size_t ws_size,
                              hipStream_t stream) {
  const float* x   = (const float*)d_in[0];
  const int*   ei  = (const int*)d_in[1];
  const float* Ws1 = (const float*)d_in[2];
  const float* Wd1 = (const float*)d_in[3];
  const float* as1 = (const float*)d_in[4];
  const float* ad1 = (const float*)d_in[5];
  const float* b1  = (const float*)d_in[6];
  const float* Ws2 = (const float*)d_in[7];
  const float* Wd2 = (const float*)d_in[8];
  const float* as2 = (const float*)d_in[9];
  const float* ad2 = (const float*)d_in[10];
  const float* b2  = (const float*)d_in[11];
  const float* Ws3 = (const float*)d_in[12];
  const float* Wd3 = (const float*)d_in[13];
  const float* as3 = (const float*)d_in[14];
  const float* ad3 = (const float*)d_in[15];
  const float* b3  = (const float*)d_in[16];

  const int N = in_sizes[0] / 128;  // 50000
  const int E = in_sizes[1] / 2;    // 400000
  const int* src = ei;
  const int* dst = ei + E;

  // workspace layout (bytes), total ~165 MB; all offsets 16B-aligned
  char* w = (char*)d_ws;
  _Float16* xs     = (_Float16*)(w + 0);           // [N,512] f16
  _Float16* h_hi   = (_Float16*)(w + 51200000);    // [N,512] f16 ([N,128] x_hi early)
  _Float16* h_lo   = (_Float16*)(w + 102400000);
  float*    als    = (float*)(w + 153600000);      // [N,4]
  float*    ald    = (float*)(w + 154400000);      // [N,4]
  float*    xs3    = (float*)(w + 155200000);      // [N,16] f32
  _Float16* wgt    = (_Float16*)(w + 158400000);   // [E,4] f16
  int*      counts = (int*)(w + 161600000);        // [N]
  int*      cur    = (int*)(w + 161800000);        // [N]
  int*      offs   = (int*)(w + 162000000);        // [N+1]
  int*      bsum   = (int*)(w + 162200192);        // [~49]
  int*      srcp   = (int*)(w + 162204288);        // [E]
  float*    wsd    = (float*)(w + 163804288);      // [512,4]
  _Float16* wt_hi  = (_Float16*)(w + 163812480);   // [512,512] f16 (B^T)
  _Float16* wt_lo  = (_Float16*)(w + 164336768);
  _Float16* wt3_hi = (_Float16*)(w + 164861056);   // [16,512] f16
  _Float16* wt3_lo = (_Float16*)(w + 164877440);

  // ---- CSR build ----
  hipMemsetAsync(counts, 0, 2 * (size_t)N * 4, stream);  // counts + cur contiguous
  hist_kernel<<<(E + 255) / 256, 256, 0, stream>>>(dst, counts, E);
  int nb = (N + 1023) / 1024;
  scan1<<<nb, 1024, 0, stream>>>(counts, offs, bsum, N);
  scan2<<<1, 64, 0, stream>>>(bsum, offs, nb, N, E);
  scan3<<<nb, 1024, 0, stream>>>(offs, bsum, N);
  scatter_kernel<<<(E + 255) / 256, 256, 0, stream>>>(src, dst, offs, cur, srcp, E);

  int ggrid = ((N + 127) / 128) * 4;  // 1-D: bm=bid>>2, bn=bid&3
  dim3 cwb(32, 8);
  int nwb = (N + 3) / 4;

  // ---- layer 1 (K=128) ----
  convX<<<(N * 128 / 4 + 255) / 256, 256, 0, stream>>>(x, h_hi, h_lo, N * 128 / 4);
  wsd_kernel<<<(128 * 4 * 16 + 255) / 256, 256, 0, stream>>>(Wd1, ad1, wsd, 128, 4, 128);
  convW<<<dim3(16, 4), cwb, 0, stream>>>(Ws1, wt_hi, wt_lo, 128);
  gemm_f16<128><<<ggrid, 256, 0, stream>>>(h_hi, h_lo, wt_hi, wt_lo, xs, N);
  al_f16<<<nwb, 256, 0, stream>>>(xs, h_hi, h_lo, as1, wsd, als, ald, N, 128);
  wgt4_kernel<<<nwb, 256, 0, stream>>>(als, ald, offs, srcp, wgt, N);
  agg512<<<N, 256, 0, stream>>>(xs, wgt, offs, srcp, b1, h_hi, h_lo, N);

  // ---- layer 2 (K=512) ----
  wsd_kernel<<<(512 * 4 * 16 + 255) / 256, 256, 0, stream>>>(Wd2, ad2, wsd, 512, 4, 128);
  convW<<<dim3(16, 16), cwb, 0, stream>>>(Ws2, wt_hi, wt_lo, 512);
  gemm_f16<512><<<ggrid, 256, 0, stream>>>(h_hi, h_lo, wt_hi, wt_lo, xs, N);
  al_f16<<<nwb, 256, 0, stream>>>(xs, h_hi, h_lo, as2, wsd, als, ald, N, 512);
  wgt4_kernel<<<nwb, 256, 0, stream>>>(als, ald, offs, srcp, wgt, N);
  agg512<<<N, 256, 0, stream>>>(xs, wgt, offs, srcp, b2, h_hi, h_lo, N);

  // ---- layer 3 (K=512, N=16, H=1) ----
  wsd_kernel<<<(512 * 16 + 255) / 256, 256, 0, stream>>>(Wd3, ad3, wsd, 512, 1, 16);
  convW3<<<32, 256, 0, stream>>>(Ws3, wt3_hi, wt3_lo);
  gemm3<<<(N / 16 + 4) / 4, 256, 0, stream>>>(h_hi, h_lo, wt3_hi, wt3_lo, xs3, N);
  al3_f16<<<nwb, 256, 0, stream>>>(xs3, h_hi, h_lo, as3, wsd, als, ald, N);
  wgt1_kernel<<<nwb, 256, 0, stream>>>(als, ald, offs, srcp, wgt, N);
  agg16<<<(N + 15) / 16, 256, 0, stream>>>(xs3, wgt, offs, srcp, b3, (float*)d_out, N);
}

// Round 6
// 677.944 us; speedup vs baseline: 1.7997x; 1.1055x over previous
//
#include <hip/hip_runtime.h>
#include <math.h>

#define NEG_SLOPE 0.2f
#define EPSF 1e-16f

typedef _Float16 h2v __attribute__((ext_vector_type(2)));
typedef _Float16 h4v __attribute__((ext_vector_type(4)));
typedef _Float16 h8v __attribute__((ext_vector_type(8)));
typedef float f4v __attribute__((ext_vector_type(4)));

#define AS1 __attribute__((address_space(1)))
#define AS3 __attribute__((address_space(3)))

__device__ __forceinline__ void gll16(const void* g, void* l) {
  __builtin_amdgcn_global_load_lds((AS1 void*)g, (AS3 void*)l, 16, 0, 0);
}

// ---------------- CSR build ----------------

__global__ void hist_kernel(const int* __restrict__ dst, int* __restrict__ counts, int E) {
  int t = blockIdx.x * 256 + threadIdx.x;
  if (t < E) atomicAdd(&counts[dst[t]], 1);
}

__global__ void scan1(const int* __restrict__ counts, int* __restrict__ offs,
                      int* __restrict__ bsum, int N) {
  __shared__ int sd[1024];
  int tid = threadIdx.x;
  int i = blockIdx.x * 1024 + tid;
  int v = (i < N) ? counts[i] : 0;
  sd[tid] = v;
  __syncthreads();
  for (int s = 1; s < 1024; s <<= 1) {
    int tv = (tid >= s) ? sd[tid - s] : 0;
    __syncthreads();
    sd[tid] += tv;
    __syncthreads();
  }
  if (i < N) offs[i] = sd[tid] - v;  // local exclusive
  if (tid == 1023) bsum[blockIdx.x] = sd[1023];
}

__global__ void scan2(int* __restrict__ bsum, int* __restrict__ offs, int nb, int N, int E) {
  if (threadIdx.x == 0) {
    int r = 0;
    for (int i = 0; i < nb; i++) { int v = bsum[i]; bsum[i] = r; r += v; }
    offs[N] = E;
  }
}

__global__ void scan3(int* __restrict__ offs, const int* __restrict__ bsum, int N) {
  int i = blockIdx.x * 1024 + threadIdx.x;
  if (i < N) offs[i] += bsum[blockIdx.x];
}

__global__ void scatter_kernel(const int* __restrict__ src, const int* __restrict__ dst,
                               const int* __restrict__ off, int* __restrict__ cur,
                               int* __restrict__ srcp, int E) {
  int t = blockIdx.x * 256 + threadIdx.x;
  if (t < E) {
    int d = dst[t];
    int p = off[d] + atomicAdd(&cur[d], 1);
    srcp[p] = src[t];
  }
}

// ---------------- fp32->f16 hi/lo converts ----------------

__global__ void convX(const float* __restrict__ x, _Float16* __restrict__ xh,
                      _Float16* __restrict__ xl, int n4) {
  int i = blockIdx.x * 256 + threadIdx.x;
  if (i >= n4) return;
  float4 v = ((const float4*)x)[i];
  h4v h, l;
  h[0] = (_Float16)v.x; l[0] = (_Float16)(v.x - (float)h[0]);
  h[1] = (_Float16)v.y; l[1] = (_Float16)(v.y - (float)h[1]);
  h[2] = (_Float16)v.z; l[2] = (_Float16)(v.z - (float)h[2]);
  h[3] = (_Float16)v.w; l[3] = (_Float16)(v.w - (float)h[3]);
  ((h4v*)xh)[i] = h;
  ((h4v*)xl)[i] = l;
}

// W [K][512] f32 -> Wt_hi [512][K] f16 transposed (hi only), coalesced via LDS tile.
__global__ void convW(const float* __restrict__ W, _Float16* __restrict__ Th, int K) {
  __shared__ float tile[32][33];
  int bx = blockIdx.x * 32;  // output-col base (N=512 dim)
  int by = blockIdx.y * 32;  // k base
  int tx = threadIdx.x, ty = threadIdx.y;
#pragma unroll
  for (int i = 0; i < 32; i += 8)
    tile[ty + i][tx] = W[(size_t)(by + ty + i) * 512 + bx + tx];
  __syncthreads();
#pragma unroll
  for (int i = 0; i < 32; i += 8)
    Th[(size_t)(bx + ty + i) * K + by + tx] = (_Float16)tile[tx][ty + i];
}

// Ws3 [512][16] -> Bt_hi [16][512]
__global__ void convW3(const float* __restrict__ W, _Float16* __restrict__ Th) {
  int t = blockIdx.x * 256 + threadIdx.x;
  if (t >= 512 * 16) return;
  int k = t >> 4, c = t & 15;
  Th[c * 512 + k] = (_Float16)W[t];
}

// ---------------- split-f16 MFMA GEMM, 2-phase double-buffered, 2-product ----------------
// C[M,512](f16) = (Ah+Al)[M,K] @ Bh[K,512]; B transposed [512][K] f16 (hi only — W values
// are O(1/sqrt(fan)), rounding error ~2^-12 rel, well within absmax budget).
// 128x128 tile, BK=32, 4 waves (2x2), 16x16x32 mfma, 2 products (Ah*Bh + Al*Bh).
// LDS per buffer 24KB (Ah:0 Al:8192 Bh:16384), double-buffered = 48KB -> 3 blocks/CU.
// Bijective XCD swizzle (m204): contiguous wgid chunk per XCD -> A-panel L2 reuse.

#define STAGE(bs, kt)                                  \
  do {                                                 \
    const size_t ko = (size_t)(kt) + w * 8;            \
    char* d0 = sm + (bs) + (w * 128) * 16;             \
    char* d1 = d0 + 1024;                              \
    gll16(Ah + (tm + l) * K + ko,      d0);            \
    gll16(Ah + (tm + 64 + l) * K + ko, d1);            \
    gll16(Al + (tm + l) * K + ko,      d0 + 8192);     \
    gll16(Al + (tm + 64 + l) * K + ko, d1 + 8192);     \
    gll16(Bh + (cn + l) * K + ko,      d0 + 16384);    \
    gll16(Bh + (cn + 64 + l) * K + ko, d1 + 16384);    \
  } while (0)

template <int K>
__global__ __launch_bounds__(256) void gemm_f16(
    const _Float16* __restrict__ Ah, const _Float16* __restrict__ Al,
    const _Float16* __restrict__ Bh, _Float16* __restrict__ C, int M) {
  __shared__ __align__(16) char sm[49152];  // 2 x 24KB
  const int t = threadIdx.x;
  const int w = t >> 6, l = t & 63;
  const int wr = w >> 1, wc = w & 1;
  const int kg = l >> 4, rr = l & 15;

  // bijective XCD swizzle: xcd = orig%8 gets contiguous wgid chunk
  const int nwg = gridDim.x;
  const int q = nwg >> 3, r = nwg & 7;
  const int orig = blockIdx.x;
  const int xcd = orig & 7, slot = orig >> 3;
  const int wgid = (xcd < r ? xcd * (q + 1) : r * (q + 1) + (xcd - r) * q) + slot;
  const size_t tm = (size_t)(wgid >> 2) * 128;
  const size_t cn = (size_t)(wgid & 3) * 128;

  f4v acc[4][4];
#pragma unroll
  for (int i = 0; i < 4; i++)
#pragma unroll
    for (int j = 0; j < 4; j++) acc[i][j] = (f4v){0.f, 0.f, 0.f, 0.f};

  STAGE(0, 0);
  __syncthreads();  // vmcnt(0)+lgkmcnt(0)+barrier (compiler-inserted drain)
  int cur = 0;

  for (int kt = 0; kt < K; kt += 32) {
    if (kt + 32 < K) STAGE(cur ^ 24576, kt + 32);  // prefetch next tile over this MFMA

    const char* base = sm + cur;
    h8v ah[4], alo[4], bh[4];
#pragma unroll
    for (int i = 0; i < 4; i++) {
      int ca = (kg * 128 + wr * 64 + i * 16 + rr) * 16;
      int cb = (kg * 128 + wc * 64 + i * 16 + rr) * 16;
      ah[i]  = *(const h8v*)(base + ca);
      alo[i] = *(const h8v*)(base + 8192 + ca);
      bh[i]  = *(const h8v*)(base + 16384 + cb);
    }
#pragma unroll
    for (int i = 0; i < 4; i++)
#pragma unroll
      for (int j = 0; j < 4; j++) {
        acc[i][j] = __builtin_amdgcn_mfma_f32_16x16x32_f16(ah[i],  bh[j], acc[i][j], 0, 0, 0);
        acc[i][j] = __builtin_amdgcn_mfma_f32_16x16x32_f16(alo[i], bh[j], acc[i][j], 0, 0, 0);
      }
    __syncthreads();  // drains next-tile vmcnt + buffer swap barrier
    cur ^= 24576;
  }

  // epilogue: C/D layout col=lane&15, row=(lane>>4)*4+reg; store f16
#pragma unroll
  for (int i = 0; i < 4; i++) {
    int row0 = wr * 64 + i * 16 + (l >> 4) * 4;
#pragma unroll
    for (int j = 0; j < 4; j++) {
      int col = wc * 64 + j * 16 + rr;
#pragma unroll
      for (int r2 = 0; r2 < 4; r2++) {
        size_t row = tm + row0 + r2;
        if (row < (size_t)M) C[row * 512 + cn + col] = (_Float16)acc[i][j][r2];
      }
    }
  }
}

// ---------------- layer-3 projection via MFMA: C[M,16](f32) = A[M,512] @ B[512,16] -------
// one wave per 16-row tile; B pre-transposed hi [16][512].

__global__ __launch_bounds__(256) void gemm3(const _Float16* __restrict__ Ah,
                                             const _Float16* __restrict__ Al,
                                             const _Float16* __restrict__ Bth,
                                             float* __restrict__ C, int M) {
  int wv = threadIdx.x >> 6, l = threadIdx.x & 63;
  size_t tm = ((size_t)blockIdx.x * 4 + wv) * 16;
  if (tm >= (size_t)M) return;
  int rr = l & 15, kg = l >> 4;
  f4v acc = (f4v){0.f, 0.f, 0.f, 0.f};
  for (int kt = 0; kt < 512; kt += 32) {
    int ka = kt + kg * 8;
    h8v a_h = *(const h8v*)&Ah[(tm + rr) * 512 + ka];
    h8v a_l = *(const h8v*)&Al[(tm + rr) * 512 + ka];
    h8v b_h = *(const h8v*)&Bth[rr * 512 + ka];
    acc = __builtin_amdgcn_mfma_f32_16x16x32_f16(a_h, b_h, acc, 0, 0, 0);
    acc = __builtin_amdgcn_mfma_f32_16x16x32_f16(a_l, b_h, acc, 0, 0, 0);
  }
#pragma unroll
  for (int r = 0; r < 4; r++) {
    size_t row = tm + kg * 4 + r;
    if (row < (size_t)M) C[row * 16 + rr] = acc[r];
  }
}

// ---------------- wsd[k][h] = sum_c Wd[k][h*C+c] * a_d[h][c] ----------------

__global__ void wsd_kernel(const float* __restrict__ Wd, const float* __restrict__ a_d,
                           float* __restrict__ wsd, int K, int H, int C) {
  int g = (blockIdx.x * 256 + threadIdx.x) >> 4;
  int l16 = threadIdx.x & 15;
  if (g >= K * H) return;
  int k = g / H, h = g - k * H;
  int ce = C >> 4;
  float s = 0.f;
  for (int j = 0; j < ce; j++) {
    int c = l16 * ce + j;
    s += Wd[(size_t)k * (H * C) + h * C + c] * a_d[h * C + c];
  }
#pragma unroll
  for (int o = 1; o < 16; o <<= 1) s += __shfl_xor(s, o);
  if (l16 == 0) wsd[k * H + h] = s;
}

// ---------------- attention logits (layers 1,2: H=4) ----------------
// xs f16 [N,512]; xin hi f16 [N,K] (lo not needed at logit precision)

__global__ void al_f16(const _Float16* __restrict__ xs, const _Float16* __restrict__ ih,
                       const float* __restrict__ a_s, const float* __restrict__ wsd,
                       float* __restrict__ als, float* __restrict__ ald, int N, int K) {
  int wid = threadIdx.x >> 6, lane = threadIdx.x & 63;
  int n = blockIdx.x * 4 + wid;
  if (n >= N) return;
  h8v vx = *(const h8v*)&xs[(size_t)n * 512 + lane * 8];
  float s = 0.f;
#pragma unroll
  for (int j = 0; j < 8; j++) s += (float)vx[j] * a_s[lane * 8 + j];
  for (int o = 1; o < 16; o <<= 1) s += __shfl_xor(s, o);
  if (!(lane & 15)) als[n * 4 + (lane >> 4)] = s;

  float d0 = 0.f, d1 = 0.f, d2 = 0.f, d3 = 0.f;
  int k0 = lane * 8;
  if (k0 < K) {
    h8v qh = *(const h8v*)&ih[(size_t)n * K + k0];
#pragma unroll
    for (int j = 0; j < 8; j++) {
      float xv = (float)qh[j];
      float4 wv = *(const float4*)&wsd[(k0 + j) * 4];
      d0 += xv * wv.x; d1 += xv * wv.y; d2 += xv * wv.z; d3 += xv * wv.w;
    }
  }
  for (int o = 1; o < 64; o <<= 1) {
    d0 += __shfl_xor(d0, o); d1 += __shfl_xor(d1, o);
    d2 += __shfl_xor(d2, o); d3 += __shfl_xor(d3, o);
  }
  if (lane == 0) *(float4*)&ald[n * 4] = make_float4(d0, d1, d2, d3);
}

// layer 3 logits: H=1
__global__ void al3_f16(const float* __restrict__ xs3, const _Float16* __restrict__ ih,
                        const float* __restrict__ as3, const float* __restrict__ wsd,
                        float* __restrict__ als, float* __restrict__ ald, int N) {
  int wid = threadIdx.x >> 6, lane = threadIdx.x & 63;
  int n = blockIdx.x * 4 + wid;
  if (n >= N) return;
  float s = (lane < 16) ? xs3[(size_t)n * 16 + lane] * as3[lane] : 0.f;
  for (int o = 1; o < 16; o <<= 1) s += __shfl_xor(s, o);
  h8v qh = *(const h8v*)&ih[(size_t)n * 512 + lane * 8];
  float d = 0.f;
#pragma unroll
  for (int j = 0; j < 8; j++) d += (float)qh[j] * wsd[lane * 8 + j];
  for (int o = 1; o < 64; o <<= 1) d += __shfl_xor(d, o);
  if (lane == 0) { als[n] = s; ald[n] = d; }
}

// ---------------- per-edge normalized softmax weights ----------------
// H=4: one wave per node. lane = e*4+h.

__global__ void wgt4_kernel(const float* __restrict__ als, const float* __restrict__ ald,
                            const int* __restrict__ off, const int* __restrict__ srcp,
                            _Float16* __restrict__ wgt, int N) {
  int wid = threadIdx.x >> 6, lane = threadIdx.x & 63;
  int n = blockIdx.x * 4 + wid;
  if (n >= N) return;
  int h = lane & 3, e = lane >> 2;
  float aldn = ald[n * 4 + h];
  int p0 = off[n], deg = off[n + 1] - p0;
  if (deg == 0) return;
  float ev0 = -1e30f;
  if (e < deg) {
    float v = als[srcp[p0 + e] * 4 + h] + aldn;
    ev0 = (v > 0.f) ? v : NEG_SLOPE * v;
  }
  float m = ev0;
  for (int base = 16; base < deg; base += 16) {
    float ev = -1e30f;
    if (base + e < deg) {
      float v = als[srcp[p0 + base + e] * 4 + h] + aldn;
      ev = (v > 0.f) ? v : NEG_SLOPE * v;
    }
    m = fmaxf(m, ev);
  }
#pragma unroll
  for (int o = 4; o < 64; o <<= 1) m = fmaxf(m, __shfl_xor(m, o));
  float den = (e < deg) ? __expf(ev0 - m) : 0.f;
  for (int base = 16; base < deg; base += 16) {
    if (base + e < deg) {
      float v = als[srcp[p0 + base + e] * 4 + h] + aldn;
      v = (v > 0.f) ? v : NEG_SLOPE * v;
      den += __expf(v - m);
    }
  }
#pragma unroll
  for (int o = 4; o < 64; o <<= 1) den += __shfl_xor(den, o);
  float rw = 1.f / (den + EPSF);
  if (e < deg) wgt[(size_t)(p0 + e) * 4 + h] = (_Float16)(__expf(ev0 - m) * rw);
  for (int base = 16; base < deg; base += 16) {
    if (base + e < deg) {
      float v = als[srcp[p0 + base + e] * 4 + h] + aldn;
      v = (v > 0.f) ? v : NEG_SLOPE * v;
      wgt[(size_t)(p0 + base + e) * 4 + h] = (_Float16)(__expf(v - m) * rw);
    }
  }
}

// H=1: one wave per node, lane = edge slot.
__global__ void wgt1_kernel(const float* __restrict__ als, const float* __restrict__ ald,
                            const int* __restrict__ off, const int* __restrict__ srcp,
                            _Float16* __restrict__ wgt, int N) {
  int wid = threadIdx.x >> 6, lane = threadIdx.x & 63;
  int n = blockIdx.x * 4 + wid;
  if (n >= N) return;
  float aldn = ald[n];
  int p0 = off[n], deg = off[n + 1] - p0;
  if (deg == 0) return;
  float ev0 = -1e30f;
  if (lane < deg) {
    float v = als[srcp[p0 + lane]] + aldn;
    ev0 = (v > 0.f) ? v : NEG_SLOPE * v;
  }
  float m = ev0;
  for (int base = 64; base < deg; base += 64) {
    float ev = -1e30f;
    if (base + lane < deg) {
      float v = als[srcp[p0 + base + lane]] + aldn;
      ev = (v > 0.f) ? v : NEG_SLOPE * v;
    }
    m = fmaxf(m, ev);
  }
#pragma unroll
  for (int o = 1; o < 64; o <<= 1) m = fmaxf(m, __shfl_xor(m, o));
  float den = (lane < deg) ? __expf(ev0 - m) : 0.f;
  for (int base = 64; base < deg; base += 64) {
    if (base + lane < deg) {
      float v = als[srcp[p0 + base + lane]] + aldn;
      v = (v > 0.f) ? v : NEG_SLOPE * v;
      den += __expf(v - m);
    }
  }
#pragma unroll
  for (int o = 1; o < 64; o <<= 1) den += __shfl_xor(den, o);
  float rw = 1.f / (den + EPSF);
  if (lane < deg) wgt[p0 + lane] = (_Float16)(__expf(ev0 - m) * rw);
  for (int base = 64; base < deg; base += 64) {
    if (base + lane < deg) {
      float v = als[srcp[p0 + base + lane]] + aldn;
      v = (v > 0.f) ? v : NEG_SLOPE * v;
      wgt[p0 + base + lane] = (_Float16)(__expf(v - m) * rw);
    }
  }
}

// ---------------- aggregation: single weighted-gather pass ----------------
// layers 1,2: one block per node, thread t handles channels 2t,2t+1. xs f16.

__global__ __launch_bounds__(256) void agg512(
    const _Float16* __restrict__ xs, const _Float16* __restrict__ wgt,
    const int* __restrict__ off, const int* __restrict__ srcp,
    const float* __restrict__ bias,
    _Float16* __restrict__ oh, _Float16* __restrict__ ol, int N) {
  int n = blockIdx.x;
  int t = threadIdx.x;
  int h = t >> 6;
  int p0 = off[n], p1 = off[n + 1];
  float ax = 0.f, ay = 0.f;
  for (int p = p0; p < p1; p++) {
    int s = srcp[p];
    float w = (float)wgt[(size_t)p * 4 + h];
    h2v v = *(const h2v*)&xs[(size_t)s * 512 + 2 * t];
    ax += w * (float)v[0]; ay += w * (float)v[1];
  }
  float2 b = *(const float2*)&bias[2 * t];
  ax = fmaxf(ax + b.x, 0.f);  // fused relu
  ay = fmaxf(ay + b.y, 0.f);
  _Float16 hx = (_Float16)ax, hy = (_Float16)ay;
  h2v wh, wl;
  wh[0] = hx; wh[1] = hy;
  wl[0] = (_Float16)(ax - (float)hx); wl[1] = (_Float16)(ay - (float)hy);
  *(h2v*)&oh[(size_t)n * 512 + 2 * t] = wh;
  *(h2v*)&ol[(size_t)n * 512 + 2 * t] = wl;
}

// layer 3: H=1, C=16, no relu, f32 out. 16 nodes per block.
__global__ void agg16(const float* __restrict__ xs3, const _Float16* __restrict__ wgt,
                      const int* __restrict__ off, const int* __restrict__ srcp,
                      const float* __restrict__ bias, float* __restrict__ out, int N) {
  int g = threadIdx.x >> 4, c = threadIdx.x & 15;
  int n = blockIdx.x * 16 + g;
  if (n >= N) return;
  int p0 = off[n], p1 = off[n + 1];
  float acc = 0.f;
  for (int p = p0; p < p1; p++)
    acc += (float)wgt[p] * xs3[(size_t)srcp[p] * 16 + c];
  out[(size_t)n * 16 + c] = acc + bias[c];
}

// ---------------- launch ----------------

extern "C" void kernel_launch(void* const* d_in, const int* in_sizes, int n_in,
                              void* d_out, int out_size, void* d_ws, size_t ws_size,
                              hipStream_t stream) {
  const float* x   = (const float*)d_in[0];
  const int*   ei  = (const int*)d_in[1];
  const float* Ws1 = (const float*)d_in[2];
  const float* Wd1 = (const float*)d_in[3];
  const float* as1 = (const float*)d_in[4];
  const float* ad1 = (const float*)d_in[5];
  const float* b1  = (const float*)d_in[6];
  const float* Ws2 = (const float*)d_in[7];
  const float* Wd2 = (const float*)d_in[8];
  const float* as2 = (const float*)d_in[9];
  const float* ad2 = (const float*)d_in[10];
  const float* b2  = (const float*)d_in[11];
  const float* Ws3 = (const float*)d_in[12];
  const float* Wd3 = (const float*)d_in[13];
  const float* as3 = (const float*)d_in[14];
  const float* ad3 = (const float*)d_in[15];
  const float* b3  = (const float*)d_in[16];

  const int N = in_sizes[0] / 128;  // 50000
  const int E = in_sizes[1] / 2;    // 400000
  const int* src = ei;
  const int* dst = ei + E;

  // workspace layout (bytes), total ~164 MB; all offsets 16B-aligned
  char* w = (char*)d_ws;
  _Float16* xs     = (_Float16*)(w + 0);           // [N,512] f16
  _Float16* h_hi   = (_Float16*)(w + 51200000);    // [N,512] f16 ([N,128] x_hi early)
  _Float16* h_lo   = (_Float16*)(w + 102400000);
  float*    als    = (float*)(w + 153600000);      // [N,4]
  float*    ald    = (float*)(w + 154400000);      // [N,4]
  float*    xs3    = (float*)(w + 155200000);      // [N,16] f32
  _Float16* wgt    = (_Float16*)(w + 158400000);   // [E,4] f16
  int*      counts = (int*)(w + 161600000);        // [N]
  int*      cur    = (int*)(w + 161800000);        // [N]
  int*      offs   = (int*)(w + 162000000);        // [N+1]
  int*      bsum   = (int*)(w + 162200192);        // [~49]
  int*      srcp   = (int*)(w + 162204288);        // [E]
  float*    wsd    = (float*)(w + 163804288);      // [512,4]
  _Float16* wt_hi  = (_Float16*)(w + 163812480);   // [512,512] f16 (B^T, hi only)
  _Float16* wt3_hi = (_Float16*)(w + 164336768);   // [16,512] f16

  // ---- CSR build ----
  hipMemsetAsync(counts, 0, 2 * (size_t)N * 4, stream);  // counts + cur contiguous
  hist_kernel<<<(E + 255) / 256, 256, 0, stream>>>(dst, counts, E);
  int nb = (N + 1023) / 1024;
  scan1<<<nb, 1024, 0, stream>>>(counts, offs, bsum, N);
  scan2<<<1, 64, 0, stream>>>(bsum, offs, nb, N, E);
  scan3<<<nb, 1024, 0, stream>>>(offs, bsum, N);
  scatter_kernel<<<(E + 255) / 256, 256, 0, stream>>>(src, dst, offs, cur, srcp, E);

  int ggrid = ((N + 127) / 128) * 4;  // 1-D grid; XCD swizzle inside kernel
  dim3 cwb(32, 8);
  int nwb = (N + 3) / 4;

  // ---- layer 1 (K=128) ----
  convX<<<(N * 128 / 4 + 255) / 256, 256, 0, stream>>>(x, h_hi, h_lo, N * 128 / 4);
  wsd_kernel<<<(128 * 4 * 16 + 255) / 256, 256, 0, stream>>>(Wd1, ad1, wsd, 128, 4, 128);
  convW<<<dim3(16, 4), cwb, 0, stream>>>(Ws1, wt_hi, 128);
  gemm_f16<128><<<ggrid, 256, 0, stream>>>(h_hi, h_lo, wt_hi, xs, N);
  al_f16<<<nwb, 256, 0, stream>>>(xs, h_hi, as1, wsd, als, ald, N, 128);
  wgt4_kernel<<<nwb, 256, 0, stream>>>(als, ald, offs, srcp, wgt, N);
  agg512<<<N, 256, 0, stream>>>(xs, wgt, offs, srcp, b1, h_hi, h_lo, N);

  // ---- layer 2 (K=512) ----
  wsd_kernel<<<(512 * 4 * 16 + 255) / 256, 256, 0, stream>>>(Wd2, ad2, wsd, 512, 4, 128);
  convW<<<dim3(16, 16), cwb, 0, stream>>>(Ws2, wt_hi, 512);
  gemm_f16<512><<<ggrid, 256, 0, stream>>>(h_hi, h_lo, wt_hi, xs, N);
  al_f16<<<nwb, 256, 0, stream>>>(xs, h_hi, as2, wsd, als, ald, N, 512);
  wgt4_kernel<<<nwb, 256, 0, stream>>>(als, ald, offs, srcp, wgt, N);
  agg512<<<N, 256, 0, stream>>>(xs, wgt, offs, srcp, b2, h_hi, h_lo, N);

  // ---- layer 3 (K=512, N=16, H=1) ----
  wsd_kernel<<<(512 * 16 + 255) / 256, 256, 0, stream>>>(Wd3, ad3, wsd, 512, 1, 16);
  convW3<<<32, 256, 0, stream>>>(Ws3, wt3_hi);
  gemm3<<<(N / 16 + 4) / 4, 256, 0, stream>>>(h_hi, h_lo, wt3_hi, xs3, N);
  al3_f16<<<nwb, 256, 0, stream>>>(xs3, h_hi, as3, wsd, als, ald, N);
  wgt1_kernel<<<nwb, 256, 0, stream>>>(als, ald, offs, srcp, wgt, N);
  agg16<<<(N + 15) / 16, 256, 0, stream>>>(xs3, wgt, offs, srcp, b3, (float*)d_out, N);
}

// Round 7
// 577.886 us; speedup vs baseline: 2.1113x; 1.1731x over previous
//
#include <hip/hip_runtime.h>
#include <math.h>

#define NEG_SLOPE 0.2f
#define EPSF 1e-16f

typedef _Float16 h2v __attribute__((ext_vector_type(2)));
typedef _Float16 h4v __attribute__((ext_vector_type(4)));
typedef _Float16 h8v __attribute__((ext_vector_type(8)));
typedef float f4v __attribute__((ext_vector_type(4)));

#define AS1 __attribute__((address_space(1)))
#define AS3 __attribute__((address_space(3)))

__device__ __forceinline__ void gll16(const void* g, void* l) {
  __builtin_amdgcn_global_load_lds((AS1 void*)g, (AS3 void*)l, 16, 0, 0);
}

// ---------------- CSR build ----------------

__global__ void hist_kernel(const int* __restrict__ dst, int* __restrict__ counts, int E) {
  int t = blockIdx.x * 256 + threadIdx.x;
  if (t < E) atomicAdd(&counts[dst[t]], 1);
}

__global__ void scan1(const int* __restrict__ counts, int* __restrict__ offs,
                      int* __restrict__ bsum, int N) {
  __shared__ int sd[1024];
  int tid = threadIdx.x;
  int i = blockIdx.x * 1024 + tid;
  int v = (i < N) ? counts[i] : 0;
  sd[tid] = v;
  __syncthreads();
  for (int s = 1; s < 1024; s <<= 1) {
    int tv = (tid >= s) ? sd[tid - s] : 0;
    __syncthreads();
    sd[tid] += tv;
    __syncthreads();
  }
  if (i < N) offs[i] = sd[tid] - v;  // local exclusive
  if (tid == 1023) bsum[blockIdx.x] = sd[1023];
}

__global__ void scan2(int* __restrict__ bsum, int* __restrict__ offs, int nb, int N, int E) {
  if (threadIdx.x == 0) {
    int r = 0;
    for (int i = 0; i < nb; i++) { int v = bsum[i]; bsum[i] = r; r += v; }
    offs[N] = E;
  }
}

__global__ void scan3(int* __restrict__ offs, const int* __restrict__ bsum, int N) {
  int i = blockIdx.x * 1024 + threadIdx.x;
  if (i < N) offs[i] += bsum[blockIdx.x];
}

__global__ void scatter_kernel(const int* __restrict__ src, const int* __restrict__ dst,
                               const int* __restrict__ off, int* __restrict__ cur,
                               int* __restrict__ srcp, int E) {
  int t = blockIdx.x * 256 + threadIdx.x;
  if (t < E) {
    int d = dst[t];
    int p = off[d] + atomicAdd(&cur[d], 1);
    srcp[p] = src[t];
  }
}

// ---------------- fp32 -> f16 converts ----------------

__global__ void convX(const float* __restrict__ x, _Float16* __restrict__ xh, int n4) {
  int i = blockIdx.x * 256 + threadIdx.x;
  if (i >= n4) return;
  float4 v = ((const float4*)x)[i];
  h4v h;
  h[0] = (_Float16)v.x; h[1] = (_Float16)v.y;
  h[2] = (_Float16)v.z; h[3] = (_Float16)v.w;
  ((h4v*)xh)[i] = h;
}

// W [K][512] f32 -> Wt [512][K] f16 transposed, coalesced via LDS tile.
__global__ void convW(const float* __restrict__ W, _Float16* __restrict__ Th, int K) {
  __shared__ float tile[32][33];
  int bx = blockIdx.x * 32;  // output-col base (N=512 dim)
  int by = blockIdx.y * 32;  // k base
  int tx = threadIdx.x, ty = threadIdx.y;
#pragma unroll
  for (int i = 0; i < 32; i += 8)
    tile[ty + i][tx] = W[(size_t)(by + ty + i) * 512 + bx + tx];
  __syncthreads();
#pragma unroll
  for (int i = 0; i < 32; i += 8)
    Th[(size_t)(bx + ty + i) * K + by + tx] = (_Float16)tile[tx][ty + i];
}

// Ws3 [512][16] -> Bt [16][512]
__global__ void convW3(const float* __restrict__ W, _Float16* __restrict__ Th) {
  int t = blockIdx.x * 256 + threadIdx.x;
  if (t >= 512 * 16) return;
  int k = t >> 4, c = t & 15;
  Th[c * 512 + k] = (_Float16)W[t];
}

// ---------------- f16 MFMA GEMM, 2-phase double-buffered ----------------
// C[M,512](f16) = A[M,K](f16) @ B[K,512]; B transposed [512][K] f16.
// 128x128 tile, BK=32, 4 waves (2x2), 16x16x32 mfma, single product.
// LDS per buffer 16KB (A:0 B:8192), double-buffered = 32KB.
// Bijective XCD swizzle (m204): contiguous wgid chunk per XCD -> A-panel L2 reuse.

#define STAGE(bs, kt)                                  \
  do {                                                 \
    const size_t ko = (size_t)(kt) + w * 8;            \
    char* d0 = sm + (bs) + (w * 128) * 16;             \
    char* d1 = d0 + 1024;                              \
    gll16(A + (tm + l) * K + ko,      d0);             \
    gll16(A + (tm + 64 + l) * K + ko, d1);             \
    gll16(Bh + (cn + l) * K + ko,      d0 + 8192);     \
    gll16(Bh + (cn + 64 + l) * K + ko, d1 + 8192);     \
  } while (0)

template <int K>
__global__ __launch_bounds__(256) void gemm_f16(
    const _Float16* __restrict__ A, const _Float16* __restrict__ Bh,
    _Float16* __restrict__ C, int M) {
  __shared__ __align__(16) char sm[32768];  // 2 x 16KB
  const int t = threadIdx.x;
  const int w = t >> 6, l = t & 63;
  const int wr = w >> 1, wc = w & 1;
  const int kg = l >> 4, rr = l & 15;

  // bijective XCD swizzle: xcd = orig%8 gets contiguous wgid chunk
  const int nwg = gridDim.x;
  const int q = nwg >> 3, r = nwg & 7;
  const int orig = blockIdx.x;
  const int xcd = orig & 7, slot = orig >> 3;
  const int wgid = (xcd < r ? xcd * (q + 1) : r * (q + 1) + (xcd - r) * q) + slot;
  const size_t tm = (size_t)(wgid >> 2) * 128;
  const size_t cn = (size_t)(wgid & 3) * 128;

  f4v acc[4][4];
#pragma unroll
  for (int i = 0; i < 4; i++)
#pragma unroll
    for (int j = 0; j < 4; j++) acc[i][j] = (f4v){0.f, 0.f, 0.f, 0.f};

  STAGE(0, 0);
  __syncthreads();  // vmcnt(0)+lgkmcnt(0)+barrier (compiler-inserted drain)
  int cur = 0;

  for (int kt = 0; kt < K; kt += 32) {
    if (kt + 32 < K) STAGE(cur ^ 16384, kt + 32);  // prefetch next tile over this MFMA

    const char* base = sm + cur;
    h8v ah[4], bh[4];
#pragma unroll
    for (int i = 0; i < 4; i++) {
      int ca = (kg * 128 + wr * 64 + i * 16 + rr) * 16;
      int cb = (kg * 128 + wc * 64 + i * 16 + rr) * 16;
      ah[i] = *(const h8v*)(base + ca);
      bh[i] = *(const h8v*)(base + 8192 + cb);
    }
#pragma unroll
    for (int i = 0; i < 4; i++)
#pragma unroll
      for (int j = 0; j < 4; j++)
        acc[i][j] = __builtin_amdgcn_mfma_f32_16x16x32_f16(ah[i], bh[j], acc[i][j], 0, 0, 0);
    __syncthreads();  // drains next-tile vmcnt + buffer swap barrier
    cur ^= 16384;
  }

  // epilogue: C/D layout col=lane&15, row=(lane>>4)*4+reg; store f16
#pragma unroll
  for (int i = 0; i < 4; i++) {
    int row0 = wr * 64 + i * 16 + (l >> 4) * 4;
#pragma unroll
    for (int j = 0; j < 4; j++) {
      int col = wc * 64 + j * 16 + rr;
#pragma unroll
      for (int r2 = 0; r2 < 4; r2++) {
        size_t row = tm + row0 + r2;
        if (row < (size_t)M) C[row * 512 + cn + col] = (_Float16)acc[i][j][r2];
      }
    }
  }
}

// ---------------- layer-3 projection via MFMA: C[M,16](f32) = A[M,512] @ B[512,16] -------
// one wave per 16-row tile; B pre-transposed [16][512] f16.

__global__ __launch_bounds__(256) void gemm3(const _Float16* __restrict__ A,
                                             const _Float16* __restrict__ Bth,
                                             float* __restrict__ C, int M) {
  int wv = threadIdx.x >> 6, l = threadIdx.x & 63;
  size_t tm = ((size_t)blockIdx.x * 4 + wv) * 16;
  if (tm >= (size_t)M) return;
  int rr = l & 15, kg = l >> 4;
  f4v acc = (f4v){0.f, 0.f, 0.f, 0.f};
  for (int kt = 0; kt < 512; kt += 32) {
    int ka = kt + kg * 8;
    h8v a_h = *(const h8v*)&A[(tm + rr) * 512 + ka];
    h8v b_h = *(const h8v*)&Bth[rr * 512 + ka];
    acc = __builtin_amdgcn_mfma_f32_16x16x32_f16(a_h, b_h, acc, 0, 0, 0);
  }
#pragma unroll
  for (int r = 0; r < 4; r++) {
    size_t row = tm + kg * 4 + r;
    if (row < (size_t)M) C[row * 16 + rr] = acc[r];
  }
}

// ---------------- wsd[k][h] = sum_c Wd[k][h*C+c] * a_d[h][c] ----------------

__global__ void wsd_kernel(const float* __restrict__ Wd, const float* __restrict__ a_d,
                           float* __restrict__ wsd, int K, int H, int C) {
  int g = (blockIdx.x * 256 + threadIdx.x) >> 4;
  int l16 = threadIdx.x & 15;
  if (g >= K * H) return;
  int k = g / H, h = g - k * H;
  int ce = C >> 4;
  float s = 0.f;
  for (int j = 0; j < ce; j++) {
    int c = l16 * ce + j;
    s += Wd[(size_t)k * (H * C) + h * C + c] * a_d[h * C + c];
  }
#pragma unroll
  for (int o = 1; o < 16; o <<= 1) s += __shfl_xor(s, o);
  if (l16 == 0) wsd[k * H + h] = s;
}

// ---------------- attention logits (layers 1,2: H=4) ----------------
// xs f16 [N,512]; xin f16 [N,K]

__global__ void al_f16(const _Float16* __restrict__ xs, const _Float16* __restrict__ ih,
                       const float* __restrict__ a_s, const float* __restrict__ wsd,
                       float* __restrict__ als, float* __restrict__ ald, int N, int K) {
  int wid = threadIdx.x >> 6, lane = threadIdx.x & 63;
  int n = blockIdx.x * 4 + wid;
  if (n >= N) return;
  h8v vx = *(const h8v*)&xs[(size_t)n * 512 + lane * 8];
  float s = 0.f;
#pragma unroll
  for (int j = 0; j < 8; j++) s += (float)vx[j] * a_s[lane * 8 + j];
  for (int o = 1; o < 16; o <<= 1) s += __shfl_xor(s, o);
  if (!(lane & 15)) als[n * 4 + (lane >> 4)] = s;

  float d0 = 0.f, d1 = 0.f, d2 = 0.f, d3 = 0.f;
  int k0 = lane * 8;
  if (k0 < K) {
    h8v qh = *(const h8v*)&ih[(size_t)n * K + k0];
#pragma unroll
    for (int j = 0; j < 8; j++) {
      float xv = (float)qh[j];
      float4 wv = *(const float4*)&wsd[(k0 + j) * 4];
      d0 += xv * wv.x; d1 += xv * wv.y; d2 += xv * wv.z; d3 += xv * wv.w;
    }
  }
  for (int o = 1; o < 64; o <<= 1) {
    d0 += __shfl_xor(d0, o); d1 += __shfl_xor(d1, o);
    d2 += __shfl_xor(d2, o); d3 += __shfl_xor(d3, o);
  }
  if (lane == 0) *(float4*)&ald[n * 4] = make_float4(d0, d1, d2, d3);
}

// layer 3 logits: H=1
__global__ void al3_f16(const float* __restrict__ xs3, const _Float16* __restrict__ ih,
                        const float* __restrict__ as3, const float* __restrict__ wsd,
                        float* __restrict__ als, float* __restrict__ ald, int N) {
  int wid = threadIdx.x >> 6, lane = threadIdx.x & 63;
  int n = blockIdx.x * 4 + wid;
  if (n >= N) return;
  float s = (lane < 16) ? xs3[(size_t)n * 16 + lane] * as3[lane] : 0.f;
  for (int o = 1; o < 16; o <<= 1) s += __shfl_xor(s, o);
  h8v qh = *(const h8v*)&ih[(size_t)n * 512 + lane * 8];
  float d = 0.f;
#pragma unroll
  for (int j = 0; j < 8; j++) d += (float)qh[j] * wsd[lane * 8 + j];
  for (int o = 1; o < 64; o <<= 1) d += __shfl_xor(d, o);
  if (lane == 0) { als[n] = s; ald[n] = d; }
}

// ---------------- per-edge normalized softmax weights ----------------
// H=4: one wave per node. lane = e*4+h.

__global__ void wgt4_kernel(const float* __restrict__ als, const float* __restrict__ ald,
                            const int* __restrict__ off, const int* __restrict__ srcp,
                            _Float16* __restrict__ wgt, int N) {
  int wid = threadIdx.x >> 6, lane = threadIdx.x & 63;
  int n = blockIdx.x * 4 + wid;
  if (n >= N) return;
  int h = lane & 3, e = lane >> 2;
  float aldn = ald[n * 4 + h];
  int p0 = off[n], deg = off[n + 1] - p0;
  if (deg == 0) return;
  float ev0 = -1e30f;
  if (e < deg) {
    float v = als[srcp[p0 + e] * 4 + h] + aldn;
    ev0 = (v > 0.f) ? v : NEG_SLOPE * v;
  }
  float m = ev0;
  for (int base = 16; base < deg; base += 16) {
    float ev = -1e30f;
    if (base + e < deg) {
      float v = als[srcp[p0 + base + e] * 4 + h] + aldn;
      ev = (v > 0.f) ? v : NEG_SLOPE * v;
    }
    m = fmaxf(m, ev);
  }
#pragma unroll
  for (int o = 4; o < 64; o <<= 1) m = fmaxf(m, __shfl_xor(m, o));
  float den = (e < deg) ? __expf(ev0 - m) : 0.f;
  for (int base = 16; base < deg; base += 16) {
    if (base + e < deg) {
      float v = als[srcp[p0 + base + e] * 4 + h] + aldn;
      v = (v > 0.f) ? v : NEG_SLOPE * v;
      den += __expf(v - m);
    }
  }
#pragma unroll
  for (int o = 4; o < 64; o <<= 1) den += __shfl_xor(den, o);
  float rw = 1.f / (den + EPSF);
  if (e < deg) wgt[(size_t)(p0 + e) * 4 + h] = (_Float16)(__expf(ev0 - m) * rw);
  for (int base = 16; base < deg; base += 16) {
    if (base + e < deg) {
      float v = als[srcp[p0 + base + e] * 4 + h] + aldn;
      v = (v > 0.f) ? v : NEG_SLOPE * v;
      wgt[(size_t)(p0 + base + e) * 4 + h] = (_Float16)(__expf(v - m) * rw);
    }
  }
}

// H=1: one wave per node, lane = edge slot.
__global__ void wgt1_kernel(const float* __restrict__ als, const float* __restrict__ ald,
                            const int* __restrict__ off, const int* __restrict__ srcp,
                            _Float16* __restrict__ wgt, int N) {
  int wid = threadIdx.x >> 6, lane = threadIdx.x & 63;
  int n = blockIdx.x * 4 + wid;
  if (n >= N) return;
  float aldn = ald[n];
  int p0 = off[n], deg = off[n + 1] - p0;
  if (deg == 0) return;
  float ev0 = -1e30f;
  if (lane < deg) {
    float v = als[srcp[p0 + lane]] + aldn;
    ev0 = (v > 0.f) ? v : NEG_SLOPE * v;
  }
  float m = ev0;
  for (int base = 64; base < deg; base += 64) {
    float ev = -1e30f;
    if (base + lane < deg) {
      float v = als[srcp[p0 + base + lane]] + aldn;
      ev = (v > 0.f) ? v : NEG_SLOPE * v;
    }
    m = fmaxf(m, ev);
  }
#pragma unroll
  for (int o = 1; o < 64; o <<= 1) m = fmaxf(m, __shfl_xor(m, o));
  float den = (lane < deg) ? __expf(ev0 - m) : 0.f;
  for (int base = 64; base < deg; base += 64) {
    if (base + lane < deg) {
      float v = als[srcp[p0 + base + lane]] + aldn;
      v = (v > 0.f) ? v : NEG_SLOPE * v;
      den += __expf(v - m);
    }
  }
#pragma unroll
  for (int o = 1; o < 64; o <<= 1) den += __shfl_xor(den, o);
  float rw = 1.f / (den + EPSF);
  if (lane < deg) wgt[p0 + lane] = (_Float16)(__expf(ev0 - m) * rw);
  for (int base = 64; base < deg; base += 64) {
    if (base + lane < deg) {
      float v = als[srcp[p0 + base + lane]] + aldn;
      v = (v > 0.f) ? v : NEG_SLOPE * v;
      wgt[p0 + base + lane] = (_Float16)(__expf(v - m) * rw);
    }
  }
}

// ---------------- aggregation: single weighted-gather pass ----------------
// layers 1,2: one block per node, thread t handles channels 2t,2t+1. xs f16, out f16.
// unroll-2 with dual accumulators for gather ILP.

__global__ __launch_bounds__(256) void agg512(
    const _Float16* __restrict__ xs, const _Float16* __restrict__ wgt,
    const int* __restrict__ off, const int* __restrict__ srcp,
    const float* __restrict__ bias, _Float16* __restrict__ oh, int N) {
  int n = blockIdx.x;
  int t = threadIdx.x;
  int h = t >> 6;
  int p0 = off[n], p1 = off[n + 1];
  float ax = 0.f, ay = 0.f, bx = 0.f, by = 0.f;
  int p = p0;
  for (; p + 1 < p1; p += 2) {
    int s0 = srcp[p], s1 = srcp[p + 1];
    float w0 = (float)wgt[(size_t)p * 4 + h];
    float w1 = (float)wgt[(size_t)(p + 1) * 4 + h];
    h2v v0 = *(const h2v*)&xs[(size_t)s0 * 512 + 2 * t];
    h2v v1 = *(const h2v*)&xs[(size_t)s1 * 512 + 2 * t];
    ax += w0 * (float)v0[0]; ay += w0 * (float)v0[1];
    bx += w1 * (float)v1[0]; by += w1 * (float)v1[1];
  }
  if (p < p1) {
    int s0 = srcp[p];
    float w0 = (float)wgt[(size_t)p * 4 + h];
    h2v v0 = *(const h2v*)&xs[(size_t)s0 * 512 + 2 * t];
    ax += w0 * (float)v0[0]; ay += w0 * (float)v0[1];
  }
  ax += bx; ay += by;
  float2 b = *(const float2*)&bias[2 * t];
  ax = fmaxf(ax + b.x, 0.f);  // fused relu
  ay = fmaxf(ay + b.y, 0.f);
  h2v wh;
  wh[0] = (_Float16)ax; wh[1] = (_Float16)ay;
  *(h2v*)&oh[(size_t)n * 512 + 2 * t] = wh;
}

// layer 3: H=1, C=16, no relu, f32 out. 16 nodes per block.
__global__ void agg16(const float* __restrict__ xs3, const _Float16* __restrict__ wgt,
                      const int* __restrict__ off, const int* __restrict__ srcp,
                      const float* __restrict__ bias, float* __restrict__ out, int N) {
  int g = threadIdx.x >> 4, c = threadIdx.x & 15;
  int n = blockIdx.x * 16 + g;
  if (n >= N) return;
  int p0 = off[n], p1 = off[n + 1];
  float acc = 0.f;
  for (int p = p0; p < p1; p++)
    acc += (float)wgt[p] * xs3[(size_t)srcp[p] * 16 + c];
  out[(size_t)n * 16 + c] = acc + bias[c];
}

// ---------------- launch ----------------

extern "C" void kernel_launch(void* const* d_in, const int* in_sizes, int n_in,
                              void* d_out, int out_size, void* d_ws, size_t ws_size,
                              hipStream_t stream) {
  const float* x   = (const float*)d_in[0];
  const int*   ei  = (const int*)d_in[1];
  const float* Ws1 = (const float*)d_in[2];
  const float* Wd1 = (const float*)d_in[3];
  const float* as1 = (const float*)d_in[4];
  const float* ad1 = (const float*)d_in[5];
  const float* b1  = (const float*)d_in[6];
  const float* Ws2 = (const float*)d_in[7];
  const float* Wd2 = (const float*)d_in[8];
  const float* as2 = (const float*)d_in[9];
  const float* ad2 = (const float*)d_in[10];
  const float* b2  = (const float*)d_in[11];
  const float* Ws3 = (const float*)d_in[12];
  const float* Wd3 = (const float*)d_in[13];
  const float* as3 = (const float*)d_in[14];
  const float* ad3 = (const float*)d_in[15];
  const float* b3  = (const float*)d_in[16];

  const int N = in_sizes[0] / 128;  // 50000
  const int E = in_sizes[1] / 2;    // 400000
  const int* src = ei;
  const int* dst = ei + E;

  // workspace layout (bytes), total ~113.2 MB; all offsets 16B-aligned
  char* w = (char*)d_ws;
  _Float16* xs     = (_Float16*)(w + 0);           // [N,512] f16
  _Float16* hbuf   = (_Float16*)(w + 51200000);    // [N,512] f16 ([N,128] x_f16 early)
  float*    als    = (float*)(w + 102400000);      // [N,4]
  float*    ald    = (float*)(w + 103200000);      // [N,4]
  float*    xs3    = (float*)(w + 104000000);      // [N,16] f32
  _Float16* wgt    = (_Float16*)(w + 107200000);   // [E,4] f16
  int*      counts = (int*)(w + 110400000);        // [N]
  int*      cur    = (int*)(w + 110600000);        // [N]
  int*      offs   = (int*)(w + 110800000);        // [N+1]
  int*      bsum   = (int*)(w + 111000192);        // [~49]
  int*      srcp   = (int*)(w + 111004288);        // [E]
  float*    wsd    = (float*)(w + 112604288);      // [512,4]
  _Float16* wt_hi  = (_Float16*)(w + 112612480);   // [512,512] f16 (B^T)
  _Float16* wt3_hi = (_Float16*)(w + 113136768);   // [16,512] f16

  // ---- CSR build ----
  hipMemsetAsync(counts, 0, 2 * (size_t)N * 4, stream);  // counts + cur contiguous
  hist_kernel<<<(E + 255) / 256, 256, 0, stream>>>(dst, counts, E);
  int nb = (N + 1023) / 1024;
  scan1<<<nb, 1024, 0, stream>>>(counts, offs, bsum, N);
  scan2<<<1, 64, 0, stream>>>(bsum, offs, nb, N, E);
  scan3<<<nb, 1024, 0, stream>>>(offs, bsum, N);
  scatter_kernel<<<(E + 255) / 256, 256, 0, stream>>>(src, dst, offs, cur, srcp, E);

  int ggrid = ((N + 127) / 128) * 4;  // 1-D grid; XCD swizzle inside kernel
  dim3 cwb(32, 8);
  int nwb = (N + 3) / 4;

  // ---- layer 1 (K=128) ----
  convX<<<(N * 128 / 4 + 255) / 256, 256, 0, stream>>>(x, hbuf, N * 128 / 4);
  wsd_kernel<<<(128 * 4 * 16 + 255) / 256, 256, 0, stream>>>(Wd1, ad1, wsd, 128, 4, 128);
  convW<<<dim3(16, 4), cwb, 0, stream>>>(Ws1, wt_hi, 128);
  gemm_f16<128><<<ggrid, 256, 0, stream>>>(hbuf, wt_hi, xs, N);
  al_f16<<<nwb, 256, 0, stream>>>(xs, hbuf, as1, wsd, als, ald, N, 128);
  wgt4_kernel<<<nwb, 256, 0, stream>>>(als, ald, offs, srcp, wgt, N);
  agg512<<<N, 256, 0, stream>>>(xs, wgt, offs, srcp, b1, hbuf, N);

  // ---- layer 2 (K=512) ----
  wsd_kernel<<<(512 * 4 * 16 + 255) / 256, 256, 0, stream>>>(Wd2, ad2, wsd, 512, 4, 128);
  convW<<<dim3(16, 16), cwb, 0, stream>>>(Ws2, wt_hi, 512);
  gemm_f16<512><<<ggrid, 256, 0, stream>>>(hbuf, wt_hi, xs, N);
  al_f16<<<nwb, 256, 0, stream>>>(xs, hbuf, as2, wsd, als, ald, N, 512);
  wgt4_kernel<<<nwb, 256, 0, stream>>>(als, ald, offs, srcp, wgt, N);
  agg512<<<N, 256, 0, stream>>>(xs, wgt, offs, srcp, b2, hbuf, N);

  // ---- layer 3 (K=512, N=16, H=1) ----
  wsd_kernel<<<(512 * 16 + 255) / 256, 256, 0, stream>>>(Wd3, ad3, wsd, 512, 1, 16);
  convW3<<<32, 256, 0, stream>>>(Ws3, wt3_hi);
  gemm3<<<(N / 16 + 4) / 4, 256, 0, stream>>>(hbuf, wt3_hi, xs3, N);
  al3_f16<<<nwb, 256, 0, stream>>>(xs3, hbuf, as3, wsd, als, ald, N);
  wgt1_kernel<<<nwb, 256, 0, stream>>>(als, ald, offs, srcp, wgt, N);
  agg16<<<(N + 15) / 16, 256, 0, stream>>>(xs3, wgt, offs, srcp, b3, (float*)d_out, N);
}

// Round 8
// 525.973 us; speedup vs baseline: 2.3197x; 1.0987x over previous
//
#include <hip/hip_runtime.h>
#include <math.h>

#define NEG_SLOPE 0.2f
#define EPSF 1e-16f

typedef _Float16 h2v __attribute__((ext_vector_type(2)));
typedef _Float16 h4v __attribute__((ext_vector_type(4)));
typedef _Float16 h8v __attribute__((ext_vector_type(8)));
typedef float f4v __attribute__((ext_vector_type(4)));

#define AS1 __attribute__((address_space(1)))
#define AS3 __attribute__((address_space(3)))

__device__ __forceinline__ void gll16(const void* g, void* l) {
  __builtin_amdgcn_global_load_lds((AS1 void*)g, (AS3 void*)l, 16, 0, 0);
}

// ---------------- CSR build ----------------

__global__ void hist_kernel(const int* __restrict__ dst, int* __restrict__ counts, int E) {
  int t = blockIdx.x * 256 + threadIdx.x;
  if (t < E) atomicAdd(&counts[dst[t]], 1);
}

__global__ void scan1(const int* __restrict__ counts, int* __restrict__ offs,
                      int* __restrict__ bsum, int N) {
  __shared__ int sd[1024];
  int tid = threadIdx.x;
  int i = blockIdx.x * 1024 + tid;
  int v = (i < N) ? counts[i] : 0;
  sd[tid] = v;
  __syncthreads();
  for (int s = 1; s < 1024; s <<= 1) {
    int tv = (tid >= s) ? sd[tid - s] : 0;
    __syncthreads();
    sd[tid] += tv;
    __syncthreads();
  }
  if (i < N) offs[i] = sd[tid] - v;  // local exclusive
  if (tid == 1023) bsum[blockIdx.x] = sd[1023];
}

__global__ void scan2(int* __restrict__ bsum, int* __restrict__ offs, int nb, int N, int E) {
  if (threadIdx.x == 0) {
    int r = 0;
    for (int i = 0; i < nb; i++) { int v = bsum[i]; bsum[i] = r; r += v; }
    offs[N] = E;
  }
}

__global__ void scan3(int* __restrict__ offs, const int* __restrict__ bsum, int N) {
  int i = blockIdx.x * 1024 + threadIdx.x;
  if (i < N) offs[i] += bsum[blockIdx.x];
}

__global__ void scatter_kernel(const int* __restrict__ src, const int* __restrict__ dst,
                               const int* __restrict__ off, int* __restrict__ cur,
                               int* __restrict__ srcp, int E) {
  int t = blockIdx.x * 256 + threadIdx.x;
  if (t < E) {
    int d = dst[t];
    int p = off[d] + atomicAdd(&cur[d], 1);
    srcp[p] = src[t];
  }
}

// ---------------- fp32 -> f16 converts ----------------

__global__ void convX(const float* __restrict__ x, _Float16* __restrict__ xh, int n4) {
  int i = blockIdx.x * 256 + threadIdx.x;
  if (i >= n4) return;
  float4 v = ((const float4*)x)[i];
  h4v h;
  h[0] = (_Float16)v.x; h[1] = (_Float16)v.y;
  h[2] = (_Float16)v.z; h[3] = (_Float16)v.w;
  ((h4v*)xh)[i] = h;
}

// W [K][512] f32 -> Wt [512][K] f16 transposed, coalesced via LDS tile.
__global__ void convW(const float* __restrict__ W, _Float16* __restrict__ Th, int K) {
  __shared__ float tile[32][33];
  int bx = blockIdx.x * 32;  // output-col base (N=512 dim)
  int by = blockIdx.y * 32;  // k base
  int tx = threadIdx.x, ty = threadIdx.y;
#pragma unroll
  for (int i = 0; i < 32; i += 8)
    tile[ty + i][tx] = W[(size_t)(by + ty + i) * 512 + bx + tx];
  __syncthreads();
#pragma unroll
  for (int i = 0; i < 32; i += 8)
    Th[(size_t)(bx + ty + i) * K + by + tx] = (_Float16)tile[tx][ty + i];
}

// Ws3 [512][16] -> Bt [16][512]
__global__ void convW3(const float* __restrict__ W, _Float16* __restrict__ Th) {
  int t = blockIdx.x * 256 + threadIdx.x;
  if (t >= 512 * 16) return;
  int k = t >> 4, c = t & 15;
  Th[c * 512 + k] = (_Float16)W[t];
}

// ---------------- f16 MFMA GEMM, 2-phase double-buffered, fused als epilogue ------------
// C[M,512](f16) = A[M,K](f16) @ B[K,512]; B transposed [512][K] f16.
// 128x128 tile, BK=32, 4 waves (2x2), 16x16x32 mfma.
// Fused: als[row, cn>>7] = sum_col C[row,col]*a_s[col] — block covers a full head.
// Bijective XCD swizzle (m204).

#define STAGE(bs, kt)                                  \
  do {                                                 \
    const size_t ko = (size_t)(kt) + w * 8;            \
    char* d0 = sm + (bs) + (w * 128) * 16;             \
    char* d1 = d0 + 1024;                              \
    gll16(A + (tm + l) * K + ko,      d0);             \
    gll16(A + (tm + 64 + l) * K + ko, d1);             \
    gll16(Bh + (cn + l) * K + ko,      d0 + 8192);     \
    gll16(Bh + (cn + 64 + l) * K + ko, d1 + 8192);     \
  } while (0)

template <int K>
__global__ __launch_bounds__(256) void gemm_f16(
    const _Float16* __restrict__ A, const _Float16* __restrict__ Bh,
    const float* __restrict__ a_s, _Float16* __restrict__ C,
    float* __restrict__ als, int M) {
  __shared__ __align__(16) char sm[32768];  // 2 x 16KB
  const int t = threadIdx.x;
  const int w = t >> 6, l = t & 63;
  const int wr = w >> 1, wc = w & 1;
  const int kg = l >> 4, rr = l & 15;

  // bijective XCD swizzle
  const int nwg = gridDim.x;
  const int q = nwg >> 3, r = nwg & 7;
  const int orig = blockIdx.x;
  const int xcd = orig & 7, slot = orig >> 3;
  const int wgid = (xcd < r ? xcd * (q + 1) : r * (q + 1) + (xcd - r) * q) + slot;
  const size_t tm = (size_t)(wgid >> 2) * 128;
  const size_t cn = (size_t)(wgid & 3) * 128;

  f4v acc[4][4];
#pragma unroll
  for (int i = 0; i < 4; i++)
#pragma unroll
    for (int j = 0; j < 4; j++) acc[i][j] = (f4v){0.f, 0.f, 0.f, 0.f};

  STAGE(0, 0);
  __syncthreads();
  int cur = 0;

  for (int kt = 0; kt < K; kt += 32) {
    if (kt + 32 < K) STAGE(cur ^ 16384, kt + 32);  // prefetch next tile over this MFMA

    const char* base = sm + cur;
    h8v ah[4], bh[4];
#pragma unroll
    for (int i = 0; i < 4; i++) {
      int ca = (kg * 128 + wr * 64 + i * 16 + rr) * 16;
      int cb = (kg * 128 + wc * 64 + i * 16 + rr) * 16;
      ah[i] = *(const h8v*)(base + ca);
      bh[i] = *(const h8v*)(base + 8192 + cb);
    }
#pragma unroll
    for (int i = 0; i < 4; i++)
#pragma unroll
      for (int j = 0; j < 4; j++)
        acc[i][j] = __builtin_amdgcn_mfma_f32_16x16x32_f16(ah[i], bh[j], acc[i][j], 0, 0, 0);
    __syncthreads();
    cur ^= 16384;
  }

  // epilogue: C/D layout col=lane&15, row=(lane>>4)*4+reg
  float sp[16];
#pragma unroll
  for (int k = 0; k < 16; k++) sp[k] = 0.f;
#pragma unroll
  for (int i = 0; i < 4; i++) {
    int row0 = wr * 64 + i * 16 + kg * 4;
#pragma unroll
    for (int j = 0; j < 4; j++) {
      int col = wc * 64 + j * 16 + rr;
      float aw = a_s[cn + col];
#pragma unroll
      for (int r2 = 0; r2 < 4; r2++) {
        float v = acc[i][j][r2];
        size_t row = tm + row0 + r2;
        if (row < (size_t)M) C[row * 512 + cn + col] = (_Float16)v;
        sp[i * 4 + r2] += v * aw;
      }
    }
  }
  // reduce sp over the 16 rr lanes (kg preserved)
#pragma unroll
  for (int o = 1; o < 16; o <<= 1)
#pragma unroll
    for (int k = 0; k < 16; k++) sp[k] += __shfl_xor(sp[k], o);
  // combine across the two wc waves via LDS, store als
  float* ap = (float*)sm;
  if (wc == 0 && rr == 0) {
#pragma unroll
    for (int k = 0; k < 16; k++)
      ap[wr * 64 + (k >> 2) * 16 + kg * 4 + (k & 3)] = sp[k];
  }
  __syncthreads();
  if (wc == 1 && rr == 0) {
    int head = (int)(cn >> 7);
#pragma unroll
    for (int k = 0; k < 16; k++) {
      int row = wr * 64 + (k >> 2) * 16 + kg * 4 + (k & 3);
      size_t grow = tm + row;
      if (grow < (size_t)M) als[grow * 4 + head] = ap[row] + sp[k];
    }
  }
}

// ---------------- layer-3 projection via MFMA + fused als3 ----------------
// C[M,16](f32) = A[M,512] @ B[512,16]; one wave per 16-row tile; B^T [16][512] f16.

__global__ __launch_bounds__(256) void gemm3(const _Float16* __restrict__ A,
                                             const _Float16* __restrict__ Bth,
                                             const float* __restrict__ as3,
                                             float* __restrict__ C,
                                             float* __restrict__ als, int M) {
  int wv = threadIdx.x >> 6, l = threadIdx.x & 63;
  size_t tm = ((size_t)blockIdx.x * 4 + wv) * 16;
  if (tm >= (size_t)M) return;
  int rr = l & 15, kg = l >> 4;
  f4v acc = (f4v){0.f, 0.f, 0.f, 0.f};
  for (int kt = 0; kt < 512; kt += 32) {
    int ka = kt + kg * 8;
    h8v a_h = *(const h8v*)&A[(tm + rr) * 512 + ka];
    h8v b_h = *(const h8v*)&Bth[rr * 512 + ka];
    acc = __builtin_amdgcn_mfma_f32_16x16x32_f16(a_h, b_h, acc, 0, 0, 0);
  }
  float aw = as3[rr];
  float s[4];
#pragma unroll
  for (int r = 0; r < 4; r++) s[r] = acc[r] * aw;
#pragma unroll
  for (int o = 1; o < 16; o <<= 1)
#pragma unroll
    for (int r = 0; r < 4; r++) s[r] += __shfl_xor(s[r], o);
#pragma unroll
  for (int r = 0; r < 4; r++) {
    size_t row = tm + kg * 4 + r;
    if (row < (size_t)M) {
      C[row * 16 + rr] = acc[r];
      if (rr == 0) als[row] = s[r];
    }
  }
}

// ---------------- wsd[k][h] = sum_c Wd[k][h*C+c] * a_d[h][c] ----------------

__global__ void wsd_kernel(const float* __restrict__ Wd, const float* __restrict__ a_d,
                           float* __restrict__ wsd, int K, int H, int C) {
  int g = (blockIdx.x * 256 + threadIdx.x) >> 4;
  int l16 = threadIdx.x & 15;
  if (g >= K * H) return;
  int k = g / H, h = g - k * H;
  int ce = C >> 4;
  float s = 0.f;
  for (int j = 0; j < ce; j++) {
    int c = l16 * ce + j;
    s += Wd[(size_t)k * (H * C) + h * C + c] * a_d[h * C + c];
  }
#pragma unroll
  for (int o = 1; o < 16; o <<= 1) s += __shfl_xor(s, o);
  if (l16 == 0) wsd[k * H + h] = s;
}

// ---------------- per-edge normalized softmax weights (ald fused in) ----------------
// H=4: one wave per node. lane = e*4+h. ald computed in-register from own h-row.

template <int K>
__global__ void wgt4_kernel(const float* __restrict__ als, const _Float16* __restrict__ hin,
                            const float* __restrict__ wsd, const int* __restrict__ off,
                            const int* __restrict__ srcp, _Float16* __restrict__ wgt, int N) {
  int wid = threadIdx.x >> 6, lane = threadIdx.x & 63;
  int n = blockIdx.x * 4 + wid;
  if (n >= N) return;
  int p0 = off[n], deg = off[n + 1] - p0;
  if (deg == 0) return;

  // ald for own node: lane covers K/64 consecutive k
  float d0 = 0.f, d1 = 0.f, d2 = 0.f, d3 = 0.f;
  constexpr int KP = K / 64;
  {
    int k0 = lane * KP;
    if constexpr (K == 512) {
      h8v qv = *(const h8v*)&hin[(size_t)n * K + k0];
#pragma unroll
      for (int j = 0; j < 8; j++) {
        float xv = (float)qv[j];
        float4 wv = *(const float4*)&wsd[(k0 + j) * 4];
        d0 += xv * wv.x; d1 += xv * wv.y; d2 += xv * wv.z; d3 += xv * wv.w;
      }
    } else {
      h2v qv = *(const h2v*)&hin[(size_t)n * K + k0];
#pragma unroll
      for (int j = 0; j < KP; j++) {
        float xv = (float)qv[j];
        float4 wv = *(const float4*)&wsd[(k0 + j) * 4];
        d0 += xv * wv.x; d1 += xv * wv.y; d2 += xv * wv.z; d3 += xv * wv.w;
      }
    }
#pragma unroll
    for (int o = 1; o < 64; o <<= 1) {
      d0 += __shfl_xor(d0, o); d1 += __shfl_xor(d1, o);
      d2 += __shfl_xor(d2, o); d3 += __shfl_xor(d3, o);
    }
  }
  int h = lane & 3, e = lane >> 2;
  float aldn = (h == 0) ? d0 : (h == 1) ? d1 : (h == 2) ? d2 : d3;

  float ev0 = -1e30f;
  if (e < deg) {
    float v = als[srcp[p0 + e] * 4 + h] + aldn;
    ev0 = (v > 0.f) ? v : NEG_SLOPE * v;
  }
  float m = ev0;
  for (int base = 16; base < deg; base += 16) {
    float ev = -1e30f;
    if (base + e < deg) {
      float v = als[srcp[p0 + base + e] * 4 + h] + aldn;
      ev = (v > 0.f) ? v : NEG_SLOPE * v;
    }
    m = fmaxf(m, ev);
  }
#pragma unroll
  for (int o = 4; o < 64; o <<= 1) m = fmaxf(m, __shfl_xor(m, o));
  float den = (e < deg) ? __expf(ev0 - m) : 0.f;
  for (int base = 16; base < deg; base += 16) {
    if (base + e < deg) {
      float v = als[srcp[p0 + base + e] * 4 + h] + aldn;
      v = (v > 0.f) ? v : NEG_SLOPE * v;
      den += __expf(v - m);
    }
  }
#pragma unroll
  for (int o = 4; o < 64; o <<= 1) den += __shfl_xor(den, o);
  float rw = 1.f / (den + EPSF);
  if (e < deg) wgt[(size_t)(p0 + e) * 4 + h] = (_Float16)(__expf(ev0 - m) * rw);
  for (int base = 16; base < deg; base += 16) {
    if (base + e < deg) {
      float v = als[srcp[p0 + base + e] * 4 + h] + aldn;
      v = (v > 0.f) ? v : NEG_SLOPE * v;
      wgt[(size_t)(p0 + base + e) * 4 + h] = (_Float16)(__expf(v - m) * rw);
    }
  }
}

// H=1: one wave per node, lane = edge slot; ald fused (own h-row · wsd).
__global__ void wgt1_kernel(const float* __restrict__ als, const _Float16* __restrict__ hin,
                            const float* __restrict__ wsd, const int* __restrict__ off,
                            const int* __restrict__ srcp, _Float16* __restrict__ wgt, int N) {
  int wid = threadIdx.x >> 6, lane = threadIdx.x & 63;
  int n = blockIdx.x * 4 + wid;
  if (n >= N) return;
  int p0 = off[n], deg = off[n + 1] - p0;
  if (deg == 0) return;

  float aldn = 0.f;
  {
    h8v qv = *(const h8v*)&hin[(size_t)n * 512 + lane * 8];
#pragma unroll
    for (int j = 0; j < 8; j++) aldn += (float)qv[j] * wsd[lane * 8 + j];
#pragma unroll
    for (int o = 1; o < 64; o <<= 1) aldn += __shfl_xor(aldn, o);
  }

  float ev0 = -1e30f;
  if (lane < deg) {
    float v = als[srcp[p0 + lane]] + aldn;
    ev0 = (v > 0.f) ? v : NEG_SLOPE * v;
  }
  float m = ev0;
  for (int base = 64; base < deg; base += 64) {
    float ev = -1e30f;
    if (base + lane < deg) {
      float v = als[srcp[p0 + base + lane]] + aldn;
      ev = (v > 0.f) ? v : NEG_SLOPE * v;
    }
    m = fmaxf(m, ev);
  }
#pragma unroll
  for (int o = 1; o < 64; o <<= 1) m = fmaxf(m, __shfl_xor(m, o));
  float den = (lane < deg) ? __expf(ev0 - m) : 0.f;
  for (int base = 64; base < deg; base += 64) {
    if (base + lane < deg) {
      float v = als[srcp[p0 + base + lane]] + aldn;
      v = (v > 0.f) ? v : NEG_SLOPE * v;
      den += __expf(v - m);
    }
  }
#pragma unroll
  for (int o = 1; o < 64; o <<= 1) den += __shfl_xor(den, o);
  float rw = 1.f / (den + EPSF);
  if (lane < deg) wgt[p0 + lane] = (_Float16)(__expf(ev0 - m) * rw);
  for (int base = 64; base < deg; base += 64) {
    if (base + lane < deg) {
      float v = als[srcp[p0 + base + lane]] + aldn;
      v = (v > 0.f) ? v : NEG_SLOPE * v;
      wgt[p0 + base + lane] = (_Float16)(__expf(v - m) * rw);
    }
  }
}

// ---------------- aggregation: single weighted-gather pass ----------------
// layers 1,2: one 128-thread block per node, thread t handles channels 4t..4t+3.

__global__ __launch_bounds__(128) void agg512(
    const _Float16* __restrict__ xs, const _Float16* __restrict__ wgt,
    const int* __restrict__ off, const int* __restrict__ srcp,
    const float* __restrict__ bias, _Float16* __restrict__ oh, int N) {
  int n = blockIdx.x;
  int t = threadIdx.x;
  int h = t >> 5;  // channel 4t -> head 4t/128
  int p0 = off[n], p1 = off[n + 1];
  float a0 = 0.f, a1 = 0.f, a2 = 0.f, a3 = 0.f;
  float c0 = 0.f, c1 = 0.f, c2 = 0.f, c3 = 0.f;
  int p = p0;
  for (; p + 1 < p1; p += 2) {
    int s0 = srcp[p], s1 = srcp[p + 1];
    float w0 = (float)wgt[(size_t)p * 4 + h];
    float w1 = (float)wgt[(size_t)(p + 1) * 4 + h];
    h4v v0 = *(const h4v*)&xs[(size_t)s0 * 512 + 4 * t];
    h4v v1 = *(const h4v*)&xs[(size_t)s1 * 512 + 4 * t];
    a0 += w0 * (float)v0[0]; a1 += w0 * (float)v0[1];
    a2 += w0 * (float)v0[2]; a3 += w0 * (float)v0[3];
    c0 += w1 * (float)v1[0]; c1 += w1 * (float)v1[1];
    c2 += w1 * (float)v1[2]; c3 += w1 * (float)v1[3];
  }
  if (p < p1) {
    int s0 = srcp[p];
    float w0 = (float)wgt[(size_t)p * 4 + h];
    h4v v0 = *(const h4v*)&xs[(size_t)s0 * 512 + 4 * t];
    a0 += w0 * (float)v0[0]; a1 += w0 * (float)v0[1];
    a2 += w0 * (float)v0[2]; a3 += w0 * (float)v0[3];
  }
  a0 += c0; a1 += c1; a2 += c2; a3 += c3;
  float4 b = *(const float4*)&bias[4 * t];
  a0 = fmaxf(a0 + b.x, 0.f); a1 = fmaxf(a1 + b.y, 0.f);
  a2 = fmaxf(a2 + b.z, 0.f); a3 = fmaxf(a3 + b.w, 0.f);
  h4v wh;
  wh[0] = (_Float16)a0; wh[1] = (_Float16)a1;
  wh[2] = (_Float16)a2; wh[3] = (_Float16)a3;
  *(h4v*)&oh[(size_t)n * 512 + 4 * t] = wh;
}

// layer 3: H=1, C=16, no relu, f32 out. 16 nodes per block.
__global__ void agg16(const float* __restrict__ xs3, const _Float16* __restrict__ wgt,
                      const int* __restrict__ off, const int* __restrict__ srcp,
                      const float* __restrict__ bias, float* __restrict__ out, int N) {
  int g = threadIdx.x >> 4, c = threadIdx.x & 15;
  int n = blockIdx.x * 16 + g;
  if (n >= N) return;
  int p0 = off[n], p1 = off[n + 1];
  float acc = 0.f;
  for (int p = p0; p < p1; p++)
    acc += (float)wgt[p] * xs3[(size_t)srcp[p] * 16 + c];
  out[(size_t)n * 16 + c] = acc + bias[c];
}

// ---------------- launch ----------------

extern "C" void kernel_launch(void* const* d_in, const int* in_sizes, int n_in,
                              void* d_out, int out_size, void* d_ws, size_t ws_size,
                              hipStream_t stream) {
  const float* x   = (const float*)d_in[0];
  const int*   ei  = (const int*)d_in[1];
  const float* Ws1 = (const float*)d_in[2];
  const float* Wd1 = (const float*)d_in[3];
  const float* as1 = (const float*)d_in[4];
  const float* ad1 = (const float*)d_in[5];
  const float* b1  = (const float*)d_in[6];
  const float* Ws2 = (const float*)d_in[7];
  const float* Wd2 = (const float*)d_in[8];
  const float* as2 = (const float*)d_in[9];
  const float* ad2 = (const float*)d_in[10];
  const float* b2  = (const float*)d_in[11];
  const float* Ws3 = (const float*)d_in[12];
  const float* Wd3 = (const float*)d_in[13];
  const float* as3 = (const float*)d_in[14];
  const float* ad3 = (const float*)d_in[15];
  const float* b3  = (const float*)d_in[16];

  const int N = in_sizes[0] / 128;  // 50000
  const int E = in_sizes[1] / 2;    // 400000
  const int* src = ei;
  const int* dst = ei + E;

  // workspace layout (bytes), total ~113 MB; all offsets 16B-aligned
  char* w = (char*)d_ws;
  _Float16* xs     = (_Float16*)(w + 0);           // [N,512] f16
  _Float16* hbuf   = (_Float16*)(w + 51200000);    // [N,512] f16 ([N,128] x_f16 early)
  float*    als    = (float*)(w + 102400000);      // [N,4] (layer3: [N] flat)
  float*    xs3    = (float*)(w + 104000000);      // [N,16] f32
  _Float16* wgt    = (_Float16*)(w + 107200000);   // [E,4] f16
  int*      counts = (int*)(w + 110400000);        // [N]
  int*      cur    = (int*)(w + 110600000);        // [N]
  int*      offs   = (int*)(w + 110800000);        // [N+1]
  int*      bsum   = (int*)(w + 111000192);        // [~49]
  int*      srcp   = (int*)(w + 111004288);        // [E]
  float*    wsd    = (float*)(w + 112604288);      // [512,4]
  _Float16* wt_hi  = (_Float16*)(w + 112612480);   // [512,512] f16 (B^T)
  _Float16* wt3_hi = (_Float16*)(w + 113136768);   // [16,512] f16

  // ---- CSR build ----
  hipMemsetAsync(counts, 0, 2 * (size_t)N * 4, stream);  // counts + cur contiguous
  hist_kernel<<<(E + 255) / 256, 256, 0, stream>>>(dst, counts, E);
  int nb = (N + 1023) / 1024;
  scan1<<<nb, 1024, 0, stream>>>(counts, offs, bsum, N);
  scan2<<<1, 64, 0, stream>>>(bsum, offs, nb, N, E);
  scan3<<<nb, 1024, 0, stream>>>(offs, bsum, N);
  scatter_kernel<<<(E + 255) / 256, 256, 0, stream>>>(src, dst, offs, cur, srcp, E);

  int ggrid = ((N + 127) / 128) * 4;  // 1-D grid; XCD swizzle inside kernel
  dim3 cwb(32, 8);
  int nwb = (N + 3) / 4;

  // ---- layer 1 (K=128) ----
  convX<<<(N * 128 / 4 + 255) / 256, 256, 0, stream>>>(x, hbuf, N * 128 / 4);
  wsd_kernel<<<(128 * 4 * 16 + 255) / 256, 256, 0, stream>>>(Wd1, ad1, wsd, 128, 4, 128);
  convW<<<dim3(16, 4), cwb, 0, stream>>>(Ws1, wt_hi, 128);
  gemm_f16<128><<<ggrid, 256, 0, stream>>>(hbuf, wt_hi, as1, xs, als, N);
  wgt4_kernel<128><<<nwb, 256, 0, stream>>>(als, hbuf, wsd, offs, srcp, wgt, N);
  agg512<<<N, 128, 0, stream>>>(xs, wgt, offs, srcp, b1, hbuf, N);

  // ---- layer 2 (K=512) ----
  wsd_kernel<<<(512 * 4 * 16 + 255) / 256, 256, 0, stream>>>(Wd2, ad2, wsd, 512, 4, 128);
  convW<<<dim3(16, 16), cwb, 0, stream>>>(Ws2, wt_hi, 512);
  gemm_f16<512><<<ggrid, 256, 0, stream>>>(hbuf, wt_hi, as2, xs, als, N);
  wgt4_kernel<512><<<nwb, 256, 0, stream>>>(als, hbuf, wsd, offs, srcp, wgt, N);
  agg512<<<N, 128, 0, stream>>>(xs, wgt, offs, srcp, b2, hbuf, N);

  // ---- layer 3 (K=512, N=16, H=1) ----
  wsd_kernel<<<(512 * 16 + 255) / 256, 256, 0, stream>>>(Wd3, ad3, wsd, 512, 1, 16);
  convW3<<<32, 256, 0, stream>>>(Ws3, wt3_hi);
  gemm3<<<(N / 16 + 4) / 4, 256, 0, stream>>>(hbuf, wt3_hi, as3, xs3, als, N);
  wgt1_kernel<<<nwb, 256, 0, stream>>>(als, hbuf, wsd, offs, srcp, wgt, N);
  agg16<<<(N + 15) / 16, 256, 0, stream>>>(xs3, wgt, offs, srcp, b3, (float*)d_out, N);
}

// Round 9
// 512.898 us; speedup vs baseline: 2.3788x; 1.0255x over previous
//
#include <hip/hip_runtime.h>
#include <math.h>

#define NEG_SLOPE 0.2f
#define EPSF 1e-16f

typedef _Float16 h2v __attribute__((ext_vector_type(2)));
typedef _Float16 h4v __attribute__((ext_vector_type(4)));
typedef _Float16 h8v __attribute__((ext_vector_type(8)));
typedef float f4v __attribute__((ext_vector_type(4)));

#define AS1 __attribute__((address_space(1)))
#define AS3 __attribute__((address_space(3)))

__device__ __forceinline__ void gll16(const void* g, void* l) {
  __builtin_amdgcn_global_load_lds((AS1 void*)g, (AS3 void*)l, 16, 0, 0);
}

// ---------------- CSR build ----------------

__global__ void hist_kernel(const int* __restrict__ dst, int* __restrict__ counts, int E) {
  int t = blockIdx.x * 256 + threadIdx.x;
  if (t < E) atomicAdd(&counts[dst[t]], 1);
}

__global__ void scan1(const int* __restrict__ counts, int* __restrict__ offs,
                      int* __restrict__ bsum, int N) {
  __shared__ int sd[1024];
  int tid = threadIdx.x;
  int i = blockIdx.x * 1024 + tid;
  int v = (i < N) ? counts[i] : 0;
  sd[tid] = v;
  __syncthreads();
  for (int s = 1; s < 1024; s <<= 1) {
    int tv = (tid >= s) ? sd[tid - s] : 0;
    __syncthreads();
    sd[tid] += tv;
    __syncthreads();
  }
  if (i < N) offs[i] = sd[tid] - v;  // local exclusive
  if (tid == 1023) bsum[blockIdx.x] = sd[1023];
}

__global__ void scan2(int* __restrict__ bsum, int* __restrict__ offs, int nb, int N, int E) {
  if (threadIdx.x == 0) {
    int r = 0;
    for (int i = 0; i < nb; i++) { int v = bsum[i]; bsum[i] = r; r += v; }
    offs[N] = E;
  }
}

__global__ void scan3(int* __restrict__ offs, const int* __restrict__ bsum, int N) {
  int i = blockIdx.x * 1024 + threadIdx.x;
  if (i < N) offs[i] += bsum[blockIdx.x];
}

__global__ void scatter_kernel(const int* __restrict__ src, const int* __restrict__ dst,
                               const int* __restrict__ off, int* __restrict__ cur,
                               int* __restrict__ srcp, int E) {
  int t = blockIdx.x * 256 + threadIdx.x;
  if (t < E) {
    int d = dst[t];
    int p = off[d] + atomicAdd(&cur[d], 1);
    srcp[p] = src[t];
  }
}

// ---------------- fp32 -> f16 converts ----------------

__global__ void convX(const float* __restrict__ x, _Float16* __restrict__ xh, int n4) {
  int i = blockIdx.x * 256 + threadIdx.x;
  if (i >= n4) return;
  float4 v = ((const float4*)x)[i];
  h4v h;
  h[0] = (_Float16)v.x; h[1] = (_Float16)v.y;
  h[2] = (_Float16)v.z; h[3] = (_Float16)v.w;
  ((h4v*)xh)[i] = h;
}

// W [K][512] f32 -> Wt [512][K] f16 transposed, coalesced via LDS tile.
__global__ void convW(const float* __restrict__ W, _Float16* __restrict__ Th, int K) {
  __shared__ float tile[32][33];
  int bx = blockIdx.x * 32;  // output-col base (N=512 dim)
  int by = blockIdx.y * 32;  // k base
  int tx = threadIdx.x, ty = threadIdx.y;
#pragma unroll
  for (int i = 0; i < 32; i += 8)
    tile[ty + i][tx] = W[(size_t)(by + ty + i) * 512 + bx + tx];
  __syncthreads();
#pragma unroll
  for (int i = 0; i < 32; i += 8)
    Th[(size_t)(bx + ty + i) * K + by + tx] = (_Float16)tile[tx][ty + i];
}

// Ws3 [512][16] -> Bt [16][512]
__global__ void convW3(const float* __restrict__ W, _Float16* __restrict__ Th) {
  int t = blockIdx.x * 256 + threadIdx.x;
  if (t >= 512 * 16) return;
  int k = t >> 4, c = t & 15;
  Th[c * 512 + k] = (_Float16)W[t];
}

// ---------------- f16 MFMA GEMM, 3-buffer counted-vmcnt pipeline, fused als ------------
// C[M,512](f16) = A[M,K](f16) @ B[K,512]; B transposed [512][K] f16.
// 128x128 tile, BK=32, 4 waves (2x2), 16x16x32 mfma.
// Pipeline (T3/T4): 3 x 16KB LDS buffers; one raw s_barrier per K-step; counted
// s_waitcnt vmcnt(4) keeps the next tile's 4 global_load_lds IN FLIGHT across the
// barrier (never drains to 0 until the last step). Invariant at iter entry:
// outstanding = {cur(4), nxt(4)}; vmcnt(4) => cur landed; stage 3rd after barrier.
// Fused: als[row, cn>>7] = sum_col C[row,col]*a_s[col]. Bijective XCD swizzle (m204).

#define STAGE(bs, kt)                                  \
  do {                                                 \
    const size_t ko = (size_t)(kt) + w * 8;            \
    char* d0 = sm + (bs) + (w * 128) * 16;             \
    char* d1 = d0 + 1024;                              \
    gll16(A + (tm + l) * K + ko,      d0);             \
    gll16(A + (tm + 64 + l) * K + ko, d1);             \
    gll16(Bh + (cn + l) * K + ko,      d0 + 8192);     \
    gll16(Bh + (cn + 64 + l) * K + ko, d1 + 8192);     \
  } while (0)

template <int K>
__global__ __launch_bounds__(256) void gemm_f16(
    const _Float16* __restrict__ A, const _Float16* __restrict__ Bh,
    const float* __restrict__ a_s, _Float16* __restrict__ C,
    float* __restrict__ als, int M) {
  __shared__ __align__(16) char sm[49152];  // 3 x 16KB
  const int t = threadIdx.x;
  const int w = t >> 6, l = t & 63;
  const int wr = w >> 1, wc = w & 1;
  const int kg = l >> 4, rr = l & 15;

  // bijective XCD swizzle
  const int nwg = gridDim.x;
  const int q = nwg >> 3, r = nwg & 7;
  const int orig = blockIdx.x;
  const int xcd = orig & 7, slot = orig >> 3;
  const int wgid = (xcd < r ? xcd * (q + 1) : r * (q + 1) + (xcd - r) * q) + slot;
  const size_t tm = (size_t)(wgid >> 2) * 128;
  const size_t cn = (size_t)(wgid & 3) * 128;

  f4v acc[4][4];
#pragma unroll
  for (int i = 0; i < 4; i++)
#pragma unroll
    for (int j = 0; j < 4; j++) acc[i][j] = (f4v){0.f, 0.f, 0.f, 0.f};

  // prologue: stage first two K-tiles (8 loads outstanding per wave)
  STAGE(0, 0);
  STAGE(16384, 32);
  int o_cur = 0, o_nxt = 16384, o_3rd = 32768;

#pragma unroll 4
  for (int kt = 0; kt < K; kt += 32) {
    if (kt + 32 < K) {
      asm volatile("s_waitcnt vmcnt(4)" ::: "memory");  // cur's 4 landed; nxt in flight
    } else {
      asm volatile("s_waitcnt vmcnt(0)" ::: "memory");  // last tile: full drain
    }
    __builtin_amdgcn_sched_barrier(0);
    __builtin_amdgcn_s_barrier();   // all waves' cur-loads landed; readers of o_3rd done
    if (kt + 64 < K) STAGE(o_3rd, kt + 64);  // overlaps this step's MFMA

    const char* base = sm + o_cur;
    h8v ah[4], bh[4];
#pragma unroll
    for (int i = 0; i < 4; i++) {
      int ca = (kg * 128 + wr * 64 + i * 16 + rr) * 16;
      int cb = (kg * 128 + wc * 64 + i * 16 + rr) * 16;
      ah[i] = *(const h8v*)(base + ca);
      bh[i] = *(const h8v*)(base + 8192 + cb);
    }
#pragma unroll
    for (int i = 0; i < 4; i++)
#pragma unroll
      for (int j = 0; j < 4; j++)
        acc[i][j] = __builtin_amdgcn_mfma_f32_16x16x32_f16(ah[i], bh[j], acc[i][j], 0, 0, 0);

    int tmp = o_cur; o_cur = o_nxt; o_nxt = o_3rd; o_3rd = tmp;
  }

  // epilogue: C/D layout col=lane&15, row=(lane>>4)*4+reg
  float sp[16];
#pragma unroll
  for (int k = 0; k < 16; k++) sp[k] = 0.f;
#pragma unroll
  for (int i = 0; i < 4; i++) {
    int row0 = wr * 64 + i * 16 + kg * 4;
#pragma unroll
    for (int j = 0; j < 4; j++) {
      int col = wc * 64 + j * 16 + rr;
      float aw = a_s[cn + col];
#pragma unroll
      for (int r2 = 0; r2 < 4; r2++) {
        float v = acc[i][j][r2];
        size_t row = tm + row0 + r2;
        if (row < (size_t)M) C[row * 512 + cn + col] = (_Float16)v;
        sp[i * 4 + r2] += v * aw;
      }
    }
  }
  // reduce sp over the 16 rr lanes (kg preserved)
#pragma unroll
  for (int o = 1; o < 16; o <<= 1)
#pragma unroll
    for (int k = 0; k < 16; k++) sp[k] += __shfl_xor(sp[k], o);
  // combine across the two wc waves via LDS, store als
  __syncthreads();  // all waves done with main-loop LDS before reuse
  float* ap = (float*)sm;
  if (wc == 0 && rr == 0) {
#pragma unroll
    for (int k = 0; k < 16; k++)
      ap[wr * 64 + (k >> 2) * 16 + kg * 4 + (k & 3)] = sp[k];
  }
  __syncthreads();
  if (wc == 1 && rr == 0) {
    int head = (int)(cn >> 7);
#pragma unroll
    for (int k = 0; k < 16; k++) {
      int row = wr * 64 + (k >> 2) * 16 + kg * 4 + (k & 3);
      size_t grow = tm + row;
      if (grow < (size_t)M) als[grow * 4 + head] = ap[row] + sp[k];
    }
  }
}

// ---------------- layer-3 projection via MFMA + fused als3 ----------------
// C[M,16](f32) = A[M,512] @ B[512,16]; one wave per 16-row tile; B^T [16][512] f16.

__global__ __launch_bounds__(256) void gemm3(const _Float16* __restrict__ A,
                                             const _Float16* __restrict__ Bth,
                                             const float* __restrict__ as3,
                                             float* __restrict__ C,
                                             float* __restrict__ als, int M) {
  int wv = threadIdx.x >> 6, l = threadIdx.x & 63;
  size_t tm = ((size_t)blockIdx.x * 4 + wv) * 16;
  if (tm >= (size_t)M) return;
  int rr = l & 15, kg = l >> 4;
  f4v acc = (f4v){0.f, 0.f, 0.f, 0.f};
  for (int kt = 0; kt < 512; kt += 32) {
    int ka = kt + kg * 8;
    h8v a_h = *(const h8v*)&A[(tm + rr) * 512 + ka];
    h8v b_h = *(const h8v*)&Bth[rr * 512 + ka];
    acc = __builtin_amdgcn_mfma_f32_16x16x32_f16(a_h, b_h, acc, 0, 0, 0);
  }
  float aw = as3[rr];
  float s[4];
#pragma unroll
  for (int r = 0; r < 4; r++) s[r] = acc[r] * aw;
#pragma unroll
  for (int o = 1; o < 16; o <<= 1)
#pragma unroll
    for (int r = 0; r < 4; r++) s[r] += __shfl_xor(s[r], o);
#pragma unroll
  for (int r = 0; r < 4; r++) {
    size_t row = tm + kg * 4 + r;
    if (row < (size_t)M) {
      C[row * 16 + rr] = acc[r];
      if (rr == 0) als[row] = s[r];
    }
  }
}

// ---------------- wsd[k][h] = sum_c Wd[k][h*C+c] * a_d[h][c] ----------------

__global__ void wsd_kernel(const float* __restrict__ Wd, const float* __restrict__ a_d,
                           float* __restrict__ wsd, int K, int H, int C) {
  int g = (blockIdx.x * 256 + threadIdx.x) >> 4;
  int l16 = threadIdx.x & 15;
  if (g >= K * H) return;
  int k = g / H, h = g - k * H;
  int ce = C >> 4;
  float s = 0.f;
  for (int j = 0; j < ce; j++) {
    int c = l16 * ce + j;
    s += Wd[(size_t)k * (H * C) + h * C + c] * a_d[h * C + c];
  }
#pragma unroll
  for (int o = 1; o < 16; o <<= 1) s += __shfl_xor(s, o);
  if (l16 == 0) wsd[k * H + h] = s;
}

// ---------------- per-edge normalized softmax weights (ald fused in) ----------------
// H=4: one wave per node. lane = e*4+h. ald computed in-register from own h-row.

template <int K>
__global__ void wgt4_kernel(const float* __restrict__ als, const _Float16* __restrict__ hin,
                            const float* __restrict__ wsd, const int* __restrict__ off,
                            const int* __restrict__ srcp, _Float16* __restrict__ wgt, int N) {
  int wid = threadIdx.x >> 6, lane = threadIdx.x & 63;
  int n = blockIdx.x * 4 + wid;
  if (n >= N) return;
  int p0 = off[n], deg = off[n + 1] - p0;
  if (deg == 0) return;

  // ald for own node: lane covers K/64 consecutive k
  float d0 = 0.f, d1 = 0.f, d2 = 0.f, d3 = 0.f;
  constexpr int KP = K / 64;
  {
    int k0 = lane * KP;
    if constexpr (K == 512) {
      h8v qv = *(const h8v*)&hin[(size_t)n * K + k0];
#pragma unroll
      for (int j = 0; j < 8; j++) {
        float xv = (float)qv[j];
        float4 wv = *(const float4*)&wsd[(k0 + j) * 4];
        d0 += xv * wv.x; d1 += xv * wv.y; d2 += xv * wv.z; d3 += xv * wv.w;
      }
    } else {
      h2v qv = *(const h2v*)&hin[(size_t)n * K + k0];
#pragma unroll
      for (int j = 0; j < KP; j++) {
        float xv = (float)qv[j];
        float4 wv = *(const float4*)&wsd[(k0 + j) * 4];
        d0 += xv * wv.x; d1 += xv * wv.y; d2 += xv * wv.z; d3 += xv * wv.w;
      }
    }
#pragma unroll
    for (int o = 1; o < 64; o <<= 1) {
      d0 += __shfl_xor(d0, o); d1 += __shfl_xor(d1, o);
      d2 += __shfl_xor(d2, o); d3 += __shfl_xor(d3, o);
    }
  }
  int h = lane & 3, e = lane >> 2;
  float aldn = (h == 0) ? d0 : (h == 1) ? d1 : (h == 2) ? d2 : d3;

  float ev0 = -1e30f;
  if (e < deg) {
    float v = als[srcp[p0 + e] * 4 + h] + aldn;
    ev0 = (v > 0.f) ? v : NEG_SLOPE * v;
  }
  float m = ev0;
  for (int base = 16; base < deg; base += 16) {
    float ev = -1e30f;
    if (base + e < deg) {
      float v = als[srcp[p0 + base + e] * 4 + h] + aldn;
      ev = (v > 0.f) ? v : NEG_SLOPE * v;
    }
    m = fmaxf(m, ev);
  }
#pragma unroll
  for (int o = 4; o < 64; o <<= 1) m = fmaxf(m, __shfl_xor(m, o));
  float den = (e < deg) ? __expf(ev0 - m) : 0.f;
  for (int base = 16; base < deg; base += 16) {
    if (base + e < deg) {
      float v = als[srcp[p0 + base + e] * 4 + h] + aldn;
      v = (v > 0.f) ? v : NEG_SLOPE * v;
      den += __expf(v - m);
    }
  }
#pragma unroll
  for (int o = 4; o < 64; o <<= 1) den += __shfl_xor(den, o);
  float rw = 1.f / (den + EPSF);
  if (e < deg) wgt[(size_t)(p0 + e) * 4 + h] = (_Float16)(__expf(ev0 - m) * rw);
  for (int base = 16; base < deg; base += 16) {
    if (base + e < deg) {
      float v = als[srcp[p0 + base + e] * 4 + h] + aldn;
      v = (v > 0.f) ? v : NEG_SLOPE * v;
      wgt[(size_t)(p0 + base + e) * 4 + h] = (_Float16)(__expf(v - m) * rw);
    }
  }
}

// H=1: one wave per node, lane = edge slot; ald fused (own h-row · wsd).
__global__ void wgt1_kernel(const float* __restrict__ als, const _Float16* __restrict__ hin,
                            const float* __restrict__ wsd, const int* __restrict__ off,
                            const int* __restrict__ srcp, _Float16* __restrict__ wgt, int N) {
  int wid = threadIdx.x >> 6, lane = threadIdx.x & 63;
  int n = blockIdx.x * 4 + wid;
  if (n >= N) return;
  int p0 = off[n], deg = off[n + 1] - p0;
  if (deg == 0) return;

  float aldn = 0.f;
  {
    h8v qv = *(const h8v*)&hin[(size_t)n * 512 + lane * 8];
#pragma unroll
    for (int j = 0; j < 8; j++) aldn += (float)qv[j] * wsd[lane * 8 + j];
#pragma unroll
    for (int o = 1; o < 64; o <<= 1) aldn += __shfl_xor(aldn, o);
  }

  float ev0 = -1e30f;
  if (lane < deg) {
    float v = als[srcp[p0 + lane]] + aldn;
    ev0 = (v > 0.f) ? v : NEG_SLOPE * v;
  }
  float m = ev0;
  for (int base = 64; base < deg; base += 64) {
    float ev = -1e30f;
    if (base + lane < deg) {
      float v = als[srcp[p0 + base + lane]] + aldn;
      ev = (v > 0.f) ? v : NEG_SLOPE * v;
    }
    m = fmaxf(m, ev);
  }
#pragma unroll
  for (int o = 1; o < 64; o <<= 1) m = fmaxf(m, __shfl_xor(m, o));
  float den = (lane < deg) ? __expf(ev0 - m) : 0.f;
  for (int base = 64; base < deg; base += 64) {
    if (base + lane < deg) {
      float v = als[srcp[p0 + base + lane]] + aldn;
      v = (v > 0.f) ? v : NEG_SLOPE * v;
      den += __expf(v - m);
    }
  }
#pragma unroll
  for (int o = 1; o < 64; o <<= 1) den += __shfl_xor(den, o);
  float rw = 1.f / (den + EPSF);
  if (lane < deg) wgt[p0 + lane] = (_Float16)(__expf(ev0 - m) * rw);
  for (int base = 64; base < deg; base += 64) {
    if (base + lane < deg) {
      float v = als[srcp[p0 + base + lane]] + aldn;
      v = (v > 0.f) ? v : NEG_SLOPE * v;
      wgt[p0 + base + lane] = (_Float16)(__expf(v - m) * rw);
    }
  }
}

// ---------------- aggregation: single weighted-gather pass ----------------
// layers 1,2: one 128-thread block per node, thread t handles channels 4t..4t+3.

__global__ __launch_bounds__(128) void agg512(
    const _Float16* __restrict__ xs, const _Float16* __restrict__ wgt,
    const int* __restrict__ off, const int* __restrict__ srcp,
    const float* __restrict__ bias, _Float16* __restrict__ oh, int N) {
  int n = blockIdx.x;
  int t = threadIdx.x;
  int h = t >> 5;  // channel 4t -> head 4t/128
  int p0 = off[n], p1 = off[n + 1];
  float a0 = 0.f, a1 = 0.f, a2 = 0.f, a3 = 0.f;
  float c0 = 0.f, c1 = 0.f, c2 = 0.f, c3 = 0.f;
  int p = p0;
  for (; p + 1 < p1; p += 2) {
    int s0 = srcp[p], s1 = srcp[p + 1];
    float w0 = (float)wgt[(size_t)p * 4 + h];
    float w1 = (float)wgt[(size_t)(p + 1) * 4 + h];
    h4v v0 = *(const h4v*)&xs[(size_t)s0 * 512 + 4 * t];
    h4v v1 = *(const h4v*)&xs[(size_t)s1 * 512 + 4 * t];
    a0 += w0 * (float)v0[0]; a1 += w0 * (float)v0[1];
    a2 += w0 * (float)v0[2]; a3 += w0 * (float)v0[3];
    c0 += w1 * (float)v1[0]; c1 += w1 * (float)v1[1];
    c2 += w1 * (float)v1[2]; c3 += w1 * (float)v1[3];
  }
  if (p < p1) {
    int s0 = srcp[p];
    float w0 = (float)wgt[(size_t)p * 4 + h];
    h4v v0 = *(const h4v*)&xs[(size_t)s0 * 512 + 4 * t];
    a0 += w0 * (float)v0[0]; a1 += w0 * (float)v0[1];
    a2 += w0 * (float)v0[2]; a3 += w0 * (float)v0[3];
  }
  a0 += c0; a1 += c1; a2 += c2; a3 += c3;
  float4 b = *(const float4*)&bias[4 * t];
  a0 = fmaxf(a0 + b.x, 0.f); a1 = fmaxf(a1 + b.y, 0.f);
  a2 = fmaxf(a2 + b.z, 0.f); a3 = fmaxf(a3 + b.w, 0.f);
  h4v wh;
  wh[0] = (_Float16)a0; wh[1] = (_Float16)a1;
  wh[2] = (_Float16)a2; wh[3] = (_Float16)a3;
  *(h4v*)&oh[(size_t)n * 512 + 4 * t] = wh;
}

// layer 3: H=1, C=16, no relu, f32 out. 16 nodes per block.
__global__ void agg16(const float* __restrict__ xs3, const _Float16* __restrict__ wgt,
                      const int* __restrict__ off, const int* __restrict__ srcp,
                      const float* __restrict__ bias, float* __restrict__ out, int N) {
  int g = threadIdx.x >> 4, c = threadIdx.x & 15;
  int n = blockIdx.x * 16 + g;
  if (n >= N) return;
  int p0 = off[n], p1 = off[n + 1];
  float acc = 0.f;
  for (int p = p0; p < p1; p++)
    acc += (float)wgt[p] * xs3[(size_t)srcp[p] * 16 + c];
  out[(size_t)n * 16 + c] = acc + bias[c];
}

// ---------------- launch ----------------

extern "C" void kernel_launch(void* const* d_in, const int* in_sizes, int n_in,
                              void* d_out, int out_size, void* d_ws, size_t ws_size,
                              hipStream_t stream) {
  const float* x   = (const float*)d_in[0];
  const int*   ei  = (const int*)d_in[1];
  const float* Ws1 = (const float*)d_in[2];
  const float* Wd1 = (const float*)d_in[3];
  const float* as1 = (const float*)d_in[4];
  const float* ad1 = (const float*)d_in[5];
  const float* b1  = (const float*)d_in[6];
  const float* Ws2 = (const float*)d_in[7];
  const float* Wd2 = (const float*)d_in[8];
  const float* as2 = (const float*)d_in[9];
  const float* ad2 = (const float*)d_in[10];
  const float* b2  = (const float*)d_in[11];
  const float* Ws3 = (const float*)d_in[12];
  const float* Wd3 = (const float*)d_in[13];
  const float* as3 = (const float*)d_in[14];
  const float* ad3 = (const float*)d_in[15];
  const float* b3  = (const float*)d_in[16];

  const int N = in_sizes[0] / 128;  // 50000
  const int E = in_sizes[1] / 2;    // 400000
  const int* src = ei;
  const int* dst = ei + E;

  // workspace layout (bytes), total ~113 MB; all offsets 16B-aligned
  char* w = (char*)d_ws;
  _Float16* xs     = (_Float16*)(w + 0);           // [N,512] f16
  _Float16* hbuf   = (_Float16*)(w + 51200000);    // [N,512] f16 ([N,128] x_f16 early)
  float*    als    = (float*)(w + 102400000);      // [N,4] (layer3: [N] flat)
  float*    xs3    = (float*)(w + 104000000);      // [N,16] f32
  _Float16* wgt    = (_Float16*)(w + 107200000);   // [E,4] f16
  int*      counts = (int*)(w + 110400000);        // [N]
  int*      cur    = (int*)(w + 110600000);        // [N]
  int*      offs   = (int*)(w + 110800000);        // [N+1]
  int*      bsum   = (int*)(w + 111000192);        // [~49]
  int*      srcp   = (int*)(w + 111004288);        // [E]
  float*    wsd    = (float*)(w + 112604288);      // [512,4]
  _Float16* wt_hi  = (_Float16*)(w + 112612480);   // [512,512] f16 (B^T)
  _Float16* wt3_hi = (_Float16*)(w + 113136768);   // [16,512] f16

  // ---- CSR build ----
  hipMemsetAsync(counts, 0, 2 * (size_t)N * 4, stream);  // counts + cur contiguous
  hist_kernel<<<(E + 255) / 256, 256, 0, stream>>>(dst, counts, E);
  int nb = (N + 1023) / 1024;
  scan1<<<nb, 1024, 0, stream>>>(counts, offs, bsum, N);
  scan2<<<1, 64, 0, stream>>>(bsum, offs, nb, N, E);
  scan3<<<nb, 1024, 0, stream>>>(offs, bsum, N);
  scatter_kernel<<<(E + 255) / 256, 256, 0, stream>>>(src, dst, offs, cur, srcp, E);

  int ggrid = ((N + 127) / 128) * 4;  // 1-D grid; XCD swizzle inside kernel
  dim3 cwb(32, 8);
  int nwb = (N + 3) / 4;

  // ---- layer 1 (K=128) ----
  convX<<<(N * 128 / 4 + 255) / 256, 256, 0, stream>>>(x, hbuf, N * 128 / 4);
  wsd_kernel<<<(128 * 4 * 16 + 255) / 256, 256, 0, stream>>>(Wd1, ad1, wsd, 128, 4, 128);
  convW<<<dim3(16, 4), cwb, 0, stream>>>(Ws1, wt_hi, 128);
  gemm_f16<128><<<ggrid, 256, 0, stream>>>(hbuf, wt_hi, as1, xs, als, N);
  wgt4_kernel<128><<<nwb, 256, 0, stream>>>(als, hbuf, wsd, offs, srcp, wgt, N);
  agg512<<<N, 128, 0, stream>>>(xs, wgt, offs, srcp, b1, hbuf, N);

  // ---- layer 2 (K=512) ----
  wsd_kernel<<<(512 * 4 * 16 + 255) / 256, 256, 0, stream>>>(Wd2, ad2, wsd, 512, 4, 128);
  convW<<<dim3(16, 16), cwb, 0, stream>>>(Ws2, wt_hi, 512);
  gemm_f16<512><<<ggrid, 256, 0, stream>>>(hbuf, wt_hi, as2, xs, als, N);
  wgt4_kernel<512><<<nwb, 256, 0, stream>>>(als, hbuf, wsd, offs, srcp, wgt, N);
  agg512<<<N, 128, 0, stream>>>(xs, wgt, offs, srcp, b2, hbuf, N);

  // ---- layer 3 (K=512, N=16, H=1) ----
  wsd_kernel<<<(512 * 16 + 255) / 256, 256, 0, stream>>>(Wd3, ad3, wsd, 512, 1, 16);
  convW3<<<32, 256, 0, stream>>>(Ws3, wt3_hi);
  gemm3<<<(N / 16 + 4) / 4, 256, 0, stream>>>(hbuf, wt3_hi, as3, xs3, als, N);
  wgt1_kernel<<<nwb, 256, 0, stream>>>(als, hbuf, wsd, offs, srcp, wgt, N);
  agg16<<<(N + 15) / 16, 256, 0, stream>>>(xs3, wgt, offs, srcp, b3, (float*)d_out, N);
}